// Round 4
// baseline (69526.990 us; speedup 1.0000x reference)
//
#include <hip/hip_runtime.h>
#include <hip/hip_bf16.h>
#include <stdint.h>
#include <math.h>

using s16x8 = __attribute__((ext_vector_type(8))) short;
using f32x4 = __attribute__((ext_vector_type(4))) float;

#define NBLK 728

// ---------------- threefry2x32 (JAX-exact, partitionable) ----------------
__device__ __forceinline__ void tf2x32(uint32_t k0, uint32_t k1,
                                       uint32_t x0, uint32_t x1,
                                       uint32_t* o0, uint32_t* o1) {
  uint32_t ks0 = k0, ks1 = k1, ks2 = k0 ^ k1 ^ 0x1BD11BDAu;
  x0 += ks0; x1 += ks1;
  const int R[8] = {13,15,26,6, 17,29,16,24};
#pragma unroll
  for (int g = 0; g < 5; ++g) {
    const int base = (g & 1) ? 4 : 0;
#pragma unroll
    for (int j = 0; j < 4; ++j) {
      int r = R[base + j];
      x0 += x1;
      x1 = (x1 << r) | (x1 >> (32 - r));
      x1 ^= x0;
    }
    switch (g) {
      case 0: x0 += ks1; x1 += ks2 + 1u; break;
      case 1: x0 += ks2; x1 += ks0 + 2u; break;
      case 2: x0 += ks0; x1 += ks1 + 3u; break;
      case 3: x0 += ks1; x1 += ks2 + 4u; break;
      case 4: x0 += ks2; x1 += ks0 + 5u; break;
    }
  }
  *o0 = x0; *o1 = x1;
}

__device__ __forceinline__ float gumbel_from_bits(uint32_t bits) {
  float u = __uint_as_float((bits >> 9) | 0x3f800000u) - 1.0f;
  if (u == 0.0f) u = 1.1754943508222875e-38f;  // finfo(f32).tiny
  return -logf(-logf(u));
}

__device__ __forceinline__ float sigf(float x) { return 1.0f / (1.0f + expf(-x)); }

__device__ __forceinline__ unsigned short f2bf(float f) {
  unsigned u = __float_as_uint(f);
  unsigned r = (u + 0x7fffu + ((u >> 16) & 1u)) >> 16;
  return (unsigned short)r;
}

__device__ __forceinline__ float blk_sum(float v, volatile float* s4, int tid) {
#pragma unroll
  for (int o = 1; o < 64; o <<= 1) v += __shfl_xor(v, o, 64);
  __syncthreads();
  if ((tid & 63) == 0) s4[tid >> 6] = v;
  __syncthreads();
  return s4[0] + s4[1] + s4[2] + s4[3];
}

// device-scope grid barrier (monotonic counter; cnt zeroed per launch by init_state)
__device__ __forceinline__ void gsync(int* cnt, int* tgt) {
  __syncthreads();
  if (threadIdx.x == 0) {
    __threadfence();
    __hip_atomic_fetch_add(cnt, 1, __ATOMIC_RELEASE, __HIP_MEMORY_SCOPE_AGENT);
    *tgt += NBLK;
    while (__hip_atomic_load(cnt, __ATOMIC_ACQUIRE, __HIP_MEMORY_SCOPE_AGENT) < *tgt)
      __builtin_amdgcn_s_sleep(4);
    __threadfence();
  }
  __syncthreads();
}

// ---------------- init / embed / copy / convert ----------------
__global__ void init_state(const float* __restrict__ h0, const float* __restrict__ c0,
                           float* __restrict__ u0, float* __restrict__ cbuf,
                           float* __restrict__ stack, int* __restrict__ depth,
                           int* __restrict__ cnt) {
  int i = blockIdx.x * blockDim.x + threadIdx.x;  // 65536
  if (i < 65536) {
    int b = i >> 11, k = i & 2047;
    u0[i] = (k < 1024) ? h0[b * 1024 + k] : 0.0f;   // [h0, si=0]
    stack[i] = 0.0f;
  }
  if (i < 32768) cbuf[i] = c0[i];
  if (i < 64) depth[i] = 0;      // both parities
  if (i == 0) cnt[0] = 0;
}

__global__ void embed_kernel(const int* __restrict__ toks, const float* __restrict__ embW,
                             float* __restrict__ emb) {
  int row = blockIdx.x;            // t*32+b
  int tid = threadIdx.x;           // 128 threads, float4 each
  int tk = toks[row];
  float4 v = ((const float4*)(embW + (size_t)tk * 512))[tid];
  ((float4*)(emb + (size_t)row * 512))[tid] = v;
}

__global__ void final_copy(const float* __restrict__ u0, const float* __restrict__ cbuf,
                           float* __restrict__ out) {
  int i = blockIdx.x * blockDim.x + threadIdx.x;  // 32768
  int b = i >> 10, k = i & 1023;
  out[131072000u + i] = u0[(size_t)b * 2048 + k];
  out[131072000u + 32768u + i] = cbuf[i];
}

__global__ void to_bf16(const float* __restrict__ s, unsigned short* __restrict__ d, int n4) {
  int i = blockIdx.x * blockDim.x + threadIdx.x;
  if (i < n4) {
    float4 v = *(const float4*)(s + (size_t)i * 4);
    ushort4 o;
    o.x = f2bf(v.x); o.y = f2bf(v.y); o.z = f2bf(v.z); o.w = f2bf(v.w);
    *(ushort4*)(d + (size_t)i * 4) = o;
  }
}

// ---------------- persistent scan: 128 steps in one kernel ----------------
// Virtual A (32 x 2560) = [emb_t(512) | h(1024) | si(1024)]
// G cols (12800): [r 0..4095 | s 4096..8191 | m 8192..12287 | z 12288..12799]
// Tasks (GEMM phase): 64-col x 16-Ktile chunks:
//   r: 192 (64ct x 3js), s: 192, m: 320 (64ct x 5js), z: 24 (8ct x 3js) = 728
__global__ __launch_bounds__(256, 4) void scan_persistent(
    const float* __restrict__ emb, float* __restrict__ u0, float* __restrict__ u1,
    float* __restrict__ cbuf, float* __restrict__ stack, int* __restrict__ depth,
    float* __restrict__ Gpart, unsigned short* __restrict__ outsb, int* __restrict__ cnt,
    const float* __restrict__ rWih, const float* __restrict__ rWhh, const float* __restrict__ rb,
    const float* __restrict__ sWih, const float* __restrict__ sWhh, const float* __restrict__ sbv,
    const float* __restrict__ mWih, const float* __restrict__ mWhh, const float* __restrict__ mb,
    const float* __restrict__ piW1, const float* __restrict__ pib1,
    const float* __restrict__ pilng, const float* __restrict__ pilnb,
    const float* __restrict__ piW2, const float* __restrict__ pib2) {
  __shared__ float As2[32][34];   // [k][m]
  __shared__ float Ws2[32][70];   // [k][n]
  __shared__ float s4[4];
  __shared__ int sact[2];
  int blk = blockIdx.x, tid = threadIdx.x;
  int tgt = 0;

  // task decode (GEMM phase)
  int seg, ct, js;
  if (blk < 192)      { seg = 0; ct = blk / 3;        js = blk % 3; }
  else if (blk < 384) { seg = 1; int l = blk - 192; ct = l / 3; js = l % 3; }
  else if (blk < 704) { seg = 2; int l = blk - 384; ct = l / 5; js = l % 5; }
  else                { seg = 3; int l = blk - 704; ct = l / 3; js = l % 3; }
  int c0 = ct << 6;
  int col0 = (seg << 12) + c0;     // seg3 -> 12288 + c0
  int bk0 = js << 4, bk1 = bk0 + 16;
  int tx4 = (tid & 15) << 2, ty2 = (tid >> 4) << 1;
  int mA = tid >> 3, kA = (tid & 7) << 2;   // A stage: 1 float4/thread
  int rW = tid >> 3, kW = (tid & 7) << 2;   // W stage: 2 float4/thread

  for (int t = 0; t < 128; ++t) {
    const float* u  = (t & 1) ? u1 : u0;
    float*       un = (t & 1) ? u0 : u1;
    const float* embt = emb + (size_t)t * 16384;

    // ---------- phase 1: gates GEMM ----------
    {
      float acc[2][4] = {};
      float4 apf, wpf0, wpf1;
      // prefetch helper (resolves weight/A piece per 32-K tile)
#define LOADT(BK) { \
        int k0 = (BK) << 5; \
        const float* wb; int wlen, woff; \
        if (seg == 0)      { if (k0 < 512) { wb = rWih; wlen = 512;  woff = k0; } \
                             else          { wb = rWhh; wlen = 1024; woff = k0 - 512; } } \
        else if (seg == 1) { if (k0 < 512) { wb = sWih; wlen = 512;  woff = k0; } \
                             else          { wb = sWhh; wlen = 1024; woff = k0 - 512; } } \
        else if (seg == 2) { if (k0 < 512)       { wb = mWih; wlen = 1536; woff = k0; } \
                             else if (k0 < 1536) { wb = mWhh; wlen = 1024; woff = k0 - 512; } \
                             else                { wb = mWih; wlen = 1536; woff = k0 - 1024; } } \
        else               { if (k0 < 512) { wb = piW1; wlen = 1536; woff = k0 + 1024; } \
                             else          { wb = piW1; wlen = 1536; woff = k0 - 512; } } \
        const float* ab; int alen, aoff; \
        if (k0 < 512) { ab = embt; alen = 512;  aoff = k0; } \
        else          { ab = u;    alen = 2048; aoff = k0 - 512; } \
        apf  = *(const float4*)(ab + (size_t)mA * alen + aoff + kA); \
        wpf0 = *(const float4*)(wb + (size_t)(c0 + rW) * wlen + woff + kW); \
        wpf1 = *(const float4*)(wb + (size_t)(c0 + rW + 32) * wlen + woff + kW); }
      LOADT(bk0);
      for (int bk = bk0; bk < bk1; ++bk) {
        __syncthreads();
        As2[kA + 0][mA] = apf.x; As2[kA + 1][mA] = apf.y;
        As2[kA + 2][mA] = apf.z; As2[kA + 3][mA] = apf.w;
        Ws2[kW + 0][rW] = wpf0.x; Ws2[kW + 1][rW] = wpf0.y;
        Ws2[kW + 2][rW] = wpf0.z; Ws2[kW + 3][rW] = wpf0.w;
        Ws2[kW + 0][rW + 32] = wpf1.x; Ws2[kW + 1][rW + 32] = wpf1.y;
        Ws2[kW + 2][rW + 32] = wpf1.z; Ws2[kW + 3][rW + 32] = wpf1.w;
        __syncthreads();
        if (bk + 1 < bk1) LOADT(bk + 1);
#pragma unroll
        for (int k = 0; k < 32; ++k) {
          float2 a = *(const float2*)&As2[k][ty2];
          float4 w = *(const float4*)&Ws2[k][tx4];
          acc[0][0] += a.x * w.x; acc[0][1] += a.x * w.y; acc[0][2] += a.x * w.z; acc[0][3] += a.x * w.w;
          acc[1][0] += a.y * w.x; acc[1][1] += a.y * w.y; acc[1][2] += a.y * w.z; acc[1][3] += a.y * w.w;
        }
      }
#undef LOADT
      float* gp = Gpart + (size_t)js * 409600 + col0 + tx4;
      *(float4*)(gp + (size_t)(ty2 + 0) * 12800) = make_float4(acc[0][0], acc[0][1], acc[0][2], acc[0][3]);
      *(float4*)(gp + (size_t)(ty2 + 1) * 12800) = make_float4(acc[1][0], acc[1][1], acc[1][2], acc[1][3]);
    }
    gsync(cnt, &tgt);

    // ---------- phase 2: pointwise (128 blocks: b = blk>>2, quarter = blk&3) ----------
    if (blk < 128) {
      int b = blk >> 2, q4 = blk & 3;
      const float* Gb = Gpart + (size_t)b * 12800;
#define P3(c) (Gb[(c)] + Gb[409600 + (c)] + Gb[819200 + (c)])
#define P5(c) (Gb[(c)] + Gb[409600 + (c)] + Gb[819200 + (c)] + Gb[1228800 + (c)] + Gb[1638400 + (c)])
      float z0 = P3(12288 + tid) + pib1[tid];
      float z1 = P3(12544 + tid) + pib1[tid + 256];
      float mu = blk_sum(z0 + z1, s4, tid) * (1.0f / 512.0f);
      float d0 = z0 - mu, d1 = z1 - mu;
      float var = blk_sum(d0 * d0 + d1 * d1, s4, tid) * (1.0f / 512.0f);
      float rstd = rsqrtf(var + 1e-5f);
      float l0 = fmaxf(d0 * rstd * pilng[tid] + pilnb[tid], 0.0f);
      float l1 = fmaxf(d1 * rstd * pilng[tid + 256] + pilnb[tid + 256], 0.0f);
      float lg[3];
#pragma unroll
      for (int kk = 0; kk < 3; ++kk)
        lg[kk] = blk_sum(l0 * piW2[kk * 512 + tid] + l1 * piW2[kk * 512 + tid + 256], s4, tid);
      const int* dp = depth + ((t & 1) << 5);
      int* dn = depth + (((t + 1) & 1) << 5);
      if (tid == 0) {
        int dcur = dp[b];
#pragma unroll
        for (int kk = 0; kk < 3; ++kk) lg[kk] += pib2[kk];
        if (dcur >= 2) lg[0] = -INFINITY;   // mask push when stack full
        if (dcur == 0) lg[2] = -INFINITY;   // mask merge when empty
        uint32_t kt0, kt1;
        tf2x32(0u, 42u, 0u, (uint32_t)t, &kt0, &kt1);
#pragma unroll
        for (int kk = 0; kk < 3; ++kk) {
          uint32_t o0, o1;
          tf2x32(kt0, kt1, 0u, (uint32_t)(3 * b + kk), &o0, &o1);
          lg[kk] += gumbel_from_bits(o0 ^ o1);
        }
        int a = 0; float best = lg[0];
        if (lg[1] > best) { best = lg[1]; a = 1; }
        if (lg[2] > best) { a = 2; }
        sact[0] = a; sact[1] = dcur;
      }
      __syncthreads();
      int a = sact[0], dcur = sact[1];
      int dnew = dcur + ((a == 0) ? 1 : 0) - ((a == 2) ? 1 : 0);
      int k = (q4 << 8) + tid;
      float ir = P3(k)        + rb[k],        fr = P3(1024 + k)  + rb[1024 + k];
      float gr = P3(2048 + k) + rb[2048 + k], orr = P3(3072 + k) + rb[3072 + k];
      float is = P3(4096 + k) + sbv[k],       fs = P3(5120 + k)  + sbv[1024 + k];
      float gs = P3(6144 + k) + sbv[2048 + k], os = P3(7168 + k) + sbv[3072 + k];
      float im = P5(8192 + k) + mb[k],        fm = P5(9216 + k)  + mb[1024 + k];
      float gm = P5(10240 + k) + mb[2048 + k], om = P5(11264 + k) + mb[3072 + k];
      float cold = cbuf[b * 1024 + k];
      float crn = sigf(fr) * cold + sigf(ir) * tanhf(gr); float hrn = sigf(orr) * tanhf(crn);
      float csn = sigf(fs) * cold + sigf(is) * tanhf(gs); float hsn = sigf(os)  * tanhf(csn);
      float cmn = sigf(fm) * cold + sigf(im) * tanhf(gm); float hmn = sigf(om)  * tanhf(cmn);
      float hn = (a == 0) ? hsn : ((a == 1) ? hrn : hmn);
      float cn = (a == 0) ? csn : ((a == 1) ? crn : cmn);
      cbuf[b * 1024 + k] = cn;
      un[(size_t)b * 2048 + k] = hn;
      outsb[(size_t)t * 32768 + b * 1024 + k] = f2bf(hn);
      float si;
      if (a == 0) { stack[(size_t)(b * 2 + dcur) * 1024 + k] = hsn; si = hsn; }
      else si = (dnew > 0) ? stack[(size_t)(b * 2 + (dnew - 1)) * 1024 + k] : 0.0f;
      un[(size_t)b * 2048 + 1024 + k] = si;
      if (q4 == 0 && tid == 0) dn[b] = dnew;
#undef P3
#undef P5
    }
    gsync(cnt, &tgt);
  }
}

// ---------------- bf16 MFMA GEMM: C = A(M,K) @ W(N,K)^T + bias [+ tanh-BN -> bf16] ----------------
template <int EPI>
__global__ __launch_bounds__(256) void mfma_gemm(
    const unsigned short* __restrict__ A, const unsigned short* __restrict__ W,
    const float* __restrict__ bias, int K, int N,
    float* __restrict__ Cf, unsigned short* __restrict__ Cb,
    const float* __restrict__ g, const float* __restrict__ bb, float invS) {
  __shared__ unsigned short As[128][40];
  __shared__ unsigned short Bs[128][40];
  int tid = threadIdx.x;
  int m0 = blockIdx.y << 7, n0 = blockIdx.x << 7;
  int wid = tid >> 6, lane = tid & 63;
  int wm = (wid >> 1) << 6, wn = (wid & 1) << 6;
  int lr = lane & 15, lk = (lane >> 4) << 3;
  f32x4 acc[4][4] = {};
  for (int k0 = 0; k0 < K; k0 += 32) {
    __syncthreads();
#pragma unroll
    for (int q = 0; q < 2; ++q) {
      int idx = tid + (q << 8);                // 0..511
      int row = idx >> 2, k8 = (idx & 3) << 3;
      *(s16x8*)&As[row][k8] = *(const s16x8*)(A + (size_t)(m0 + row) * K + k0 + k8);
      *(s16x8*)&Bs[row][k8] = *(const s16x8*)(W + (size_t)(n0 + row) * K + k0 + k8);
    }
    __syncthreads();
    s16x8 af[4], bw[4];
#pragma unroll
    for (int i = 0; i < 4; ++i) {
      af[i] = *(const s16x8*)&As[wm + (i << 4) + lr][lk];
      bw[i] = *(const s16x8*)&Bs[wn + (i << 4) + lr][lk];
    }
#pragma unroll
    for (int i = 0; i < 4; ++i)
#pragma unroll
      for (int j = 0; j < 4; ++j)
        acc[i][j] = __builtin_amdgcn_mfma_f32_16x16x32_bf16(af[i], bw[j], acc[i][j], 0, 0, 0);
  }
#pragma unroll
  for (int i = 0; i < 4; ++i) {
    int row = m0 + wm + (i << 4) + ((lane >> 4) << 2);
#pragma unroll
    for (int j = 0; j < 4; ++j) {
      int col = n0 + wn + (j << 4) + lr;
      float bv = bias[col];
#pragma unroll
      for (int r = 0; r < 4; ++r) {
        float v = acc[i][j][r] + bv;
        if (EPI) {
          v = tanhf(v * invS * g[col] + bb[col]);
          Cb[(size_t)(row + r) * N + col] = f2bf(v);
        } else {
          Cf[(size_t)(row + r) * N + col] = v;
        }
      }
    }
  }
}

// ---------------- launcher ----------------
extern "C" void kernel_launch(void* const* d_in, const int* in_sizes, int n_in,
                              void* d_out, int out_size, void* d_ws, size_t ws_size,
                              hipStream_t stream) {
  const int*   tokens = (const int*)d_in[0];
  const float* h0    = (const float*)d_in[1];
  const float* c0    = (const float*)d_in[2];
  const float* embW  = (const float*)d_in[3];
  const float* rWih  = (const float*)d_in[4];
  const float* rWhh  = (const float*)d_in[5];
  const float* rb    = (const float*)d_in[6];
  const float* sWih  = (const float*)d_in[7];
  const float* sWhh  = (const float*)d_in[8];
  const float* sbv   = (const float*)d_in[9];
  const float* mWih  = (const float*)d_in[10];
  const float* mWhh  = (const float*)d_in[11];
  const float* mb    = (const float*)d_in[12];
  const float* piW1  = (const float*)d_in[13];
  const float* pib1  = (const float*)d_in[14];
  const float* pilng = (const float*)d_in[15];
  const float* pilnb = (const float*)d_in[16];
  const float* piW2  = (const float*)d_in[17];
  const float* pib2  = (const float*)d_in[18];
  const float* predW = (const float*)d_in[19];
  const float* predb = (const float*)d_in[20];
  const float* bng   = (const float*)d_in[21];
  const float* bnb   = (const float*)d_in[22];
  const float* decW  = (const float*)d_in[23];
  const float* decb  = (const float*)d_in[24];
  float* out = (float*)d_out;
  float* ws  = (float*)d_ws;

  float* emb   = ws;                          // 2,097,152 f
  float* u0    = emb + 2097152;               //    65,536 f
  float* u1    = u0 + 65536;                  //    65,536 f
  float* cbuf  = u1 + 65536;                  //    32,768 f
  float* stack = cbuf + 32768;                //    65,536 f
  float* Gpart = stack + 65536;               // 2,048,000 f (5 x 32 x 12800)
  unsigned short* outsb  = (unsigned short*)(Gpart + 2048000);  // 4,194,304 us
  unsigned short* ytbf   = outsb + 4194304;                     // 2,097,152 us
  unsigned short* predWb = ytbf + 2097152;                      //   524,288 us
  unsigned short* decWb  = predWb + 524288;                     // 16,384,000 us
  int* depth = (int*)(decWb + 16384000);                        // 64 ints
  int* cnt   = depth + 64;                                      // 1 int

  init_state<<<dim3(256), dim3(256), 0, stream>>>(h0, c0, u0, cbuf, stack, depth, cnt);
  embed_kernel<<<dim3(4096), dim3(128), 0, stream>>>(tokens, embW, emb);
  to_bf16<<<dim3(512), dim3(256), 0, stream>>>(predW, predWb, 131072);
  to_bf16<<<dim3(16000), dim3(256), 0, stream>>>(decW, decWb, 4096000);

  scan_persistent<<<dim3(NBLK), dim3(256), 0, stream>>>(
      emb, u0, u1, cbuf, stack, depth, Gpart, outsb, cnt,
      rWih, rWhh, rb, sWih, sWhh, sbv, mWih, mWhh, mb,
      piW1, pib1, pilng, pilnb, piW2, pib2);

  float invS = 1.0f / sqrtf(1.0f + 1e-5f);
  // y = tanh((outs @ predW^T + predb) * invS * bn_g + bn_b) -> ytbf (4096,512) bf16
  mfma_gemm<1><<<dim3(4, 32), dim3(256), 0, stream>>>(
      outsb, predWb, predb, 1024, 512, nullptr, ytbf, bng, bnb, invS);
  // dec = yt @ decW^T + decb -> out (4096,32000) fp32
  mfma_gemm<0><<<dim3(250, 32), dim3(256), 0, stream>>>(
      ytbf, decWb, decb, 512, 32000, out, nullptr, nullptr, nullptr, 0.0f);
  final_copy<<<dim3(128), dim3(256), 0, stream>>>(u0, cbuf, out);
}

// Round 5
// 28150.708 us; speedup vs baseline: 2.4698x; 2.4698x over previous
//
#include <hip/hip_runtime.h>
#include <hip/hip_bf16.h>
#include <stdint.h>
#include <math.h>

using s16x8 = __attribute__((ext_vector_type(8))) short;
using f32x4 = __attribute__((ext_vector_type(4))) float;

#define NBLK 728

// ---------------- threefry2x32 (JAX-exact, partitionable) ----------------
__device__ __forceinline__ void tf2x32(uint32_t k0, uint32_t k1,
                                       uint32_t x0, uint32_t x1,
                                       uint32_t* o0, uint32_t* o1) {
  uint32_t ks0 = k0, ks1 = k1, ks2 = k0 ^ k1 ^ 0x1BD11BDAu;
  x0 += ks0; x1 += ks1;
  const int R[8] = {13,15,26,6, 17,29,16,24};
#pragma unroll
  for (int g = 0; g < 5; ++g) {
    const int base = (g & 1) ? 4 : 0;
#pragma unroll
    for (int j = 0; j < 4; ++j) {
      int r = R[base + j];
      x0 += x1;
      x1 = (x1 << r) | (x1 >> (32 - r));
      x1 ^= x0;
    }
    switch (g) {
      case 0: x0 += ks1; x1 += ks2 + 1u; break;
      case 1: x0 += ks2; x1 += ks0 + 2u; break;
      case 2: x0 += ks0; x1 += ks1 + 3u; break;
      case 3: x0 += ks1; x1 += ks2 + 4u; break;
      case 4: x0 += ks2; x1 += ks0 + 5u; break;
    }
  }
  *o0 = x0; *o1 = x1;
}

__device__ __forceinline__ float gumbel_from_bits(uint32_t bits) {
  float u = __uint_as_float((bits >> 9) | 0x3f800000u) - 1.0f;
  if (u == 0.0f) u = 1.1754943508222875e-38f;  // finfo(f32).tiny
  return -logf(-logf(u));
}

__device__ __forceinline__ float sigf(float x) { return 1.0f / (1.0f + expf(-x)); }

__device__ __forceinline__ unsigned short f2bf(float f) {
  unsigned u = __float_as_uint(f);
  unsigned r = (u + 0x7fffu + ((u >> 16) & 1u)) >> 16;
  return (unsigned short)r;
}

__device__ __forceinline__ float blk_sum(float v, volatile float* s4, int tid) {
#pragma unroll
  for (int o = 1; o < 64; o <<= 1) v += __shfl_xor(v, o, 64);
  __syncthreads();
  if ((tid & 63) == 0) s4[tid >> 6] = v;
  __syncthreads();
  return s4[0] + s4[1] + s4[2] + s4[3];
}

// device-scope grid barrier. RELAXED spin (no per-poll L2 invalidate — the
// R4 catastrophe), exactly one release-fence (wbl2) before signaling and one
// acquire-fence (inv) after the condition is met.
__device__ __forceinline__ void gsync(int* cnt, int* tgt) {
  __syncthreads();
  if (threadIdx.x == 0) {
    __threadfence();   // release: write back this XCD's dirty L2 lines
    __hip_atomic_fetch_add(cnt, 1, __ATOMIC_RELAXED, __HIP_MEMORY_SCOPE_AGENT);
    *tgt += NBLK;
    while (__hip_atomic_load(cnt, __ATOMIC_RELAXED, __HIP_MEMORY_SCOPE_AGENT) < *tgt)
      __builtin_amdgcn_s_sleep(8);
    __threadfence();   // acquire: invalidate stale L2 lines once
  }
  __syncthreads();
}

// ---------------- init / embed / copy / convert ----------------
__global__ void init_state(const float* __restrict__ h0, const float* __restrict__ c0,
                           float* __restrict__ u0, float* __restrict__ cbuf,
                           float* __restrict__ stack, int* __restrict__ depth,
                           int* __restrict__ cnt) {
  int i = blockIdx.x * blockDim.x + threadIdx.x;  // 65536
  if (i < 65536) {
    int b = i >> 11, k = i & 2047;
    u0[i] = (k < 1024) ? h0[b * 1024 + k] : 0.0f;   // [h0, si=0]
    stack[i] = 0.0f;
  }
  if (i < 32768) cbuf[i] = c0[i];
  if (i < 64) depth[i] = 0;      // both parities
  if (i == 0) cnt[0] = 0;
}

__global__ void embed_kernel(const int* __restrict__ toks, const float* __restrict__ embW,
                             float* __restrict__ emb) {
  int row = blockIdx.x;            // t*32+b
  int tid = threadIdx.x;           // 128 threads, float4 each
  int tk = toks[row];
  float4 v = ((const float4*)(embW + (size_t)tk * 512))[tid];
  ((float4*)(emb + (size_t)row * 512))[tid] = v;
}

__global__ void final_copy(const float* __restrict__ u0, const float* __restrict__ cbuf,
                           float* __restrict__ out) {
  int i = blockIdx.x * blockDim.x + threadIdx.x;  // 32768
  int b = i >> 10, k = i & 1023;
  out[131072000u + i] = u0[(size_t)b * 2048 + k];
  out[131072000u + 32768u + i] = cbuf[i];
}

__global__ void to_bf16(const float* __restrict__ s, unsigned short* __restrict__ d, int n4) {
  int i = blockIdx.x * blockDim.x + threadIdx.x;
  if (i < n4) {
    float4 v = *(const float4*)(s + (size_t)i * 4);
    ushort4 o;
    o.x = f2bf(v.x); o.y = f2bf(v.y); o.z = f2bf(v.z); o.w = f2bf(v.w);
    *(ushort4*)(d + (size_t)i * 4) = o;
  }
}

// ---------------- persistent scan: 128 steps in one kernel ----------------
// Virtual A (32 x 2560) = [emb_t(512) | h(1024) | si(1024)]
// G cols (12800): [r 0..4095 | s 4096..8191 | m 8192..12287 | z 12288..12799]
// Tasks (GEMM phase): 64-col x 16-Ktile chunks:
//   r: 192 (64ct x 3js), s: 192, m: 320 (64ct x 5js), z: 24 (8ct x 3js) = 728
__global__ __launch_bounds__(256, 4) void scan_persistent(
    const float* __restrict__ emb, float* __restrict__ u0, float* __restrict__ u1,
    float* __restrict__ cbuf, float* __restrict__ stack, int* __restrict__ depth,
    float* __restrict__ Gpart, unsigned short* __restrict__ outsb, int* __restrict__ cnt,
    const float* __restrict__ rWih, const float* __restrict__ rWhh, const float* __restrict__ rb,
    const float* __restrict__ sWih, const float* __restrict__ sWhh, const float* __restrict__ sbv,
    const float* __restrict__ mWih, const float* __restrict__ mWhh, const float* __restrict__ mb,
    const float* __restrict__ piW1, const float* __restrict__ pib1,
    const float* __restrict__ pilng, const float* __restrict__ pilnb,
    const float* __restrict__ piW2, const float* __restrict__ pib2) {
  __shared__ float As2[32][34];   // [k][m]
  __shared__ float Ws2[32][70];   // [k][n]
  __shared__ float s4[4];
  __shared__ int sact[2];
  int blk = blockIdx.x, tid = threadIdx.x;
  int tgt = 0;

  // task decode (GEMM phase)
  int seg, ct, js;
  if (blk < 192)      { seg = 0; ct = blk / 3;        js = blk % 3; }
  else if (blk < 384) { seg = 1; int l = blk - 192; ct = l / 3; js = l % 3; }
  else if (blk < 704) { seg = 2; int l = blk - 384; ct = l / 5; js = l % 5; }
  else                { seg = 3; int l = blk - 704; ct = l / 3; js = l % 3; }
  int c0 = ct << 6;
  int col0 = (seg << 12) + c0;     // seg3 -> 12288 + c0
  int bk0 = js << 4, bk1 = bk0 + 16;
  int tx4 = (tid & 15) << 2, ty2 = (tid >> 4) << 1;
  int mA = tid >> 3, kA = (tid & 7) << 2;   // A stage: 1 float4/thread
  int rW = tid >> 3, kW = (tid & 7) << 2;   // W stage: 2 float4/thread

  for (int t = 0; t < 128; ++t) {
    const float* u  = (t & 1) ? u1 : u0;
    float*       un = (t & 1) ? u0 : u1;
    const float* embt = emb + (size_t)t * 16384;

    // ---------- phase 1: gates GEMM ----------
    {
      float acc[2][4] = {};
      float4 apf, wpf0, wpf1;
      // prefetch helper (resolves weight/A piece per 32-K tile)
#define LOADT(BK) { \
        int k0 = (BK) << 5; \
        const float* wb; int wlen, woff; \
        if (seg == 0)      { if (k0 < 512) { wb = rWih; wlen = 512;  woff = k0; } \
                             else          { wb = rWhh; wlen = 1024; woff = k0 - 512; } } \
        else if (seg == 1) { if (k0 < 512) { wb = sWih; wlen = 512;  woff = k0; } \
                             else          { wb = sWhh; wlen = 1024; woff = k0 - 512; } } \
        else if (seg == 2) { if (k0 < 512)       { wb = mWih; wlen = 1536; woff = k0; } \
                             else if (k0 < 1536) { wb = mWhh; wlen = 1024; woff = k0 - 512; } \
                             else                { wb = mWih; wlen = 1536; woff = k0 - 1024; } } \
        else               { if (k0 < 512) { wb = piW1; wlen = 1536; woff = k0 + 1024; } \
                             else          { wb = piW1; wlen = 1536; woff = k0 - 512; } } \
        const float* ab; int alen, aoff; \
        if (k0 < 512) { ab = embt; alen = 512;  aoff = k0; } \
        else          { ab = u;    alen = 2048; aoff = k0 - 512; } \
        apf  = *(const float4*)(ab + (size_t)mA * alen + aoff + kA); \
        wpf0 = *(const float4*)(wb + (size_t)(c0 + rW) * wlen + woff + kW); \
        wpf1 = *(const float4*)(wb + (size_t)(c0 + rW + 32) * wlen + woff + kW); }
      LOADT(bk0);
      for (int bk = bk0; bk < bk1; ++bk) {
        __syncthreads();
        As2[kA + 0][mA] = apf.x; As2[kA + 1][mA] = apf.y;
        As2[kA + 2][mA] = apf.z; As2[kA + 3][mA] = apf.w;
        Ws2[kW + 0][rW] = wpf0.x; Ws2[kW + 1][rW] = wpf0.y;
        Ws2[kW + 2][rW] = wpf0.z; Ws2[kW + 3][rW] = wpf0.w;
        Ws2[kW + 0][rW + 32] = wpf1.x; Ws2[kW + 1][rW + 32] = wpf1.y;
        Ws2[kW + 2][rW + 32] = wpf1.z; Ws2[kW + 3][rW + 32] = wpf1.w;
        __syncthreads();
        if (bk + 1 < bk1) LOADT(bk + 1);
#pragma unroll
        for (int k = 0; k < 32; ++k) {
          float2 a = *(const float2*)&As2[k][ty2];
          float4 w = *(const float4*)&Ws2[k][tx4];
          acc[0][0] += a.x * w.x; acc[0][1] += a.x * w.y; acc[0][2] += a.x * w.z; acc[0][3] += a.x * w.w;
          acc[1][0] += a.y * w.x; acc[1][1] += a.y * w.y; acc[1][2] += a.y * w.z; acc[1][3] += a.y * w.w;
        }
      }
#undef LOADT
      float* gp = Gpart + (size_t)js * 409600 + col0 + tx4;
      *(float4*)(gp + (size_t)(ty2 + 0) * 12800) = make_float4(acc[0][0], acc[0][1], acc[0][2], acc[0][3]);
      *(float4*)(gp + (size_t)(ty2 + 1) * 12800) = make_float4(acc[1][0], acc[1][1], acc[1][2], acc[1][3]);
    }
    gsync(cnt, &tgt);

    // ---------- phase 2: pointwise (128 blocks: b = blk>>2, quarter = blk&3) ----------
    if (blk < 128) {
      int b = blk >> 2, q4 = blk & 3;
      const float* Gb = Gpart + (size_t)b * 12800;
#define P3(c) (Gb[(c)] + Gb[409600 + (c)] + Gb[819200 + (c)])
#define P5(c) (Gb[(c)] + Gb[409600 + (c)] + Gb[819200 + (c)] + Gb[1228800 + (c)] + Gb[1638400 + (c)])
      float z0 = P3(12288 + tid) + pib1[tid];
      float z1 = P3(12544 + tid) + pib1[tid + 256];
      float mu = blk_sum(z0 + z1, s4, tid) * (1.0f / 512.0f);
      float d0 = z0 - mu, d1 = z1 - mu;
      float var = blk_sum(d0 * d0 + d1 * d1, s4, tid) * (1.0f / 512.0f);
      float rstd = rsqrtf(var + 1e-5f);
      float l0 = fmaxf(d0 * rstd * pilng[tid] + pilnb[tid], 0.0f);
      float l1 = fmaxf(d1 * rstd * pilng[tid + 256] + pilnb[tid + 256], 0.0f);
      float lg[3];
#pragma unroll
      for (int kk = 0; kk < 3; ++kk)
        lg[kk] = blk_sum(l0 * piW2[kk * 512 + tid] + l1 * piW2[kk * 512 + tid + 256], s4, tid);
      const int* dp = depth + ((t & 1) << 5);
      int* dn = depth + (((t + 1) & 1) << 5);
      if (tid == 0) {
        int dcur = dp[b];
#pragma unroll
        for (int kk = 0; kk < 3; ++kk) lg[kk] += pib2[kk];
        if (dcur >= 2) lg[0] = -INFINITY;   // mask push when stack full
        if (dcur == 0) lg[2] = -INFINITY;   // mask merge when empty
        uint32_t kt0, kt1;
        tf2x32(0u, 42u, 0u, (uint32_t)t, &kt0, &kt1);
#pragma unroll
        for (int kk = 0; kk < 3; ++kk) {
          uint32_t o0, o1;
          tf2x32(kt0, kt1, 0u, (uint32_t)(3 * b + kk), &o0, &o1);
          lg[kk] += gumbel_from_bits(o0 ^ o1);
        }
        int a = 0; float best = lg[0];
        if (lg[1] > best) { best = lg[1]; a = 1; }
        if (lg[2] > best) { a = 2; }
        sact[0] = a; sact[1] = dcur;
      }
      __syncthreads();
      int a = sact[0], dcur = sact[1];
      int dnew = dcur + ((a == 0) ? 1 : 0) - ((a == 2) ? 1 : 0);
      int k = (q4 << 8) + tid;
      float ir = P3(k)        + rb[k],        fr = P3(1024 + k)  + rb[1024 + k];
      float gr = P3(2048 + k) + rb[2048 + k], orr = P3(3072 + k) + rb[3072 + k];
      float is = P3(4096 + k) + sbv[k],       fs = P3(5120 + k)  + sbv[1024 + k];
      float gs = P3(6144 + k) + sbv[2048 + k], os = P3(7168 + k) + sbv[3072 + k];
      float im = P5(8192 + k) + mb[k],        fm = P5(9216 + k)  + mb[1024 + k];
      float gm = P5(10240 + k) + mb[2048 + k], om = P5(11264 + k) + mb[3072 + k];
      float cold = cbuf[b * 1024 + k];
      float crn = sigf(fr) * cold + sigf(ir) * tanhf(gr); float hrn = sigf(orr) * tanhf(crn);
      float csn = sigf(fs) * cold + sigf(is) * tanhf(gs); float hsn = sigf(os)  * tanhf(csn);
      float cmn = sigf(fm) * cold + sigf(im) * tanhf(gm); float hmn = sigf(om)  * tanhf(cmn);
      float hn = (a == 0) ? hsn : ((a == 1) ? hrn : hmn);
      float cn = (a == 0) ? csn : ((a == 1) ? crn : cmn);
      cbuf[b * 1024 + k] = cn;
      un[(size_t)b * 2048 + k] = hn;
      outsb[(size_t)t * 32768 + b * 1024 + k] = f2bf(hn);
      float si;
      if (a == 0) { stack[(size_t)(b * 2 + dcur) * 1024 + k] = hsn; si = hsn; }
      else si = (dnew > 0) ? stack[(size_t)(b * 2 + (dnew - 1)) * 1024 + k] : 0.0f;
      un[(size_t)b * 2048 + 1024 + k] = si;
      if (q4 == 0 && tid == 0) dn[b] = dnew;
#undef P3
#undef P5
    }
    gsync(cnt, &tgt);
  }
}

// ---------------- bf16 MFMA GEMM: C = A(M,K) @ W(N,K)^T + bias [+ tanh-BN -> bf16] ----------------
template <int EPI>
__global__ __launch_bounds__(256) void mfma_gemm(
    const unsigned short* __restrict__ A, const unsigned short* __restrict__ W,
    const float* __restrict__ bias, int K, int N,
    float* __restrict__ Cf, unsigned short* __restrict__ Cb,
    const float* __restrict__ g, const float* __restrict__ bb, float invS) {
  __shared__ unsigned short As[128][40];
  __shared__ unsigned short Bs[128][40];
  int tid = threadIdx.x;
  int m0 = blockIdx.y << 7, n0 = blockIdx.x << 7;
  int wid = tid >> 6, lane = tid & 63;
  int wm = (wid >> 1) << 6, wn = (wid & 1) << 6;
  int lr = lane & 15, lk = (lane >> 4) << 3;
  f32x4 acc[4][4] = {};
  for (int k0 = 0; k0 < K; k0 += 32) {
    __syncthreads();
#pragma unroll
    for (int q = 0; q < 2; ++q) {
      int idx = tid + (q << 8);                // 0..511
      int row = idx >> 2, k8 = (idx & 3) << 3;
      *(s16x8*)&As[row][k8] = *(const s16x8*)(A + (size_t)(m0 + row) * K + k0 + k8);
      *(s16x8*)&Bs[row][k8] = *(const s16x8*)(W + (size_t)(n0 + row) * K + k0 + k8);
    }
    __syncthreads();
    s16x8 af[4], bw[4];
#pragma unroll
    for (int i = 0; i < 4; ++i) {
      af[i] = *(const s16x8*)&As[wm + (i << 4) + lr][lk];
      bw[i] = *(const s16x8*)&Bs[wn + (i << 4) + lr][lk];
    }
#pragma unroll
    for (int i = 0; i < 4; ++i)
#pragma unroll
      for (int j = 0; j < 4; ++j)
        acc[i][j] = __builtin_amdgcn_mfma_f32_16x16x32_bf16(af[i], bw[j], acc[i][j], 0, 0, 0);
  }
#pragma unroll
  for (int i = 0; i < 4; ++i) {
    int row = m0 + wm + (i << 4) + ((lane >> 4) << 2);
#pragma unroll
    for (int j = 0; j < 4; ++j) {
      int col = n0 + wn + (j << 4) + lr;
      float bv = bias[col];
#pragma unroll
      for (int r = 0; r < 4; ++r) {
        float v = acc[i][j][r] + bv;
        if (EPI) {
          v = tanhf(v * invS * g[col] + bb[col]);
          Cb[(size_t)(row + r) * N + col] = f2bf(v);
        } else {
          Cf[(size_t)(row + r) * N + col] = v;
        }
      }
    }
  }
}

// ---------------- launcher ----------------
extern "C" void kernel_launch(void* const* d_in, const int* in_sizes, int n_in,
                              void* d_out, int out_size, void* d_ws, size_t ws_size,
                              hipStream_t stream) {
  const int*   tokens = (const int*)d_in[0];
  const float* h0    = (const float*)d_in[1];
  const float* c0    = (const float*)d_in[2];
  const float* embW  = (const float*)d_in[3];
  const float* rWih  = (const float*)d_in[4];
  const float* rWhh  = (const float*)d_in[5];
  const float* rb    = (const float*)d_in[6];
  const float* sWih  = (const float*)d_in[7];
  const float* sWhh  = (const float*)d_in[8];
  const float* sbv   = (const float*)d_in[9];
  const float* mWih  = (const float*)d_in[10];
  const float* mWhh  = (const float*)d_in[11];
  const float* mb    = (const float*)d_in[12];
  const float* piW1  = (const float*)d_in[13];
  const float* pib1  = (const float*)d_in[14];
  const float* pilng = (const float*)d_in[15];
  const float* pilnb = (const float*)d_in[16];
  const float* piW2  = (const float*)d_in[17];
  const float* pib2  = (const float*)d_in[18];
  const float* predW = (const float*)d_in[19];
  const float* predb = (const float*)d_in[20];
  const float* bng   = (const float*)d_in[21];
  const float* bnb   = (const float*)d_in[22];
  const float* decW  = (const float*)d_in[23];
  const float* decb  = (const float*)d_in[24];
  float* out = (float*)d_out;
  float* ws  = (float*)d_ws;

  float* emb   = ws;                          // 2,097,152 f
  float* u0    = emb + 2097152;               //    65,536 f
  float* u1    = u0 + 65536;                  //    65,536 f
  float* cbuf  = u1 + 65536;                  //    32,768 f
  float* stack = cbuf + 32768;                //    65,536 f
  float* Gpart = stack + 65536;               // 2,048,000 f (5 x 32 x 12800)
  unsigned short* outsb  = (unsigned short*)(Gpart + 2048000);  // 4,194,304 us
  unsigned short* ytbf   = outsb + 4194304;                     // 2,097,152 us
  unsigned short* predWb = ytbf + 2097152;                      //   524,288 us
  unsigned short* decWb  = predWb + 524288;                     // 16,384,000 us
  int* depth = (int*)(decWb + 16384000);                        // 64 ints
  int* cnt   = depth + 64;                                      // 1 int

  init_state<<<dim3(256), dim3(256), 0, stream>>>(h0, c0, u0, cbuf, stack, depth, cnt);
  embed_kernel<<<dim3(4096), dim3(128), 0, stream>>>(tokens, embW, emb);
  to_bf16<<<dim3(512), dim3(256), 0, stream>>>(predW, predWb, 131072);
  to_bf16<<<dim3(16000), dim3(256), 0, stream>>>(decW, decWb, 4096000);

  scan_persistent<<<dim3(NBLK), dim3(256), 0, stream>>>(
      emb, u0, u1, cbuf, stack, depth, Gpart, outsb, cnt,
      rWih, rWhh, rb, sWih, sWhh, sbv, mWih, mWhh, mb,
      piW1, pib1, pilng, pilnb, piW2, pib2);

  float invS = 1.0f / sqrtf(1.0f + 1e-5f);
  // y = tanh((outs @ predW^T + predb) * invS * bn_g + bn_b) -> ytbf (4096,512) bf16
  mfma_gemm<1><<<dim3(4, 32), dim3(256), 0, stream>>>(
      outsb, predWb, predb, 1024, 512, nullptr, ytbf, bng, bnb, invS);
  // dec = yt @ decW^T + decb -> out (4096,32000) fp32
  mfma_gemm<0><<<dim3(250, 32), dim3(256), 0, stream>>>(
      ytbf, decWb, decb, 512, 32000, out, nullptr, nullptr, nullptr, 0.0f);
  final_copy<<<dim3(128), dim3(256), 0, stream>>>(u0, cbuf, out);
}

// Round 6
// 16662.117 us; speedup vs baseline: 4.1728x; 1.6895x over previous
//
#include <hip/hip_runtime.h>
#include <hip/hip_bf16.h>
#include <stdint.h>
#include <math.h>

using s16x8 = __attribute__((ext_vector_type(8))) short;
using f32x4 = __attribute__((ext_vector_type(4))) float;

#define NBLK 728
#define GRP 91   // NBLK / 8

// ---------------- threefry2x32 (JAX-exact, partitionable) ----------------
__device__ __forceinline__ void tf2x32(uint32_t k0, uint32_t k1,
                                       uint32_t x0, uint32_t x1,
                                       uint32_t* o0, uint32_t* o1) {
  uint32_t ks0 = k0, ks1 = k1, ks2 = k0 ^ k1 ^ 0x1BD11BDAu;
  x0 += ks0; x1 += ks1;
  const int R[8] = {13,15,26,6, 17,29,16,24};
#pragma unroll
  for (int g = 0; g < 5; ++g) {
    const int base = (g & 1) ? 4 : 0;
#pragma unroll
    for (int j = 0; j < 4; ++j) {
      int r = R[base + j];
      x0 += x1;
      x1 = (x1 << r) | (x1 >> (32 - r));
      x1 ^= x0;
    }
    switch (g) {
      case 0: x0 += ks1; x1 += ks2 + 1u; break;
      case 1: x0 += ks2; x1 += ks0 + 2u; break;
      case 2: x0 += ks0; x1 += ks1 + 3u; break;
      case 3: x0 += ks1; x1 += ks2 + 4u; break;
      case 4: x0 += ks2; x1 += ks0 + 5u; break;
    }
  }
  *o0 = x0; *o1 = x1;
}

__device__ __forceinline__ float gumbel_from_bits(uint32_t bits) {
  float u = __uint_as_float((bits >> 9) | 0x3f800000u) - 1.0f;
  if (u == 0.0f) u = 1.1754943508222875e-38f;  // finfo(f32).tiny
  return -logf(-logf(u));
}

__device__ __forceinline__ float sigf(float x) { return 1.0f / (1.0f + expf(-x)); }

__device__ __forceinline__ unsigned short f2bf(float f) {
  unsigned u = __float_as_uint(f);
  unsigned r = (u + 0x7fffu + ((u >> 16) & 1u)) >> 16;
  return (unsigned short)r;
}

__device__ __forceinline__ float blk_sum(float v, volatile float* s4, int tid) {
#pragma unroll
  for (int o = 1; o < 64; o <<= 1) v += __shfl_xor(v, o, 64);
  __syncthreads();
  if ((tid & 63) == 0) s4[tid >> 6] = v;
  __syncthreads();
  return s4[0] + s4[1] + s4[2] + s4[3];
}

// Two-level grid barrier. bar layout (ints, each item on its own 64B line):
//   bar[g*16]  g=0..7 : per-group arrival counters (group = blk & 7, 91 blocks)
//   bar[128]          : master counter (one add per group per barrier)
//   bar[144]          : epoch word (spin target; written once per barrier)
// Spin polls ONLY the epoch line (read-only broadcast) with sleep backoff —
// avoids R5's poll-the-mutating-counter fabric storm.
__device__ __forceinline__ void gsync(int* bar, int* ep_local) {
  __syncthreads();
  if (threadIdx.x == 0) {
    int ep = ++(*ep_local);
    __threadfence();   // release: write back dirty L2 before signaling
    int g = blockIdx.x & 7;
    int old = __hip_atomic_fetch_add(&bar[g * 16], 1, __ATOMIC_RELAXED, __HIP_MEMORY_SCOPE_AGENT);
    if (old == ep * GRP - 1) {
      int mo = __hip_atomic_fetch_add(&bar[128], 1, __ATOMIC_RELAXED, __HIP_MEMORY_SCOPE_AGENT);
      if (mo == ep * 8 - 1)
        __hip_atomic_store(&bar[144], ep, __ATOMIC_RELAXED, __HIP_MEMORY_SCOPE_AGENT);
    }
    while (__hip_atomic_load(&bar[144], __ATOMIC_RELAXED, __HIP_MEMORY_SCOPE_AGENT) < ep)
      __builtin_amdgcn_s_sleep(16);
    __threadfence();   // acquire: invalidate stale L2 once
  }
  __syncthreads();
}

// ---------------- init / embed / copy / convert ----------------
__global__ void init_state(const float* __restrict__ h0, const float* __restrict__ c0,
                           float* __restrict__ u0, float* __restrict__ cbuf,
                           float* __restrict__ stack, int* __restrict__ depth,
                           int* __restrict__ bar) {
  int i = blockIdx.x * blockDim.x + threadIdx.x;  // 65536
  if (i < 65536) {
    int b = i >> 11, k = i & 2047;
    u0[i] = (k < 1024) ? h0[b * 1024 + k] : 0.0f;   // [h0, si=0]
    stack[i] = 0.0f;
  }
  if (i < 32768) cbuf[i] = c0[i];
  if (i < 64) depth[i] = 0;      // both parities
  if (i < 160) bar[i] = 0;       // all barrier state
}

__global__ void embed_kernel(const int* __restrict__ toks, const float* __restrict__ embW,
                             float* __restrict__ emb) {
  int row = blockIdx.x;            // t*32+b
  int tid = threadIdx.x;           // 128 threads, float4 each
  int tk = toks[row];
  float4 v = ((const float4*)(embW + (size_t)tk * 512))[tid];
  ((float4*)(emb + (size_t)row * 512))[tid] = v;
}

__global__ void final_copy(const float* __restrict__ u0, const float* __restrict__ cbuf,
                           float* __restrict__ out) {
  int i = blockIdx.x * blockDim.x + threadIdx.x;  // 32768
  int b = i >> 10, k = i & 1023;
  out[131072000u + i] = u0[(size_t)b * 2048 + k];
  out[131072000u + 32768u + i] = cbuf[i];
}

__global__ void to_bf16(const float* __restrict__ s, unsigned short* __restrict__ d, int n4) {
  int i = blockIdx.x * blockDim.x + threadIdx.x;
  if (i < n4) {
    float4 v = *(const float4*)(s + (size_t)i * 4);
    ushort4 o;
    o.x = f2bf(v.x); o.y = f2bf(v.y); o.z = f2bf(v.z); o.w = f2bf(v.w);
    *(ushort4*)(d + (size_t)i * 4) = o;
  }
}

// ---------------- persistent scan: 128 steps in one kernel ----------------
// Virtual A (32 x 2560) = [emb_t(512) | h(1024) | si(1024)]
// G cols (12800): [r 0..4095 | s 4096..8191 | m 8192..12287 | z 12288..12799]
// Tasks (GEMM phase): 64-col x 16-Ktile chunks:
//   r: 192 (64ct x 3js), s: 192, m: 320 (64ct x 5js), z: 24 (8ct x 3js) = 728
__global__ __launch_bounds__(256, 4) void scan_persistent(
    const float* __restrict__ emb, float* __restrict__ u0, float* __restrict__ u1,
    float* __restrict__ cbuf, float* __restrict__ stack, int* __restrict__ depth,
    float* __restrict__ Gpart, unsigned short* __restrict__ outsb, int* __restrict__ bar,
    const float* __restrict__ rWih, const float* __restrict__ rWhh, const float* __restrict__ rb,
    const float* __restrict__ sWih, const float* __restrict__ sWhh, const float* __restrict__ sbv,
    const float* __restrict__ mWih, const float* __restrict__ mWhh, const float* __restrict__ mb,
    const float* __restrict__ piW1, const float* __restrict__ pib1,
    const float* __restrict__ pilng, const float* __restrict__ pilnb,
    const float* __restrict__ piW2, const float* __restrict__ pib2) {
  __shared__ float As2[32][34];   // [k][m]
  __shared__ float Ws2[32][70];   // [k][n]
  __shared__ float s4[4];
  __shared__ int sact[2];
  int blk = blockIdx.x, tid = threadIdx.x;
  int ep_local = 0;

  // task decode (GEMM phase)
  int seg, ct, js;
  if (blk < 192)      { seg = 0; ct = blk / 3;        js = blk % 3; }
  else if (blk < 384) { seg = 1; int l = blk - 192; ct = l / 3; js = l % 3; }
  else if (blk < 704) { seg = 2; int l = blk - 384; ct = l / 5; js = l % 5; }
  else                { seg = 3; int l = blk - 704; ct = l / 3; js = l % 3; }
  int c0 = ct << 6;
  int col0 = (seg << 12) + c0;     // seg3 -> 12288 + c0
  int bk0 = js << 4, bk1 = bk0 + 16;
  int tx4 = (tid & 15) << 2, ty2 = (tid >> 4) << 1;
  int mA = tid >> 3, kA = (tid & 7) << 2;   // A stage: 1 float4/thread
  int rW = tid >> 3, kW = (tid & 7) << 2;   // W stage: 2 float4/thread

  for (int t = 0; t < 128; ++t) {
    const float* u  = (t & 1) ? u1 : u0;
    float*       un = (t & 1) ? u0 : u1;
    const float* embt = emb + (size_t)t * 16384;

    // ---------- phase 1: gates GEMM ----------
    {
      float acc[2][4] = {};
      float4 apf, wpf0, wpf1;
      // prefetch helper (resolves weight/A piece per 32-K tile)
#define LOADT(BK) { \
        int k0 = (BK) << 5; \
        const float* wb; int wlen, woff; \
        if (seg == 0)      { if (k0 < 512) { wb = rWih; wlen = 512;  woff = k0; } \
                             else          { wb = rWhh; wlen = 1024; woff = k0 - 512; } } \
        else if (seg == 1) { if (k0 < 512) { wb = sWih; wlen = 512;  woff = k0; } \
                             else          { wb = sWhh; wlen = 1024; woff = k0 - 512; } } \
        else if (seg == 2) { if (k0 < 512)       { wb = mWih; wlen = 1536; woff = k0; } \
                             else if (k0 < 1536) { wb = mWhh; wlen = 1024; woff = k0 - 512; } \
                             else                { wb = mWih; wlen = 1536; woff = k0 - 1024; } } \
        else               { if (k0 < 512) { wb = piW1; wlen = 1536; woff = k0 + 1024; } \
                             else          { wb = piW1; wlen = 1536; woff = k0 - 512; } } \
        const float* ab; int alen, aoff; \
        if (k0 < 512) { ab = embt; alen = 512;  aoff = k0; } \
        else          { ab = u;    alen = 2048; aoff = k0 - 512; } \
        apf  = *(const float4*)(ab + (size_t)mA * alen + aoff + kA); \
        wpf0 = *(const float4*)(wb + (size_t)(c0 + rW) * wlen + woff + kW); \
        wpf1 = *(const float4*)(wb + (size_t)(c0 + rW + 32) * wlen + woff + kW); }
      LOADT(bk0);
      for (int bk = bk0; bk < bk1; ++bk) {
        __syncthreads();
        As2[kA + 0][mA] = apf.x; As2[kA + 1][mA] = apf.y;
        As2[kA + 2][mA] = apf.z; As2[kA + 3][mA] = apf.w;
        Ws2[kW + 0][rW] = wpf0.x; Ws2[kW + 1][rW] = wpf0.y;
        Ws2[kW + 2][rW] = wpf0.z; Ws2[kW + 3][rW] = wpf0.w;
        Ws2[kW + 0][rW + 32] = wpf1.x; Ws2[kW + 1][rW + 32] = wpf1.y;
        Ws2[kW + 2][rW + 32] = wpf1.z; Ws2[kW + 3][rW + 32] = wpf1.w;
        __syncthreads();
        if (bk + 1 < bk1) LOADT(bk + 1);
#pragma unroll
        for (int k = 0; k < 32; ++k) {
          float2 a = *(const float2*)&As2[k][ty2];
          float4 w = *(const float4*)&Ws2[k][tx4];
          acc[0][0] += a.x * w.x; acc[0][1] += a.x * w.y; acc[0][2] += a.x * w.z; acc[0][3] += a.x * w.w;
          acc[1][0] += a.y * w.x; acc[1][1] += a.y * w.y; acc[1][2] += a.y * w.z; acc[1][3] += a.y * w.w;
        }
      }
#undef LOADT
      float* gp = Gpart + (size_t)js * 409600 + col0 + tx4;
      *(float4*)(gp + (size_t)(ty2 + 0) * 12800) = make_float4(acc[0][0], acc[0][1], acc[0][2], acc[0][3]);
      *(float4*)(gp + (size_t)(ty2 + 1) * 12800) = make_float4(acc[1][0], acc[1][1], acc[1][2], acc[1][3]);
    }
    gsync(bar, &ep_local);

    // ---------- phase 2: pointwise (128 blocks: b = blk>>2, quarter = blk&3) ----------
    if (blk < 128) {
      int b = blk >> 2, q4 = blk & 3;
      const float* Gb = Gpart + (size_t)b * 12800;
#define P3(c) (Gb[(c)] + Gb[409600 + (c)] + Gb[819200 + (c)])
#define P5(c) (Gb[(c)] + Gb[409600 + (c)] + Gb[819200 + (c)] + Gb[1228800 + (c)] + Gb[1638400 + (c)])
      float z0 = P3(12288 + tid) + pib1[tid];
      float z1 = P3(12544 + tid) + pib1[tid + 256];
      float mu = blk_sum(z0 + z1, s4, tid) * (1.0f / 512.0f);
      float d0 = z0 - mu, d1 = z1 - mu;
      float var = blk_sum(d0 * d0 + d1 * d1, s4, tid) * (1.0f / 512.0f);
      float rstd = rsqrtf(var + 1e-5f);
      float l0 = fmaxf(d0 * rstd * pilng[tid] + pilnb[tid], 0.0f);
      float l1 = fmaxf(d1 * rstd * pilng[tid + 256] + pilnb[tid + 256], 0.0f);
      float lg[3];
#pragma unroll
      for (int kk = 0; kk < 3; ++kk)
        lg[kk] = blk_sum(l0 * piW2[kk * 512 + tid] + l1 * piW2[kk * 512 + tid + 256], s4, tid);
      const int* dp = depth + ((t & 1) << 5);
      int* dn = depth + (((t + 1) & 1) << 5);
      if (tid == 0) {
        int dcur = dp[b];
#pragma unroll
        for (int kk = 0; kk < 3; ++kk) lg[kk] += pib2[kk];
        if (dcur >= 2) lg[0] = -INFINITY;   // mask push when stack full
        if (dcur == 0) lg[2] = -INFINITY;   // mask merge when empty
        uint32_t kt0, kt1;
        tf2x32(0u, 42u, 0u, (uint32_t)t, &kt0, &kt1);
#pragma unroll
        for (int kk = 0; kk < 3; ++kk) {
          uint32_t o0, o1;
          tf2x32(kt0, kt1, 0u, (uint32_t)(3 * b + kk), &o0, &o1);
          lg[kk] += gumbel_from_bits(o0 ^ o1);
        }
        int a = 0; float best = lg[0];
        if (lg[1] > best) { best = lg[1]; a = 1; }
        if (lg[2] > best) { a = 2; }
        sact[0] = a; sact[1] = dcur;
      }
      __syncthreads();
      int a = sact[0], dcur = sact[1];
      int dnew = dcur + ((a == 0) ? 1 : 0) - ((a == 2) ? 1 : 0);
      int k = (q4 << 8) + tid;
      float ir = P3(k)        + rb[k],        fr = P3(1024 + k)  + rb[1024 + k];
      float gr = P3(2048 + k) + rb[2048 + k], orr = P3(3072 + k) + rb[3072 + k];
      float is = P3(4096 + k) + sbv[k],       fs = P3(5120 + k)  + sbv[1024 + k];
      float gs = P3(6144 + k) + sbv[2048 + k], os = P3(7168 + k) + sbv[3072 + k];
      float im = P5(8192 + k) + mb[k],        fm = P5(9216 + k)  + mb[1024 + k];
      float gm = P5(10240 + k) + mb[2048 + k], om = P5(11264 + k) + mb[3072 + k];
      float cold = cbuf[b * 1024 + k];
      float crn = sigf(fr) * cold + sigf(ir) * tanhf(gr); float hrn = sigf(orr) * tanhf(crn);
      float csn = sigf(fs) * cold + sigf(is) * tanhf(gs); float hsn = sigf(os)  * tanhf(csn);
      float cmn = sigf(fm) * cold + sigf(im) * tanhf(gm); float hmn = sigf(om)  * tanhf(cmn);
      float hn = (a == 0) ? hsn : ((a == 1) ? hrn : hmn);
      float cn = (a == 0) ? csn : ((a == 1) ? crn : cmn);
      cbuf[b * 1024 + k] = cn;
      un[(size_t)b * 2048 + k] = hn;
      outsb[(size_t)t * 32768 + b * 1024 + k] = f2bf(hn);
      float si;
      if (a == 0) { stack[(size_t)(b * 2 + dcur) * 1024 + k] = hsn; si = hsn; }
      else si = (dnew > 0) ? stack[(size_t)(b * 2 + (dnew - 1)) * 1024 + k] : 0.0f;
      un[(size_t)b * 2048 + 1024 + k] = si;
      if (q4 == 0 && tid == 0) dn[b] = dnew;
#undef P3
#undef P5
    }
    gsync(bar, &ep_local);
  }
}

// ---------------- bf16 MFMA GEMM: C = A(M,K) @ W(N,K)^T + bias [+ tanh-BN -> bf16] ----------------
template <int EPI>
__global__ __launch_bounds__(256) void mfma_gemm(
    const unsigned short* __restrict__ A, const unsigned short* __restrict__ W,
    const float* __restrict__ bias, int K, int N,
    float* __restrict__ Cf, unsigned short* __restrict__ Cb,
    const float* __restrict__ g, const float* __restrict__ bb, float invS) {
  __shared__ unsigned short As[128][40];
  __shared__ unsigned short Bs[128][40];
  int tid = threadIdx.x;
  int m0 = blockIdx.y << 7, n0 = blockIdx.x << 7;
  int wid = tid >> 6, lane = tid & 63;
  int wm = (wid >> 1) << 6, wn = (wid & 1) << 6;
  int lr = lane & 15, lk = (lane >> 4) << 3;
  f32x4 acc[4][4] = {};
  for (int k0 = 0; k0 < K; k0 += 32) {
    __syncthreads();
#pragma unroll
    for (int q = 0; q < 2; ++q) {
      int idx = tid + (q << 8);                // 0..511
      int row = idx >> 2, k8 = (idx & 3) << 3;
      *(s16x8*)&As[row][k8] = *(const s16x8*)(A + (size_t)(m0 + row) * K + k0 + k8);
      *(s16x8*)&Bs[row][k8] = *(const s16x8*)(W + (size_t)(n0 + row) * K + k0 + k8);
    }
    __syncthreads();
    s16x8 af[4], bw[4];
#pragma unroll
    for (int i = 0; i < 4; ++i) {
      af[i] = *(const s16x8*)&As[wm + (i << 4) + lr][lk];
      bw[i] = *(const s16x8*)&Bs[wn + (i << 4) + lr][lk];
    }
#pragma unroll
    for (int i = 0; i < 4; ++i)
#pragma unroll
      for (int j = 0; j < 4; ++j)
        acc[i][j] = __builtin_amdgcn_mfma_f32_16x16x32_bf16(af[i], bw[j], acc[i][j], 0, 0, 0);
  }
#pragma unroll
  for (int i = 0; i < 4; ++i) {
    int row = m0 + wm + (i << 4) + ((lane >> 4) << 2);
#pragma unroll
    for (int j = 0; j < 4; ++j) {
      int col = n0 + wn + (j << 4) + lr;
      float bv = bias[col];
#pragma unroll
      for (int r = 0; r < 4; ++r) {
        float v = acc[i][j][r] + bv;
        if (EPI) {
          v = tanhf(v * invS * g[col] + bb[col]);
          Cb[(size_t)(row + r) * N + col] = f2bf(v);
        } else {
          Cf[(size_t)(row + r) * N + col] = v;
        }
      }
    }
  }
}

// ---------------- launcher ----------------
extern "C" void kernel_launch(void* const* d_in, const int* in_sizes, int n_in,
                              void* d_out, int out_size, void* d_ws, size_t ws_size,
                              hipStream_t stream) {
  const int*   tokens = (const int*)d_in[0];
  const float* h0    = (const float*)d_in[1];
  const float* c0    = (const float*)d_in[2];
  const float* embW  = (const float*)d_in[3];
  const float* rWih  = (const float*)d_in[4];
  const float* rWhh  = (const float*)d_in[5];
  const float* rb    = (const float*)d_in[6];
  const float* sWih  = (const float*)d_in[7];
  const float* sWhh  = (const float*)d_in[8];
  const float* sbv   = (const float*)d_in[9];
  const float* mWih  = (const float*)d_in[10];
  const float* mWhh  = (const float*)d_in[11];
  const float* mb    = (const float*)d_in[12];
  const float* piW1  = (const float*)d_in[13];
  const float* pib1  = (const float*)d_in[14];
  const float* pilng = (const float*)d_in[15];
  const float* pilnb = (const float*)d_in[16];
  const float* piW2  = (const float*)d_in[17];
  const float* pib2  = (const float*)d_in[18];
  const float* predW = (const float*)d_in[19];
  const float* predb = (const float*)d_in[20];
  const float* bng   = (const float*)d_in[21];
  const float* bnb   = (const float*)d_in[22];
  const float* decW  = (const float*)d_in[23];
  const float* decb  = (const float*)d_in[24];
  float* out = (float*)d_out;
  float* ws  = (float*)d_ws;

  float* emb   = ws;                          // 2,097,152 f
  float* u0    = emb + 2097152;               //    65,536 f
  float* u1    = u0 + 65536;                  //    65,536 f
  float* cbuf  = u1 + 65536;                  //    32,768 f
  float* stack = cbuf + 32768;                //    65,536 f
  float* Gpart = stack + 65536;               // 2,048,000 f (5 x 32 x 12800)
  unsigned short* outsb  = (unsigned short*)(Gpart + 2048000);  // 4,194,304 us
  unsigned short* ytbf   = outsb + 4194304;                     // 2,097,152 us
  unsigned short* predWb = ytbf + 2097152;                      //   524,288 us
  unsigned short* decWb  = predWb + 524288;                     // 16,384,000 us
  int* depth = (int*)(decWb + 16384000);                        // 64 ints
  int* bar   = depth + 64;                                      // 160 ints

  init_state<<<dim3(256), dim3(256), 0, stream>>>(h0, c0, u0, cbuf, stack, depth, bar);
  embed_kernel<<<dim3(4096), dim3(128), 0, stream>>>(tokens, embW, emb);
  to_bf16<<<dim3(512), dim3(256), 0, stream>>>(predW, predWb, 131072);
  to_bf16<<<dim3(16000), dim3(256), 0, stream>>>(decW, decWb, 4096000);

  scan_persistent<<<dim3(NBLK), dim3(256), 0, stream>>>(
      emb, u0, u1, cbuf, stack, depth, Gpart, outsb, bar,
      rWih, rWhh, rb, sWih, sWhh, sbv, mWih, mWhh, mb,
      piW1, pib1, pilng, pilnb, piW2, pib2);

  float invS = 1.0f / sqrtf(1.0f + 1e-5f);
  // y = tanh((outs @ predW^T + predb) * invS * bn_g + bn_b) -> ytbf (4096,512) bf16
  mfma_gemm<1><<<dim3(4, 32), dim3(256), 0, stream>>>(
      outsb, predWb, predb, 1024, 512, nullptr, ytbf, bng, bnb, invS);
  // dec = yt @ decW^T + decb -> out (4096,32000) fp32
  mfma_gemm<0><<<dim3(250, 32), dim3(256), 0, stream>>>(
      ytbf, decWb, decb, 512, 32000, out, nullptr, nullptr, nullptr, 0.0f);
  final_copy<<<dim3(128), dim3(256), 0, stream>>>(u0, cbuf, out);
}

// Round 8
// 12620.873 us; speedup vs baseline: 5.5089x; 1.3202x over previous
//
#include <hip/hip_runtime.h>
#include <hip/hip_bf16.h>
#include <stdint.h>
#include <math.h>

using s16x8 = __attribute__((ext_vector_type(8))) short;
using f16x8 = __attribute__((ext_vector_type(8))) _Float16;
using f32x4 = __attribute__((ext_vector_type(4))) float;

#define NBLK 512
#define GRP 64   // NBLK / 8 groups

// ---------------- threefry2x32 (JAX-exact, partitionable) ----------------
__device__ __forceinline__ void tf2x32(uint32_t k0, uint32_t k1,
                                       uint32_t x0, uint32_t x1,
                                       uint32_t* o0, uint32_t* o1) {
  uint32_t ks0 = k0, ks1 = k1, ks2 = k0 ^ k1 ^ 0x1BD11BDAu;
  x0 += ks0; x1 += ks1;
  const int R[8] = {13,15,26,6, 17,29,16,24};
#pragma unroll
  for (int g = 0; g < 5; ++g) {
    const int base = (g & 1) ? 4 : 0;
#pragma unroll
    for (int j = 0; j < 4; ++j) {
      int r = R[base + j];
      x0 += x1;
      x1 = (x1 << r) | (x1 >> (32 - r));
      x1 ^= x0;
    }
    switch (g) {
      case 0: x0 += ks1; x1 += ks2 + 1u; break;
      case 1: x0 += ks2; x1 += ks0 + 2u; break;
      case 2: x0 += ks0; x1 += ks1 + 3u; break;
      case 3: x0 += ks1; x1 += ks2 + 4u; break;
      case 4: x0 += ks2; x1 += ks0 + 5u; break;
    }
  }
  *o0 = x0; *o1 = x1;
}

__device__ __forceinline__ float gumbel_from_bits(uint32_t bits) {
  float u = __uint_as_float((bits >> 9) | 0x3f800000u) - 1.0f;
  if (u == 0.0f) u = 1.1754943508222875e-38f;  // finfo(f32).tiny
  return -logf(-logf(u));
}

__device__ __forceinline__ float sigf(float x) { return 1.0f / (1.0f + expf(-x)); }

__device__ __forceinline__ unsigned short f2bf(float f) {
  unsigned u = __float_as_uint(f);
  unsigned r = (u + 0x7fffu + ((u >> 16) & 1u)) >> 16;
  return (unsigned short)r;
}

__device__ __forceinline__ float f16tof(unsigned short v) {
  _Float16 h; __builtin_memcpy(&h, &v, 2); return (float)h;
}

__device__ __forceinline__ float blk_sum(float v, volatile float* s4, int tid) {
#pragma unroll
  for (int o = 1; o < 64; o <<= 1) v += __shfl_xor(v, o, 64);
  __syncthreads();
  if ((tid & 63) == 0) s4[tid >> 6] = v;
  __syncthreads();
  return s4[0] + s4[1] + s4[2] + s4[3];
}

// Two-level grid barrier (R6-proven): relaxed spin on epoch broadcast line,
// one release fence before arrival, one acquire fence after.
__device__ __forceinline__ void gsync(int* bar, int* ep_local) {
  __syncthreads();
  if (threadIdx.x == 0) {
    int ep = ++(*ep_local);
    __threadfence();
    int g = blockIdx.x & 7;
    int old = __hip_atomic_fetch_add(&bar[g * 16], 1, __ATOMIC_RELAXED, __HIP_MEMORY_SCOPE_AGENT);
    if (old == ep * GRP - 1) {
      int mo = __hip_atomic_fetch_add(&bar[128], 1, __ATOMIC_RELAXED, __HIP_MEMORY_SCOPE_AGENT);
      if (mo == ep * 8 - 1)
        __hip_atomic_store(&bar[144], ep, __ATOMIC_RELAXED, __HIP_MEMORY_SCOPE_AGENT);
    }
    while (__hip_atomic_load(&bar[144], __ATOMIC_RELAXED, __HIP_MEMORY_SCOPE_AGENT) < ep)
      __builtin_amdgcn_s_sleep(16);
    __threadfence();
  }
  __syncthreads();
}

// ---------------- init / embed / copy / convert / pack ----------------
__global__ void init_state(const float* __restrict__ h0, const float* __restrict__ c0,
                           float* __restrict__ u0, float* __restrict__ cbuf,
                           float* __restrict__ stack, int* __restrict__ depth,
                           int* __restrict__ bar) {
  int i = blockIdx.x * blockDim.x + threadIdx.x;  // 65536
  if (i < 65536) {
    int b = i >> 11, k = i & 2047;
    u0[i] = (k < 1024) ? h0[b * 1024 + k] : 0.0f;   // [h0, si=0]
    stack[i] = 0.0f;
  }
  if (i < 32768) cbuf[i] = c0[i];
  if (i < 64) depth[i] = 0;
  if (i < 160) bar[i] = 0;
}

__global__ void embed_kernel(const int* __restrict__ toks, const float* __restrict__ embW,
                             float* __restrict__ emb) {
  int row = blockIdx.x;            // t*32+b
  int tid = threadIdx.x;           // 128 threads
  int tk = toks[row];
  float4 v = ((const float4*)(embW + (size_t)tk * 512))[tid];
  ((float4*)(emb + (size_t)row * 512))[tid] = v;
}

__global__ void final_copy(const float* __restrict__ u0, const float* __restrict__ cbuf,
                           float* __restrict__ out) {
  int i = blockIdx.x * blockDim.x + threadIdx.x;  // 32768
  int b = i >> 10, k = i & 1023;
  out[131072000u + i] = u0[(size_t)b * 2048 + k];
  out[131072000u + 32768u + i] = cbuf[i];
}

__global__ void to_bf16(const float* __restrict__ s, unsigned short* __restrict__ d, int n4) {
  int i = blockIdx.x * blockDim.x + threadIdx.x;
  if (i < n4) {
    float4 v = *(const float4*)(s + (size_t)i * 4);
    ushort4 o;
    o.x = f2bf(v.x); o.y = f2bf(v.y); o.z = f2bf(v.z); o.w = f2bf(v.w);
    *(ushort4*)(d + (size_t)i * 4) = o;
  }
}

__global__ void to_f16(const float* __restrict__ s, unsigned short* __restrict__ d, int n4) {
  int i = blockIdx.x * blockDim.x + threadIdx.x;
  if (i < n4) {
    float4 v = *(const float4*)(s + (size_t)i * 4);
    _Float16 h0_ = (_Float16)v.x, h1 = (_Float16)v.y, h2 = (_Float16)v.z, h3 = (_Float16)v.w;
    ushort4 o;
    __builtin_memcpy(&o.x, &h0_, 2); __builtin_memcpy(&o.y, &h1, 2);
    __builtin_memcpy(&o.z, &h2, 2); __builtin_memcpy(&o.w, &h3, 2);
    *(ushort4*)(d + (size_t)i * 4) = o;
  }
}

// Wcat fp16 (12288 x 512): rows 0..4095 rWih, 4096..8191 sWih, 8192..12287 mWih[:, :512]
__global__ void pack_wcat16(const float* __restrict__ rWih, const float* __restrict__ sWih,
                            const float* __restrict__ mWih, unsigned short* __restrict__ wcat) {
  int idx = blockIdx.x * 256 + threadIdx.x;   // 6,291,456
  if (idx >= 12288 * 512) return;
  int c = idx >> 9, k = idx & 511;
  float v;
  if (c < 4096)      v = rWih[(size_t)c * 512 + k];
  else if (c < 8192) v = sWih[(size_t)(c - 4096) * 512 + k];
  else               v = mWih[(size_t)(c - 8192) * 1536 + k];
  _Float16 h = (_Float16)v;
  unsigned short b; __builtin_memcpy(&b, &h, 2);
  wcat[idx] = b;
}

// wpak: per (blk 512, wave 4, frag 32, lane 64, e 8) fp16 in exact MFMA B-frag order.
// frag f<16: hi (fk=f); f>=16: lo (fk=f-16). Wave's slice = 16 cols x 512 K.
// r-blk (blk<128): col = blk*32 + (wv>>1)*16 + (lane&15), kh = wv&1, W = rWhh (K1024)
// s-blk: sWhh. m-blk (blk>=256): col = (blk-256)*16 + (lane&15), kh = wv (K2048),
//   k<1024 -> mWhh[col][k]; else mWih[col][512 + k-1024].
__global__ void pack_whilo(const float* __restrict__ rWhh, const float* __restrict__ sWhh,
                           const float* __restrict__ mWhh, const float* __restrict__ mWih,
                           unsigned short* __restrict__ wpak) {
  int idx = blockIdx.x * 256 + threadIdx.x;  // 33,554,432
  int e = idx & 7, lane = (idx >> 3) & 63, f = (idx >> 9) & 31, wv = (idx >> 14) & 3, blk = idx >> 16;
  int lr = lane & 15, lk = lane >> 4;
  int hilo = f >> 4, fk = f & 15;
  int seg = (blk < 128) ? 0 : ((blk < 256) ? 1 : 2);
  int kh, col;
  if (seg < 2) { int fc = wv >> 1; kh = wv & 1; col = ((seg ? blk - 128 : blk) << 5) + (fc << 4) + lr; }
  else         { kh = wv; col = ((blk - 256) << 4) + lr; }
  int k = (kh << 9) + (fk << 5) + (lk << 3) + e;
  float w;
  if (seg == 0)      w = rWhh[(size_t)col * 1024 + k];
  else if (seg == 1) w = sWhh[(size_t)col * 1024 + k];
  else w = (k < 1024) ? mWhh[(size_t)col * 1024 + k]
                      : mWih[(size_t)col * 1536 + 512 + (k - 1024)];
  _Float16 hv = (_Float16)w;
  _Float16 ov = hilo ? (_Float16)(w - (float)hv) : hv;
  unsigned short b; __builtin_memcpy(&b, &ov, 2);
  wpak[idx] = b;
}

// ---------------- X_z fp32 GEMM: Xz = emb(4096x512) @ piW1[:,1024:1536]^T ----------------
__global__ __launch_bounds__(256) void xz_gemm(const float* __restrict__ A,
                                               const float* __restrict__ W,
                                               float* __restrict__ C) {
  __shared__ float Asb[32][68];
  __shared__ float Bsb[32][68];
  int tid = threadIdx.x;
  int tx = tid & 15, ty = tid >> 4;
  int m0 = blockIdx.y * 64, n0 = blockIdx.x * 64;
  int r = tid >> 3, kb = (tid & 7) * 4;
  float acc[4][4] = {};
  for (int k0 = 0; k0 < 512; k0 += 32) {
    __syncthreads();
    float4 a0 = *(const float4*)(A + (size_t)(m0 + r) * 512 + k0 + kb);
    float4 a1 = *(const float4*)(A + (size_t)(m0 + r + 32) * 512 + k0 + kb);
    float4 b0 = *(const float4*)(W + (size_t)(n0 + r) * 1536 + 1024 + k0 + kb);
    float4 b1 = *(const float4*)(W + (size_t)(n0 + r + 32) * 1536 + 1024 + k0 + kb);
    Asb[kb + 0][r] = a0.x; Asb[kb + 1][r] = a0.y; Asb[kb + 2][r] = a0.z; Asb[kb + 3][r] = a0.w;
    Asb[kb + 0][r + 32] = a1.x; Asb[kb + 1][r + 32] = a1.y; Asb[kb + 2][r + 32] = a1.z; Asb[kb + 3][r + 32] = a1.w;
    Bsb[kb + 0][r] = b0.x; Bsb[kb + 1][r] = b0.y; Bsb[kb + 2][r] = b0.z; Bsb[kb + 3][r] = b0.w;
    Bsb[kb + 0][r + 32] = b1.x; Bsb[kb + 1][r + 32] = b1.y; Bsb[kb + 2][r + 32] = b1.z; Bsb[kb + 3][r + 32] = b1.w;
    __syncthreads();
#pragma unroll
    for (int kk = 0; kk < 32; ++kk) {
      float4 av = *(const float4*)&Asb[kk][ty * 4];
      float4 bv = *(const float4*)&Bsb[kk][tx * 4];
      float aa[4] = {av.x, av.y, av.z, av.w};
      float bw[4] = {bv.x, bv.y, bv.z, bv.w};
#pragma unroll
      for (int i = 0; i < 4; ++i)
#pragma unroll
        for (int j = 0; j < 4; ++j) acc[i][j] += aa[i] * bw[j];
    }
  }
#pragma unroll
  for (int i = 0; i < 4; ++i)
#pragma unroll
    for (int j = 0; j < 4; ++j)
      C[(size_t)(m0 + ty * 4 + i) * 512 + n0 + tx * 4 + j] = acc[i][j];
}

// ---------------- fp16 MFMA GEMM (X_ih): C = A(M,K) @ W(N,K)^T -> fp16 ----------------
__global__ __launch_bounds__(256) void mfma_gemm_f16out(
    const unsigned short* __restrict__ A, const unsigned short* __restrict__ W,
    unsigned short* __restrict__ C, int K, int N) {
  __shared__ unsigned short As[128][40];
  __shared__ unsigned short Bs[128][40];
  int tid = threadIdx.x;
  int m0 = blockIdx.y << 7, n0 = blockIdx.x << 7;
  int wid = tid >> 6, lane = tid & 63;
  int wm = (wid >> 1) << 6, wn = (wid & 1) << 6;
  int lr = lane & 15, lk = (lane >> 4) << 3;
  f32x4 acc[4][4] = {};
  for (int k0 = 0; k0 < K; k0 += 32) {
    __syncthreads();
#pragma unroll
    for (int q = 0; q < 2; ++q) {
      int idx = tid + (q << 8);
      int row = idx >> 2, k8 = (idx & 3) << 3;
      *(s16x8*)&As[row][k8] = *(const s16x8*)(A + (size_t)(m0 + row) * K + k0 + k8);
      *(s16x8*)&Bs[row][k8] = *(const s16x8*)(W + (size_t)(n0 + row) * K + k0 + k8);
    }
    __syncthreads();
#pragma unroll
    for (int i = 0; i < 4; ++i)
#pragma unroll
      for (int j = 0; j < 4; ++j) {
        f16x8 af = *(const f16x8*)&As[wm + (i << 4) + lr][lk];
        f16x8 bw = *(const f16x8*)&Bs[wn + (j << 4) + lr][lk];
        acc[i][j] = __builtin_amdgcn_mfma_f32_16x16x32_f16(af, bw, acc[i][j], 0, 0, 0);
      }
  }
#pragma unroll
  for (int i = 0; i < 4; ++i) {
    int row = m0 + wm + (i << 4) + ((lane >> 4) << 2);
#pragma unroll
    for (int j = 0; j < 4; ++j) {
      int col = n0 + wn + (j << 4) + lr;
#pragma unroll
      for (int r = 0; r < 4; ++r) {
        _Float16 h = (_Float16)acc[i][j][r];
        unsigned short b; __builtin_memcpy(&b, &h, 2);
        C[(size_t)(row + r) * N + col] = b;
      }
    }
  }
}

// ---------------- persistent scan: weights in REGISTERS (fp16 hi/lo) ----------------
// 512 blocks x 256 thr (4 waves). r: blk<128 (32 cols K1024), s: <256, m: <512 (16 cols K2048).
// Wave slice = 16 cols x 512 K as 16 hi + 16 lo f16x8 frags (128 VGPRs).
// z col blk: fp32 VALU dot (h . piW1[blk][0:1024]).
__global__ __launch_bounds__(256, 2) void scan_persistent(
    float* __restrict__ u0, float* __restrict__ u1,
    float* __restrict__ cbuf, float* __restrict__ stack, int* __restrict__ depth,
    float* __restrict__ slabG, unsigned short* __restrict__ outsb, int* __restrict__ bar,
    const unsigned short* __restrict__ wpak, const unsigned short* __restrict__ X_ihH,
    const float* __restrict__ Xz, const float* __restrict__ piW1,
    const float* __restrict__ rb, const float* __restrict__ sbv, const float* __restrict__ mb,
    const float* __restrict__ pib1, const float* __restrict__ pilng,
    const float* __restrict__ pilnb, const float* __restrict__ piW2,
    const float* __restrict__ pib2) {
  __shared__ __align__(16) _Float16 AsH[32 * 72];
  __shared__ __align__(16) _Float16 AsL[32 * 72];
  __shared__ float Cred[1536];
  __shared__ float zred[256];
  __shared__ float s4[4];
  __shared__ int sact[2];

  int blk = blockIdx.x, tid = threadIdx.x;
  int ep_local = 0;
  int seg = (blk < 128) ? 0 : ((blk < 256) ? 1 : 2);
  int gc0 = (seg == 0) ? blk * 32 : (seg == 1) ? 4096 + (blk - 128) * 32
                                               : 8192 + (blk - 256) * 16;
  int wid = tid >> 6, lane = tid & 63;
  int lr = lane & 15, lk = lane >> 4;
  int kh = (seg < 2) ? (wid & 1) : wid;
  int fc = (seg < 2) ? (wid >> 1) : 0;
  int rr = tid >> 3, k8 = (tid & 7) << 3;

  // ---- load W hi/lo fragments into registers (once) ----
  f16x8 whi[16], wlo[16];
  {
    const f16x8* wp = (const f16x8*)wpak + (((size_t)(blk * 4 + wid)) << 11) + lane;
#pragma unroll
    for (int f = 0; f < 16; ++f) {
      whi[f] = wp[(size_t)f * 64];
      wlo[f] = wp[(size_t)(f + 16) * 64];
    }
  }

  for (int t = 0; t < 128; ++t) {
    const float* u  = (t & 1) ? u1 : u0;
    float*       un = (t & 1) ? u0 : u1;

    // ---------- z col (fp32 exact): z[r] = h[r] . piW1[blk][0:1024] ----------
    {
      int r = tid & 31, kq = tid >> 5;
      const float* ur = u + r * 2048 + kq * 128;
      const float* wr = piW1 + (size_t)blk * 1536 + kq * 128;
      float zacc = 0.0f;
#pragma unroll
      for (int i8 = 0; i8 < 32; ++i8) {
        float4 a = *(const float4*)(ur + i8 * 4);
        float4 w = *(const float4*)(wr + i8 * 4);
        zacc += a.x * w.x + a.y * w.y + a.z * w.z + a.w * w.w;
      }
      zred[tid] = zacc;
    }
    __syncthreads();
    if (tid < 32) {
      float z = 0.0f;
#pragma unroll
      for (int q = 0; q < 8; ++q) z += zred[q * 32 + tid];
      slabG[(size_t)tid * 12800 + 12288 + blk] = z;
    }

    // ---------- MFMA GEMM: partial C(32 x 16|32 cols) over wave's K-range ----------
    f32x4 acc0 = {0.f, 0.f, 0.f, 0.f}, acc1 = {0.f, 0.f, 0.f, 0.f};
    float4 pa, pb, qa, qb;
#define LDU(RA, RB, CH) { const float* p_ = u + rr * 2048 + ((CH) << 6) + k8; \
                          RA = *(const float4*)p_; RB = *(const float4*)(p_ + 4); }
#define GEMM_BODY(NCH) \
    LDU(pa, pb, 0); LDU(qa, qb, 1); \
    _Pragma("unroll") \
    for (int ch = 0; ch < (NCH); ++ch) { \
      __syncthreads(); \
      { float av[8] = {pa.x, pa.y, pa.z, pa.w, pb.x, pb.y, pb.z, pb.w}; \
        f16x8 vh, vl; \
        _Pragma("unroll") \
        for (int j = 0; j < 8; ++j) { \
          _Float16 h_ = (_Float16)av[j]; vh[j] = h_; vl[j] = (_Float16)(av[j] - (float)h_); } \
        *(f16x8*)&AsH[rr * 72 + k8] = vh; \
        *(f16x8*)&AsL[rr * 72 + k8] = vl; } \
      pa = qa; pb = qb; \
      if (ch + 2 < (NCH)) LDU(qa, qb, ch + 2); \
      __syncthreads(); \
      if ((ch >> 3) == kh) { \
        _Pragma("unroll") \
        for (int tt = 0; tt < 2; ++tt) { \
          int fl = ((ch & 7) << 1) | tt; \
          int ko = (tt << 5) + (lk << 3); \
          f16x8 Ah0 = *(const f16x8*)&AsH[lr * 72 + ko]; \
          f16x8 Al0 = *(const f16x8*)&AsL[lr * 72 + ko]; \
          f16x8 Ah1 = *(const f16x8*)&AsH[(16 + lr) * 72 + ko]; \
          f16x8 Al1 = *(const f16x8*)&AsL[(16 + lr) * 72 + ko]; \
          acc0 = __builtin_amdgcn_mfma_f32_16x16x32_f16(Ah0, whi[fl], acc0, 0, 0, 0); \
          acc0 = __builtin_amdgcn_mfma_f32_16x16x32_f16(Al0, whi[fl], acc0, 0, 0, 0); \
          acc0 = __builtin_amdgcn_mfma_f32_16x16x32_f16(Ah0, wlo[fl], acc0, 0, 0, 0); \
          acc1 = __builtin_amdgcn_mfma_f32_16x16x32_f16(Ah1, whi[fl], acc1, 0, 0, 0); \
          acc1 = __builtin_amdgcn_mfma_f32_16x16x32_f16(Al1, whi[fl], acc1, 0, 0, 0); \
          acc1 = __builtin_amdgcn_mfma_f32_16x16x32_f16(Ah1, wlo[fl], acc1, 0, 0, 0); \
        } \
      } \
    }
    if (seg < 2) { GEMM_BODY(16) } else { GEMM_BODY(32) }
#undef GEMM_BODY
#undef LDU

    // ---------- combine K-split partials, write slabG ----------
    __syncthreads();
    int rq = (lane >> 4) << 2;
    if (seg < 2) {
      if (kh == 1) {
#pragma unroll
        for (int q = 0; q < 4; ++q) {
          Cred[fc * 512 + (rq + q) * 16 + lr] = acc0[q];
          Cred[fc * 512 + (16 + rq + q) * 16 + lr] = acc1[q];
        }
      }
      __syncthreads();
      if (kh == 0) {
#pragma unroll
        for (int q = 0; q < 4; ++q) {
          float v0 = acc0[q] + Cred[fc * 512 + (rq + q) * 16 + lr];
          float v1 = acc1[q] + Cred[fc * 512 + (16 + rq + q) * 16 + lr];
          slabG[(size_t)(rq + q) * 12800 + gc0 + fc * 16 + lr] = v0;
          slabG[(size_t)(16 + rq + q) * 12800 + gc0 + fc * 16 + lr] = v1;
        }
      }
    } else {
      if (kh > 0) {
#pragma unroll
        for (int q = 0; q < 4; ++q) {
          Cred[(kh - 1) * 512 + (rq + q) * 16 + lr] = acc0[q];
          Cred[(kh - 1) * 512 + (16 + rq + q) * 16 + lr] = acc1[q];
        }
      }
      __syncthreads();
      if (kh == 0) {
#pragma unroll
        for (int q = 0; q < 4; ++q) {
          float v0 = acc0[q] + Cred[(rq + q) * 16 + lr] + Cred[512 + (rq + q) * 16 + lr]
                     + Cred[1024 + (rq + q) * 16 + lr];
          float v1 = acc1[q] + Cred[(16 + rq + q) * 16 + lr] + Cred[512 + (16 + rq + q) * 16 + lr]
                     + Cred[1024 + (16 + rq + q) * 16 + lr];
          slabG[(size_t)(rq + q) * 12800 + gc0 + lr] = v0;
          slabG[(size_t)(16 + rq + q) * 12800 + gc0 + lr] = v1;
        }
      }
    }
    gsync(bar, &ep_local);

    // ---------- pointwise (blocks 0..127: b = blk>>2, quarter = blk&3) ----------
    if (blk < 128) {
      int b = blk >> 2, q4 = blk & 3;
      const float* Gb = slabG + (size_t)b * 12800;
      size_t xrow = (size_t)t * 32 + b;
      const unsigned short* Xg = X_ihH + xrow * 12288;
      const float* Xzr = Xz + xrow * 512;
#define GV(c) (Gb[(c)] + f16tof(Xg[(c)]))
      float z0 = Gb[12288 + tid] + Xzr[tid] + pib1[tid];
      float z1 = Gb[12544 + tid] + Xzr[256 + tid] + pib1[tid + 256];
      float mu = blk_sum(z0 + z1, s4, tid) * (1.0f / 512.0f);
      float d0 = z0 - mu, d1 = z1 - mu;
      float var = blk_sum(d0 * d0 + d1 * d1, s4, tid) * (1.0f / 512.0f);
      float rstd = rsqrtf(var + 1e-5f);
      float l0 = fmaxf(d0 * rstd * pilng[tid] + pilnb[tid], 0.0f);
      float l1 = fmaxf(d1 * rstd * pilng[tid + 256] + pilnb[tid + 256], 0.0f);
      float lg[3];
#pragma unroll
      for (int kk = 0; kk < 3; ++kk)
        lg[kk] = blk_sum(l0 * piW2[kk * 512 + tid] + l1 * piW2[kk * 512 + tid + 256], s4, tid);
      const int* dp = depth + ((t & 1) << 5);
      int* dn = depth + (((t + 1) & 1) << 5);
      if (tid == 0) {
        int dcur = dp[b];
#pragma unroll
        for (int kk = 0; kk < 3; ++kk) lg[kk] += pib2[kk];
        if (dcur >= 2) lg[0] = -INFINITY;
        if (dcur == 0) lg[2] = -INFINITY;
        uint32_t kt0, kt1;
        tf2x32(0u, 42u, 0u, (uint32_t)t, &kt0, &kt1);
#pragma unroll
        for (int kk = 0; kk < 3; ++kk) {
          uint32_t o0, o1;
          tf2x32(kt0, kt1, 0u, (uint32_t)(3 * b + kk), &o0, &o1);
          lg[kk] += gumbel_from_bits(o0 ^ o1);
        }
        int a = 0; float best = lg[0];
        if (lg[1] > best) { best = lg[1]; a = 1; }
        if (lg[2] > best) { a = 2; }
        sact[0] = a; sact[1] = dcur;
      }
      __syncthreads();
      int a = sact[0], dcur = sact[1];
      int dnew = dcur + ((a == 0) ? 1 : 0) - ((a == 2) ? 1 : 0);
      int k = (q4 << 8) + tid;
      float ir = GV(k)        + rb[k],        fr_ = GV(1024 + k)  + rb[1024 + k];
      float gr = GV(2048 + k) + rb[2048 + k], orr = GV(3072 + k)  + rb[3072 + k];
      float is = GV(4096 + k) + sbv[k],       fs  = GV(5120 + k)  + sbv[1024 + k];
      float gs = GV(6144 + k) + sbv[2048 + k], os = GV(7168 + k)  + sbv[3072 + k];
      float im = GV(8192 + k) + mb[k],        fm  = GV(9216 + k)  + mb[1024 + k];
      float gm = GV(10240 + k) + mb[2048 + k], om = GV(11264 + k) + mb[3072 + k];
#undef GV
      float cold = cbuf[b * 1024 + k];
      float crn = sigf(fr_) * cold + sigf(ir) * tanhf(gr); float hrn = sigf(orr) * tanhf(crn);
      float csn = sigf(fs)  * cold + sigf(is) * tanhf(gs); float hsn = sigf(os)  * tanhf(csn);
      float cmn = sigf(fm)  * cold + sigf(im) * tanhf(gm); float hmn = sigf(om)  * tanhf(cmn);
      float hn = (a == 0) ? hsn : ((a == 1) ? hrn : hmn);
      float cn = (a == 0) ? csn : ((a == 1) ? crn : cmn);
      cbuf[b * 1024 + k] = cn;
      un[(size_t)b * 2048 + k] = hn;
      outsb[(size_t)t * 32768 + b * 1024 + k] = f2bf(hn);
      float si;
      if (a == 0) { stack[(size_t)(b * 2 + dcur) * 1024 + k] = hsn; si = hsn; }
      else si = (dnew > 0) ? stack[(size_t)(b * 2 + (dnew - 1)) * 1024 + k] : 0.0f;
      un[(size_t)b * 2048 + 1024 + k] = si;
      if (q4 == 0 && tid == 0) dn[b] = dnew;
    }
    gsync(bar, &ep_local);
  }
}

// ---------------- bf16 MFMA GEMM (pred/dec): C = A(M,K)@W(N,K)^T + bias [tanh-BN] ----------------
template <int EPI>   // 0: fp32 + bias; 1: tanh-BN -> bf16
__global__ __launch_bounds__(256) void mfma_gemm(
    const unsigned short* __restrict__ A, const unsigned short* __restrict__ W,
    const float* __restrict__ bias, int K, int N,
    float* __restrict__ Cf, unsigned short* __restrict__ Cb,
    const float* __restrict__ g, const float* __restrict__ bb, float invS) {
  __shared__ unsigned short As[128][40];
  __shared__ unsigned short Bs[128][40];
  int tid = threadIdx.x;
  int m0 = blockIdx.y << 7, n0 = blockIdx.x << 7;
  int wid = tid >> 6, lane = tid & 63;
  int wm = (wid >> 1) << 6, wn = (wid & 1) << 6;
  int lr = lane & 15, lk = (lane >> 4) << 3;
  f32x4 acc[4][4] = {};
  for (int k0 = 0; k0 < K; k0 += 32) {
    __syncthreads();
#pragma unroll
    for (int q = 0; q < 2; ++q) {
      int idx = tid + (q << 8);
      int row = idx >> 2, k8 = (idx & 3) << 3;
      *(s16x8*)&As[row][k8] = *(const s16x8*)(A + (size_t)(m0 + row) * K + k0 + k8);
      *(s16x8*)&Bs[row][k8] = *(const s16x8*)(W + (size_t)(n0 + row) * K + k0 + k8);
    }
    __syncthreads();
    s16x8 af[4], bw[4];
#pragma unroll
    for (int i = 0; i < 4; ++i) {
      af[i] = *(const s16x8*)&As[wm + (i << 4) + lr][lk];
      bw[i] = *(const s16x8*)&Bs[wn + (i << 4) + lr][lk];
    }
#pragma unroll
    for (int i = 0; i < 4; ++i)
#pragma unroll
      for (int j = 0; j < 4; ++j)
        acc[i][j] = __builtin_amdgcn_mfma_f32_16x16x32_bf16(af[i], bw[j], acc[i][j], 0, 0, 0);
  }
#pragma unroll
  for (int i = 0; i < 4; ++i) {
    int row = m0 + wm + (i << 4) + ((lane >> 4) << 2);
#pragma unroll
    for (int j = 0; j < 4; ++j) {
      int col = n0 + wn + (j << 4) + lr;
      float bv = bias[col];
#pragma unroll
      for (int r = 0; r < 4; ++r) {
        float v = acc[i][j][r] + bv;
        if (EPI) {
          v = tanhf(v * invS * g[col] + bb[col]);
          Cb[(size_t)(row + r) * N + col] = f2bf(v);
        } else {
          Cf[(size_t)(row + r) * N + col] = v;
        }
      }
    }
  }
}

// ---------------- launcher ----------------
extern "C" void kernel_launch(void* const* d_in, const int* in_sizes, int n_in,
                              void* d_out, int out_size, void* d_ws, size_t ws_size,
                              hipStream_t stream) {
  const int*   tokens = (const int*)d_in[0];
  const float* h0    = (const float*)d_in[1];
  const float* c0    = (const float*)d_in[2];
  const float* embW  = (const float*)d_in[3];
  const float* rWih  = (const float*)d_in[4];
  const float* rWhh  = (const float*)d_in[5];
  const float* rb    = (const float*)d_in[6];
  const float* sWih  = (const float*)d_in[7];
  const float* sWhh  = (const float*)d_in[8];
  const float* sbv   = (const float*)d_in[9];
  const float* mWih  = (const float*)d_in[10];
  const float* mWhh  = (const float*)d_in[11];
  const float* mb    = (const float*)d_in[12];
  const float* piW1  = (const float*)d_in[13];
  const float* pib1  = (const float*)d_in[14];
  const float* pilng = (const float*)d_in[15];
  const float* pilnb = (const float*)d_in[16];
  const float* piW2  = (const float*)d_in[17];
  const float* pib2  = (const float*)d_in[18];
  const float* predW = (const float*)d_in[19];
  const float* predb = (const float*)d_in[20];
  const float* bng   = (const float*)d_in[21];
  const float* bnb   = (const float*)d_in[22];
  const float* decW  = (const float*)d_in[23];
  const float* decb  = (const float*)d_in[24];
  float* out = (float*)d_out;
  float* ws  = (float*)d_ws;

  // float region
  float* emb   = ws;                          // 2,097,152
  float* u0    = emb + 2097152;               //    65,536
  float* u1    = u0 + 65536;                  //    65,536
  float* cbuf  = u1 + 65536;                  //    32,768
  float* stack = cbuf + 32768;                //    65,536
  float* slabG = stack + 65536;               //   409,600
  float* Xz    = slabG + 409600;              // 2,097,152
  // ushort region
  unsigned short* usb    = (unsigned short*)(Xz + 2097152);
  unsigned short* X_ihH  = usb;                                 // 50,331,648
  unsigned short* wpak   = X_ihH + 50331648;                    // 33,554,432
  unsigned short* wcatH  = wpak + 33554432;                     //  6,291,456
  unsigned short* embH   = wcatH + 6291456;                     //  2,097,152
  unsigned short* outsb  = embH + 2097152;                      //  4,194,304
  int* depth = (int*)(outsb + 4194304);                         // 64 ints
  int* bar   = depth + 64;                                      // 160 ints
  // post-scan aliases (wpak is dead after the scan)
  unsigned short* decWb  = wpak;                                // 16,384,000
  unsigned short* predWb = wpak + 16384000;                     //    524,288
  unsigned short* ytbf   = wpak + 16908288;                     //  2,097,152

  init_state<<<dim3(256), dim3(256), 0, stream>>>(h0, c0, u0, cbuf, stack, depth, bar);
  embed_kernel<<<dim3(4096), dim3(128), 0, stream>>>(tokens, embW, emb);
  to_f16<<<dim3(2048), dim3(256), 0, stream>>>(emb, embH, 524288);
  pack_wcat16<<<dim3(24576), dim3(256), 0, stream>>>(rWih, sWih, mWih, wcatH);
  pack_whilo<<<dim3(131072), dim3(256), 0, stream>>>(rWhh, sWhh, mWhh, mWih, wpak);

  // Xz = emb @ piW1[:,1024:1536]^T  (fp32, exact sampling path)
  xz_gemm<<<dim3(8, 64), dim3(256), 0, stream>>>(emb, piW1, Xz);
  // X_ih = embH @ wcatH^T  (4096 x 12288, fp16)
  mfma_gemm_f16out<<<dim3(96, 32), dim3(256), 0, stream>>>(embH, wcatH, X_ihH, 512, 12288);

  scan_persistent<<<dim3(NBLK), dim3(256), 0, stream>>>(
      u0, u1, cbuf, stack, depth, slabG, outsb, bar,
      wpak, X_ihH, Xz, piW1, rb, sbv, mb, pib1, pilng, pilnb, piW2, pib2);

  // pred/dec weights converted after the scan into the dead wpak region
  to_bf16<<<dim3(512), dim3(256), 0, stream>>>(predW, predWb, 131072);
  to_bf16<<<dim3(16000), dim3(256), 0, stream>>>(decW, decWb, 4096000);

  float invS = 1.0f / sqrtf(1.0f + 1e-5f);
  mfma_gemm<1><<<dim3(4, 32), dim3(256), 0, stream>>>(
      outsb, predWb, predb, 1024, 512, nullptr, ytbf, bng, bnb, invS);
  mfma_gemm<0><<<dim3(250, 32), dim3(256), 0, stream>>>(
      ytbf, decWb, decb, 512, 32000, out, nullptr, nullptr, nullptr, 0.0f);
  final_copy<<<dim3(128), dim3(256), 0, stream>>>(u0, cbuf, out);
}

// Round 9
// 10986.514 us; speedup vs baseline: 6.3284x; 1.1488x over previous
//
#include <hip/hip_runtime.h>
#include <hip/hip_bf16.h>
#include <stdint.h>
#include <math.h>

using s16x8 = __attribute__((ext_vector_type(8))) short;
using f16x8 = __attribute__((ext_vector_type(8))) _Float16;
using f32x4 = __attribute__((ext_vector_type(4))) float;

#define NBLK 256
#define GRP 32   // NBLK / 8 groups

// ---------------- agent-scope coherent (sc0 sc1) access helpers ----------------
__device__ __forceinline__ float ldGf(const float* p) {
  unsigned v = __hip_atomic_load((const unsigned*)p, __ATOMIC_RELAXED, __HIP_MEMORY_SCOPE_AGENT);
  return __uint_as_float(v);
}
__device__ __forceinline__ void stGf(float* p, float x) {
  __hip_atomic_store((unsigned*)p, __float_as_uint(x), __ATOMIC_RELAXED, __HIP_MEMORY_SCOPE_AGENT);
}
__device__ __forceinline__ unsigned ldGu(const unsigned* p) {
  return __hip_atomic_load(p, __ATOMIC_RELAXED, __HIP_MEMORY_SCOPE_AGENT);
}
__device__ __forceinline__ void stGu(unsigned* p, unsigned v) {
  __hip_atomic_store(p, v, __ATOMIC_RELAXED, __HIP_MEMORY_SCOPE_AGENT);
}
__device__ __forceinline__ unsigned long long ldU64(const unsigned long long* p) {
  return __hip_atomic_load(p, __ATOMIC_RELAXED, __HIP_MEMORY_SCOPE_AGENT);
}
__device__ __forceinline__ int ldGi(const int* p) {
  return __hip_atomic_load(p, __ATOMIC_RELAXED, __HIP_MEMORY_SCOPE_AGENT);
}
__device__ __forceinline__ void stGi(int* p, int v) {
  __hip_atomic_store(p, v, __ATOMIC_RELAXED, __HIP_MEMORY_SCOPE_AGENT);
}

// ---------------- hi/lo fp16 packing of fp32 ----------------
__device__ __forceinline__ unsigned packHL(float x) {
  _Float16 h = (_Float16)x;
  float r = x - (float)h;
  _Float16 l = (_Float16)r;
  unsigned short hb, lb;
  __builtin_memcpy(&hb, &h, 2); __builtin_memcpy(&lb, &l, 2);
  return (unsigned)hb | ((unsigned)lb << 16);
}
__device__ __forceinline__ float unpackHL(unsigned v) {
  unsigned short hb = (unsigned short)(v & 0xffffu), lb = (unsigned short)(v >> 16);
  _Float16 h, l;
  __builtin_memcpy(&h, &hb, 2); __builtin_memcpy(&l, &lb, 2);
  return (float)h + (float)l;
}

// ---------------- threefry2x32 (JAX-exact, partitionable) ----------------
__device__ __forceinline__ void tf2x32(uint32_t k0, uint32_t k1,
                                       uint32_t x0, uint32_t x1,
                                       uint32_t* o0, uint32_t* o1) {
  uint32_t ks0 = k0, ks1 = k1, ks2 = k0 ^ k1 ^ 0x1BD11BDAu;
  x0 += ks0; x1 += ks1;
  const int R[8] = {13,15,26,6, 17,29,16,24};
#pragma unroll
  for (int g = 0; g < 5; ++g) {
    const int base = (g & 1) ? 4 : 0;
#pragma unroll
    for (int j = 0; j < 4; ++j) {
      int r = R[base + j];
      x0 += x1;
      x1 = (x1 << r) | (x1 >> (32 - r));
      x1 ^= x0;
    }
    switch (g) {
      case 0: x0 += ks1; x1 += ks2 + 1u; break;
      case 1: x0 += ks2; x1 += ks0 + 2u; break;
      case 2: x0 += ks0; x1 += ks1 + 3u; break;
      case 3: x0 += ks1; x1 += ks2 + 4u; break;
      case 4: x0 += ks2; x1 += ks0 + 5u; break;
    }
  }
  *o0 = x0; *o1 = x1;
}

__device__ __forceinline__ float gumbel_from_bits(uint32_t bits) {
  float u = __uint_as_float((bits >> 9) | 0x3f800000u) - 1.0f;
  if (u == 0.0f) u = 1.1754943508222875e-38f;  // finfo(f32).tiny
  return -logf(-logf(u));
}

__device__ __forceinline__ float sigf(float x) { return 1.0f / (1.0f + expf(-x)); }

__device__ __forceinline__ unsigned short f2bf(float f) {
  unsigned u = __float_as_uint(f);
  unsigned r = (u + 0x7fffu + ((u >> 16) & 1u)) >> 16;
  return (unsigned short)r;
}

__device__ __forceinline__ float f16tof(unsigned short v) {
  _Float16 h; __builtin_memcpy(&h, &v, 2); return (float)h;
}

// block reduction over 512 threads (8 waves)
__device__ __forceinline__ float bsum512(float v, volatile float* s8, int tid) {
#pragma unroll
  for (int o = 1; o < 64; o <<= 1) v += __shfl_xor(v, o, 64);
  __syncthreads();
  if ((tid & 63) == 0) s8[tid >> 6] = v;
  __syncthreads();
  float r = 0.0f;
#pragma unroll
  for (int j = 0; j < 8; ++j) r += s8[j];
  return r;
}

// Two-level grid barrier, FENCE-FREE: all cross-block data moves via sc0sc1
// (agent-scope relaxed atomics), so no L2 writeback/invalidate is needed.
// __syncthreads() drains each wave's vmcnt before the arrival RMW.
__device__ __forceinline__ void gsync(int* bar, int* ep_local) {
  __syncthreads();
  if (threadIdx.x == 0) {
    int ep = ++(*ep_local);
    int g = blockIdx.x & 7;
    int old = __hip_atomic_fetch_add(&bar[g * 16], 1, __ATOMIC_RELAXED, __HIP_MEMORY_SCOPE_AGENT);
    if (old == ep * GRP - 1) {
      int mo = __hip_atomic_fetch_add(&bar[128], 1, __ATOMIC_RELAXED, __HIP_MEMORY_SCOPE_AGENT);
      if (mo == ep * 8 - 1)
        __hip_atomic_store(&bar[144], ep, __ATOMIC_RELAXED, __HIP_MEMORY_SCOPE_AGENT);
    }
    while (__hip_atomic_load(&bar[144], __ATOMIC_RELAXED, __HIP_MEMORY_SCOPE_AGENT) < ep)
      __builtin_amdgcn_s_sleep(8);
  }
  __syncthreads();
}

// ---------------- init / embed / copy / convert / pack ----------------
__global__ void init_state(const float* __restrict__ h0, const float* __restrict__ c0,
                           unsigned* __restrict__ uHL0, float* __restrict__ cbuf,
                           float* __restrict__ stack, int* __restrict__ depth,
                           int* __restrict__ bar) {
  int i = blockIdx.x * blockDim.x + threadIdx.x;  // 65536
  if (i < 65536) {
    int b = i >> 11, k = i & 2047;
    float v = (k < 1024) ? h0[b * 1024 + k] : 0.0f;   // [h0 | si=0]
    uHL0[i] = packHL(v);
    stack[i] = 0.0f;
  }
  if (i < 32768) cbuf[i] = c0[i];
  if (i < 64) depth[i] = 0;
  if (i < 160) bar[i] = 0;
}

__global__ void embed_kernel(const int* __restrict__ toks, const float* __restrict__ embW,
                             float* __restrict__ emb) {
  int row = blockIdx.x;            // t*32+b
  int tid = threadIdx.x;           // 128 threads
  int tk = toks[row];
  float4 v = ((const float4*)(embW + (size_t)tk * 512))[tid];
  ((float4*)(emb + (size_t)row * 512))[tid] = v;
}

__global__ void final_copy(const unsigned* __restrict__ uHL0, const float* __restrict__ cbuf,
                           float* __restrict__ out) {
  int i = blockIdx.x * blockDim.x + threadIdx.x;  // 32768
  int b = i >> 10, k = i & 1023;
  out[131072000u + i] = unpackHL(uHL0[(size_t)b * 2048 + k]);
  out[131072000u + 32768u + i] = cbuf[i];
}

__global__ void to_bf16(const float* __restrict__ s, unsigned short* __restrict__ d, int n4) {
  int i = blockIdx.x * blockDim.x + threadIdx.x;
  if (i < n4) {
    float4 v = *(const float4*)(s + (size_t)i * 4);
    ushort4 o;
    o.x = f2bf(v.x); o.y = f2bf(v.y); o.z = f2bf(v.z); o.w = f2bf(v.w);
    *(ushort4*)(d + (size_t)i * 4) = o;
  }
}

__global__ void to_f16(const float* __restrict__ s, unsigned short* __restrict__ d, int n4) {
  int i = blockIdx.x * blockDim.x + threadIdx.x;
  if (i < n4) {
    float4 v = *(const float4*)(s + (size_t)i * 4);
    _Float16 h0_ = (_Float16)v.x, h1 = (_Float16)v.y, h2 = (_Float16)v.z, h3 = (_Float16)v.w;
    ushort4 o;
    __builtin_memcpy(&o.x, &h0_, 2); __builtin_memcpy(&o.y, &h1, 2);
    __builtin_memcpy(&o.z, &h2, 2); __builtin_memcpy(&o.w, &h3, 2);
    *(ushort4*)(d + (size_t)i * 4) = o;
  }
}

// Wcat fp16 (12288 x 512): rows 0..4095 rWih, 4096..8191 sWih, 8192..12287 mWih[:, :512]
__global__ void pack_wcat16(const float* __restrict__ rWih, const float* __restrict__ sWih,
                            const float* __restrict__ mWih, unsigned short* __restrict__ wcat) {
  int idx = blockIdx.x * 256 + threadIdx.x;   // 6,291,456
  if (idx >= 12288 * 512) return;
  int c = idx >> 9, k = idx & 511;
  float v;
  if (c < 4096)      v = rWih[(size_t)c * 512 + k];
  else if (c < 8192) v = sWih[(size_t)(c - 4096) * 512 + k];
  else               v = mWih[(size_t)(c - 8192) * 1536 + k];
  _Float16 h = (_Float16)v;
  unsigned short b; __builtin_memcpy(&b, &h, 2);
  wcat[idx] = b;
}

// wpak (R8-proven layout): per (oblk 512, owv 4, frag 32, lane 64, e 8) fp16 in
// exact MFMA B-frag order. frag f<16: hi; f>=16: lo.
// r oblk<128: col = oblk*32 + (owv>>1)*16 + lr, kh = owv&1, K1024 = rWhh
// s oblk<256: sWhh. m oblk>=256: col = (oblk-256)*16 + lr, kh = owv (K2048),
//   k<1024 -> mWhh[col][k]; else mWih[col][512 + k-1024].
__global__ void pack_whilo(const float* __restrict__ rWhh, const float* __restrict__ sWhh,
                           const float* __restrict__ mWhh, const float* __restrict__ mWih,
                           unsigned short* __restrict__ wpak) {
  int idx = blockIdx.x * 256 + threadIdx.x;  // 33,554,432
  int e = idx & 7, lane = (idx >> 3) & 63, f = (idx >> 9) & 31, wv = (idx >> 14) & 3, blk = idx >> 16;
  int lr = lane & 15, lk = lane >> 4;
  int hilo = f >> 4, fk = f & 15;
  int seg = (blk < 128) ? 0 : ((blk < 256) ? 1 : 2);
  int kh, col;
  if (seg < 2) { int fc = wv >> 1; kh = wv & 1; col = ((seg ? blk - 128 : blk) << 5) + (fc << 4) + lr; }
  else         { kh = wv; col = ((blk - 256) << 4) + lr; }
  int k = (kh << 9) + (fk << 5) + (lk << 3) + e;
  float w;
  if (seg == 0)      w = rWhh[(size_t)col * 1024 + k];
  else if (seg == 1) w = sWhh[(size_t)col * 1024 + k];
  else w = (k < 1024) ? mWhh[(size_t)col * 1024 + k]
                      : mWih[(size_t)col * 1536 + 512 + (k - 1024)];
  _Float16 hv = (_Float16)w;
  _Float16 ov = hilo ? (_Float16)(w - (float)hv) : hv;
  unsigned short b; __builtin_memcpy(&b, &ov, 2);
  wpak[idx] = b;
}

// ---------------- X_z fp32 GEMM: Xz = emb(4096x512) @ piW1[:,1024:1536]^T ----------------
__global__ __launch_bounds__(256) void xz_gemm(const float* __restrict__ A,
                                               const float* __restrict__ W,
                                               float* __restrict__ C) {
  __shared__ float Asb[32][68];
  __shared__ float Bsb[32][68];
  int tid = threadIdx.x;
  int tx = tid & 15, ty = tid >> 4;
  int m0 = blockIdx.y * 64, n0 = blockIdx.x * 64;
  int r = tid >> 3, kb = (tid & 7) * 4;
  float acc[4][4] = {};
  for (int k0 = 0; k0 < 512; k0 += 32) {
    __syncthreads();
    float4 a0 = *(const float4*)(A + (size_t)(m0 + r) * 512 + k0 + kb);
    float4 a1 = *(const float4*)(A + (size_t)(m0 + r + 32) * 512 + k0 + kb);
    float4 b0 = *(const float4*)(W + (size_t)(n0 + r) * 1536 + 1024 + k0 + kb);
    float4 b1 = *(const float4*)(W + (size_t)(n0 + r + 32) * 1536 + 1024 + k0 + kb);
    Asb[kb + 0][r] = a0.x; Asb[kb + 1][r] = a0.y; Asb[kb + 2][r] = a0.z; Asb[kb + 3][r] = a0.w;
    Asb[kb + 0][r + 32] = a1.x; Asb[kb + 1][r + 32] = a1.y; Asb[kb + 2][r + 32] = a1.z; Asb[kb + 3][r + 32] = a1.w;
    Bsb[kb + 0][r] = b0.x; Bsb[kb + 1][r] = b0.y; Bsb[kb + 2][r] = b0.z; Bsb[kb + 3][r] = b0.w;
    Bsb[kb + 0][r + 32] = b1.x; Bsb[kb + 1][r + 32] = b1.y; Bsb[kb + 2][r + 32] = b1.z; Bsb[kb + 3][r + 32] = b1.w;
    __syncthreads();
#pragma unroll
    for (int kk = 0; kk < 32; ++kk) {
      float4 av = *(const float4*)&Asb[kk][ty * 4];
      float4 bv = *(const float4*)&Bsb[kk][tx * 4];
      float aa[4] = {av.x, av.y, av.z, av.w};
      float bw[4] = {bv.x, bv.y, bv.z, bv.w};
#pragma unroll
      for (int i = 0; i < 4; ++i)
#pragma unroll
        for (int j = 0; j < 4; ++j) acc[i][j] += aa[i] * bw[j];
    }
  }
#pragma unroll
  for (int i = 0; i < 4; ++i)
#pragma unroll
    for (int j = 0; j < 4; ++j)
      C[(size_t)(m0 + ty * 4 + i) * 512 + n0 + tx * 4 + j] = acc[i][j];
}

// ---------------- fp16 MFMA GEMM (X_ih): C = A(M,K) @ W(N,K)^T -> fp16 ----------------
__global__ __launch_bounds__(256) void mfma_gemm_f16out(
    const unsigned short* __restrict__ A, const unsigned short* __restrict__ W,
    unsigned short* __restrict__ C, int K, int N) {
  __shared__ unsigned short As[128][40];
  __shared__ unsigned short Bs[128][40];
  int tid = threadIdx.x;
  int m0 = blockIdx.y << 7, n0 = blockIdx.x << 7;
  int wid = tid >> 6, lane = tid & 63;
  int wm = (wid >> 1) << 6, wn = (wid & 1) << 6;
  int lr = lane & 15, lk = (lane >> 4) << 3;
  f32x4 acc[4][4] = {};
  for (int k0 = 0; k0 < K; k0 += 32) {
    __syncthreads();
#pragma unroll
    for (int q = 0; q < 2; ++q) {
      int idx = tid + (q << 8);
      int row = idx >> 2, k8 = (idx & 3) << 3;
      *(s16x8*)&As[row][k8] = *(const s16x8*)(A + (size_t)(m0 + row) * K + k0 + k8);
      *(s16x8*)&Bs[row][k8] = *(const s16x8*)(W + (size_t)(n0 + row) * K + k0 + k8);
    }
    __syncthreads();
#pragma unroll
    for (int i = 0; i < 4; ++i)
#pragma unroll
      for (int j = 0; j < 4; ++j) {
        f16x8 af = *(const f16x8*)&As[wm + (i << 4) + lr][lk];
        f16x8 bw = *(const f16x8*)&Bs[wn + (j << 4) + lr][lk];
        acc[i][j] = __builtin_amdgcn_mfma_f32_16x16x32_f16(af, bw, acc[i][j], 0, 0, 0);
      }
  }
#pragma unroll
  for (int i = 0; i < 4; ++i) {
    int row = m0 + wm + (i << 4) + ((lane >> 4) << 2);
#pragma unroll
    for (int j = 0; j < 4; ++j) {
      int col = n0 + wn + (j << 4) + lr;
#pragma unroll
      for (int r = 0; r < 4; ++r) {
        _Float16 h = (_Float16)acc[i][j][r];
        unsigned short b; __builtin_memcpy(&b, &h, 2);
        C[(size_t)(row + r) * N + col] = b;
      }
    }
  }
}

// ---------------- persistent scan: 256 blocks x 512 threads, fence-free ----------------
// Blocks: 0..63 r (64 cols K1024), 64..127 s, 128..255 m (32 cols K2048).
// Wave w (0..7): weight slice = old wpak (oblk = seg_base + 2*nb + (w>>2), owv = w&3).
// h/si state in uHL parity buffers: packed (hi fp16 | lo fp16 << 16) per element.
__global__ __launch_bounds__(512, 2) void scan_persistent(
    unsigned* __restrict__ uHL0, unsigned* __restrict__ uHL1,
    float* __restrict__ cbuf, float* __restrict__ stack, int* __restrict__ depth,
    float* __restrict__ slabG, unsigned short* __restrict__ outsb, int* __restrict__ bar,
    const unsigned short* __restrict__ wpak, const unsigned short* __restrict__ X_ihH,
    const float* __restrict__ Xz, const float* __restrict__ piW1,
    const float* __restrict__ rb, const float* __restrict__ sbv, const float* __restrict__ mb,
    const float* __restrict__ pib1, const float* __restrict__ pilng,
    const float* __restrict__ pilnb, const float* __restrict__ piW2,
    const float* __restrict__ pib2) {
  __shared__ __align__(16) _Float16 AsH[32 * 136];
  __shared__ __align__(16) _Float16 AsL[32 * 136];
  __shared__ float Cred[3072];
  __shared__ float zredA[512];
  __shared__ float zredB[512];
  __shared__ float s8[8];
  __shared__ int sact[2];

  int blk = blockIdx.x, tid = threadIdx.x;
  int ep_local = 0;
  int seg = (blk < 64) ? 0 : ((blk < 128) ? 1 : 2);
  int nb = (seg == 0) ? blk : ((seg == 1) ? blk - 64 : blk - 128);
  int gc0 = (seg == 0) ? nb * 64 : ((seg == 1) ? 4096 + nb * 64 : 8192 + nb * 32);
  int w = tid >> 6, lane = tid & 63;
  int lr = lane & 15, lk = lane >> 4;
  int kh = (seg < 2) ? (w & 1) : (w & 3);
  int fc = (seg < 2) ? (w >> 1) : (w >> 2);
  int gcol = gc0 + fc * 16 + lr;
  int NCH = (seg < 2) ? 8 : 16;
  int rr = tid >> 4, k8 = (tid & 15) << 3;   // staging: 8 elems/thread/chunk

  // ---- load W hi/lo fragments into registers (once; R8-proven layout) ----
  f16x8 whi[16], wlo[16];
  {
    int oblk = ((seg == 0) ? 0 : ((seg == 1) ? 128 : 256)) + 2 * nb + (w >> 2);
    int owv = w & 3;
    const f16x8* wp = (const f16x8*)wpak + (((size_t)(oblk * 4 + owv)) << 11) + lane;
#pragma unroll
    for (int f = 0; f < 16; ++f) {
      whi[f] = wp[(size_t)f * 64];
      wlo[f] = wp[(size_t)(f + 16) * 64];
    }
  }

  for (int t = 0; t < 128; ++t) {
    const unsigned* uP = (t & 1) ? uHL1 : uHL0;
    unsigned*       uN = (t & 1) ? uHL0 : uHL1;

    // ---------- z cols 2*blk, 2*blk+1: fp32 dot of (hi+lo)h with piW1 ----------
    {
      int r = tid >> 4, kq = tid & 15;     // 64 elems each
      const unsigned* up = uP + r * 2048 + kq * 64;
      const float* wA = piW1 + (size_t)(2 * blk) * 1536 + kq * 64;
      const float* wB = wA + 1536;
      float za = 0.0f, zb = 0.0f;
#pragma unroll
      for (int j = 0; j < 16; ++j) {
        unsigned long long c0 = ldU64((const unsigned long long*)(up + j * 4));
        unsigned long long c1 = ldU64((const unsigned long long*)(up + j * 4 + 2));
        float a0 = unpackHL((unsigned)c0), a1 = unpackHL((unsigned)(c0 >> 32));
        float a2 = unpackHL((unsigned)c1), a3 = unpackHL((unsigned)(c1 >> 32));
        float4 wa = *(const float4*)(wA + j * 4);
        float4 wb = *(const float4*)(wB + j * 4);
        za += a0 * wa.x + a1 * wa.y + a2 * wa.z + a3 * wa.w;
        zb += a0 * wb.x + a1 * wb.y + a2 * wb.z + a3 * wb.w;
      }
      zredA[tid] = za; zredB[tid] = zb;
    }
    __syncthreads();
    if (tid < 64) {
      int r = tid & 31, cB = tid >> 5;
      const float* zr = cB ? zredB : zredA;
      float z = 0.0f;
#pragma unroll
      for (int j = 0; j < 16; ++j) z += zr[r * 16 + j];
      stGf(&slabG[(size_t)r * 12800 + 12288 + 2 * blk + cB], z);
    }

    // ---------- MFMA GEMM: stage u chunk (128 elems wide) -> hi/lo LDS -> MFMA ----------
    f32x4 acc0 = {0.f, 0.f, 0.f, 0.f}, acc1 = {0.f, 0.f, 0.f, 0.f};
    unsigned long long c0, c1, c2, c3, n0, n1, n2, n3;
#define LDU(X0, X1, X2, X3, CH) { \
      const unsigned long long* p_ = (const unsigned long long*)(uP + rr * 2048 + ((CH) << 7) + k8); \
      X0 = ldU64(p_); X1 = ldU64(p_ + 1); X2 = ldU64(p_ + 2); X3 = ldU64(p_ + 3); }
    LDU(c0, c1, c2, c3, 0);
    LDU(n0, n1, n2, n3, 1);
#pragma unroll
    for (int ch = 0; ch < 16; ++ch) {
      if (ch >= NCH) break;
      __syncthreads();
      {
        unsigned a0 = (unsigned)c0, a1 = (unsigned)(c0 >> 32);
        unsigned a2 = (unsigned)c1, a3 = (unsigned)(c1 >> 32);
        unsigned a4 = (unsigned)c2, a5 = (unsigned)(c2 >> 32);
        unsigned a6 = (unsigned)c3, a7 = (unsigned)(c3 >> 32);
        uint4 hp, lp;
        hp.x = (a0 & 0xffffu) | (a1 << 16);  hp.y = (a2 & 0xffffu) | (a3 << 16);
        hp.z = (a4 & 0xffffu) | (a5 << 16);  hp.w = (a6 & 0xffffu) | (a7 << 16);
        lp.x = (a0 >> 16) | (a1 & 0xffff0000u);  lp.y = (a2 >> 16) | (a3 & 0xffff0000u);
        lp.z = (a4 >> 16) | (a5 & 0xffff0000u);  lp.w = (a6 >> 16) | (a7 & 0xffff0000u);
        *(uint4*)&AsH[rr * 136 + k8] = hp;
        *(uint4*)&AsL[rr * 136 + k8] = lp;
      }
      c0 = n0; c1 = n1; c2 = n2; c3 = n3;
      if (ch + 2 < NCH) LDU(n0, n1, n2, n3, ch + 2);
      __syncthreads();
      if ((ch >> 2) == kh) {
#pragma unroll
        for (int tt = 0; tt < 4; ++tt) {
          int fl = ((ch & 3) << 2) | tt;
          int ko = (tt << 5) + (lk << 3);
          f16x8 Ah0 = *(const f16x8*)&AsH[lr * 136 + ko];
          f16x8 Al0 = *(const f16x8*)&AsL[lr * 136 + ko];
          f16x8 Ah1 = *(const f16x8*)&AsH[(16 + lr) * 136 + ko];
          f16x8 Al1 = *(const f16x8*)&AsL[(16 + lr) * 136 + ko];
          acc0 = __builtin_amdgcn_mfma_f32_16x16x32_f16(Ah0, whi[fl], acc0, 0, 0, 0);
          acc0 = __builtin_amdgcn_mfma_f32_16x16x32_f16(Al0, whi[fl], acc0, 0, 0, 0);
          acc0 = __builtin_amdgcn_mfma_f32_16x16x32_f16(Ah0, wlo[fl], acc0, 0, 0, 0);
          acc1 = __builtin_amdgcn_mfma_f32_16x16x32_f16(Ah1, whi[fl], acc1, 0, 0, 0);
          acc1 = __builtin_amdgcn_mfma_f32_16x16x32_f16(Al1, whi[fl], acc1, 0, 0, 0);
          acc1 = __builtin_amdgcn_mfma_f32_16x16x32_f16(Ah1, wlo[fl], acc1, 0, 0, 0);
        }
      }
    }
#undef LDU

    // ---------- combine K-split partials, write slabG (sc1) ----------
    __syncthreads();
    int rq = lk << 2;
    if (seg < 2) {
      if (kh == 1) {
#pragma unroll
        for (int q = 0; q < 4; ++q) {
          Cred[fc * 512 + (rq + q) * 16 + lr] = acc0[q];
          Cred[fc * 512 + (16 + rq + q) * 16 + lr] = acc1[q];
        }
      }
      __syncthreads();
      if (kh == 0) {
#pragma unroll
        for (int q = 0; q < 4; ++q) {
          stGf(&slabG[(size_t)(rq + q) * 12800 + gcol],
               acc0[q] + Cred[fc * 512 + (rq + q) * 16 + lr]);
          stGf(&slabG[(size_t)(16 + rq + q) * 12800 + gcol],
               acc1[q] + Cred[fc * 512 + (16 + rq + q) * 16 + lr]);
        }
      }
    } else {
      if (kh > 0) {
#pragma unroll
        for (int q = 0; q < 4; ++q) {
          Cred[(fc * 3 + kh - 1) * 512 + (rq + q) * 16 + lr] = acc0[q];
          Cred[(fc * 3 + kh - 1) * 512 + (16 + rq + q) * 16 + lr] = acc1[q];
        }
      }
      __syncthreads();
      if (kh == 0) {
#pragma unroll
        for (int q = 0; q < 4; ++q) {
          int i0 = (rq + q) * 16 + lr, i1 = (16 + rq + q) * 16 + lr;
          float v0 = acc0[q] + Cred[fc * 1536 + i0] + Cred[fc * 1536 + 512 + i0]
                     + Cred[fc * 1536 + 1024 + i0];
          float v1 = acc1[q] + Cred[fc * 1536 + i1] + Cred[fc * 1536 + 512 + i1]
                     + Cred[fc * 1536 + 1024 + i1];
          stGf(&slabG[(size_t)(rq + q) * 12800 + gcol], v0);
          stGf(&slabG[(size_t)(16 + rq + q) * 12800 + gcol], v1);
        }
      }
    }
    gsync(bar, &ep_local);

    // ---------- pointwise (blocks 0..63: b = blk>>1, k-half = blk&1) ----------
    if (blk < 64) {
      int b = blk >> 1, kh2 = blk & 1;
      int k = (kh2 << 9) + tid;
      size_t xrow = (size_t)t * 32 + b;
      const unsigned short* Xg = X_ihH + xrow * 12288;
      const float* Xzr = Xz + xrow * 512;
      float* Gb = slabG + (size_t)b * 12800;
      float zc = ldGf(&Gb[12288 + tid]) + Xzr[tid] + pib1[tid];
      float mu = bsum512(zc, s8, tid) * (1.0f / 512.0f);
      float d = zc - mu;
      float var = bsum512(d * d, s8, tid) * (1.0f / 512.0f);
      float rstd = rsqrtf(var + 1e-5f);
      float l = fmaxf(d * rstd * pilng[tid] + pilnb[tid], 0.0f);
      float lg[3];
#pragma unroll
      for (int kk = 0; kk < 3; ++kk)
        lg[kk] = bsum512(l * piW2[kk * 512 + tid], s8, tid);
      if (tid == 0) {
        int dcur = ldGi(&depth[(t & 1) * 32 + b]);
#pragma unroll
        for (int kk = 0; kk < 3; ++kk) lg[kk] += pib2[kk];
        if (dcur >= 2) lg[0] = -INFINITY;
        if (dcur == 0) lg[2] = -INFINITY;
        uint32_t kt0, kt1;
        tf2x32(0u, 42u, 0u, (uint32_t)t, &kt0, &kt1);
#pragma unroll
        for (int kk = 0; kk < 3; ++kk) {
          uint32_t o0, o1;
          tf2x32(kt0, kt1, 0u, (uint32_t)(3 * b + kk), &o0, &o1);
          lg[kk] += gumbel_from_bits(o0 ^ o1);
        }
        int a = 0; float best = lg[0];
        if (lg[1] > best) { best = lg[1]; a = 1; }
        if (lg[2] > best) { a = 2; }
        sact[0] = a; sact[1] = dcur;
      }
      __syncthreads();
      int a = sact[0], dcur = sact[1];
      int dnew = dcur + ((a == 0) ? 1 : 0) - ((a == 2) ? 1 : 0);
#define GV(c) (ldGf(&Gb[(c)]) + f16tof(Xg[(c)]))
      float ir = GV(k)        + rb[k],        fr_ = GV(1024 + k)  + rb[1024 + k];
      float gr = GV(2048 + k) + rb[2048 + k], orr = GV(3072 + k)  + rb[3072 + k];
      float is = GV(4096 + k) + sbv[k],       fs  = GV(5120 + k)  + sbv[1024 + k];
      float gs = GV(6144 + k) + sbv[2048 + k], os = GV(7168 + k)  + sbv[3072 + k];
      float im = GV(8192 + k) + mb[k],        fm  = GV(9216 + k)  + mb[1024 + k];
      float gm = GV(10240 + k) + mb[2048 + k], om = GV(11264 + k) + mb[3072 + k];
#undef GV
      float cold = cbuf[b * 1024 + k];
      float crn = sigf(fr_) * cold + sigf(ir) * tanhf(gr); float hrn = sigf(orr) * tanhf(crn);
      float csn = sigf(fs)  * cold + sigf(is) * tanhf(gs); float hsn = sigf(os)  * tanhf(csn);
      float cmn = sigf(fm)  * cold + sigf(im) * tanhf(gm); float hmn = sigf(om)  * tanhf(cmn);
      float hn = (a == 0) ? hsn : ((a == 1) ? hrn : hmn);
      float cn = (a == 0) ? csn : ((a == 1) ? crn : cmn);
      cbuf[b * 1024 + k] = cn;
      outsb[(size_t)t * 32768 + b * 1024 + k] = f2bf(hn);
      float si;
      if (a == 0) { stack[(size_t)(b * 2 + dcur) * 1024 + k] = hsn; si = hsn; }
      else si = (dnew > 0) ? stack[(size_t)(b * 2 + (dnew - 1)) * 1024 + k] : 0.0f;
      stGu(&uN[(size_t)b * 2048 + k], packHL(hn));
      stGu(&uN[(size_t)b * 2048 + 1024 + k], packHL(si));
      if (kh2 == 0 && tid == 0) stGi(&depth[((t + 1) & 1) * 32 + b], dnew);
    }
    gsync(bar, &ep_local);
  }
}

// ---------------- bf16 MFMA GEMM (pred/dec): C = A(M,K)@W(N,K)^T + bias [tanh-BN] ----------------
template <int EPI>   // 0: fp32 + bias; 1: tanh-BN -> bf16
__global__ __launch_bounds__(256) void mfma_gemm(
    const unsigned short* __restrict__ A, const unsigned short* __restrict__ W,
    const float* __restrict__ bias, int K, int N,
    float* __restrict__ Cf, unsigned short* __restrict__ Cb,
    const float* __restrict__ g, const float* __restrict__ bb, float invS) {
  __shared__ unsigned short As[128][40];
  __shared__ unsigned short Bs[128][40];
  int tid = threadIdx.x;
  int m0 = blockIdx.y << 7, n0 = blockIdx.x << 7;
  int wid = tid >> 6, lane = tid & 63;
  int wm = (wid >> 1) << 6, wn = (wid & 1) << 6;
  int lr = lane & 15, lk = (lane >> 4) << 3;
  f32x4 acc[4][4] = {};
  for (int k0 = 0; k0 < K; k0 += 32) {
    __syncthreads();
#pragma unroll
    for (int q = 0; q < 2; ++q) {
      int idx = tid + (q << 8);
      int row = idx >> 2, k8 = (idx & 3) << 3;
      *(s16x8*)&As[row][k8] = *(const s16x8*)(A + (size_t)(m0 + row) * K + k0 + k8);
      *(s16x8*)&Bs[row][k8] = *(const s16x8*)(W + (size_t)(n0 + row) * K + k0 + k8);
    }
    __syncthreads();
    s16x8 af[4], bw[4];
#pragma unroll
    for (int i = 0; i < 4; ++i) {
      af[i] = *(const s16x8*)&As[wm + (i << 4) + lr][lk];
      bw[i] = *(const s16x8*)&Bs[wn + (i << 4) + lr][lk];
    }
#pragma unroll
    for (int i = 0; i < 4; ++i)
#pragma unroll
      for (int j = 0; j < 4; ++j)
        acc[i][j] = __builtin_amdgcn_mfma_f32_16x16x32_bf16(af[i], bw[j], acc[i][j], 0, 0, 0);
  }
#pragma unroll
  for (int i = 0; i < 4; ++i) {
    int row = m0 + wm + (i << 4) + ((lane >> 4) << 2);
#pragma unroll
    for (int j = 0; j < 4; ++j) {
      int col = n0 + wn + (j << 4) + lr;
      float bv = bias[col];
#pragma unroll
      for (int r = 0; r < 4; ++r) {
        float v = acc[i][j][r] + bv;
        if (EPI) {
          v = tanhf(v * invS * g[col] + bb[col]);
          Cb[(size_t)(row + r) * N + col] = f2bf(v);
        } else {
          Cf[(size_t)(row + r) * N + col] = v;
        }
      }
    }
  }
}

// ---------------- launcher ----------------
extern "C" void kernel_launch(void* const* d_in, const int* in_sizes, int n_in,
                              void* d_out, int out_size, void* d_ws, size_t ws_size,
                              hipStream_t stream) {
  const int*   tokens = (const int*)d_in[0];
  const float* h0    = (const float*)d_in[1];
  const float* c0    = (const float*)d_in[2];
  const float* embW  = (const float*)d_in[3];
  const float* rWih  = (const float*)d_in[4];
  const float* rWhh  = (const float*)d_in[5];
  const float* rb    = (const float*)d_in[6];
  const float* sWih  = (const float*)d_in[7];
  const float* sWhh  = (const float*)d_in[8];
  const float* sbv   = (const float*)d_in[9];
  const float* mWih  = (const float*)d_in[10];
  const float* mWhh  = (const float*)d_in[11];
  const float* mb    = (const float*)d_in[12];
  const float* piW1  = (const float*)d_in[13];
  const float* pib1  = (const float*)d_in[14];
  const float* pilng = (const float*)d_in[15];
  const float* pilnb = (const float*)d_in[16];
  const float* piW2  = (const float*)d_in[17];
  const float* pib2  = (const float*)d_in[18];
  const float* predW = (const float*)d_in[19];
  const float* predb = (const float*)d_in[20];
  const float* bng   = (const float*)d_in[21];
  const float* bnb   = (const float*)d_in[22];
  const float* decW  = (const float*)d_in[23];
  const float* decb  = (const float*)d_in[24];
  float* out = (float*)d_out;
  float* ws  = (float*)d_ws;

  // float region
  float* emb   = ws;                          // 2,097,152
  unsigned* uHL0 = (unsigned*)(emb + 2097152);//    65,536
  unsigned* uHL1 = uHL0 + 65536;              //    65,536
  float* cbuf  = (float*)(uHL1 + 65536);      //    32,768
  float* stack = cbuf + 32768;                //    65,536
  float* slabG = stack + 65536;               //   409,600
  float* Xz    = slabG + 409600;              // 2,097,152
  // ushort region
  unsigned short* X_ihH  = (unsigned short*)(Xz + 2097152);     // 50,331,648
  unsigned short* wpak   = X_ihH + 50331648;                    // 33,554,432
  unsigned short* wcatH  = wpak + 33554432;                     //  6,291,456
  unsigned short* embH   = wcatH + 6291456;                     //  2,097,152
  unsigned short* outsb  = embH + 2097152;                      //  4,194,304
  int* depth = (int*)(outsb + 4194304);                         // 64 ints
  int* bar   = depth + 64;                                      // 160 ints
  // post-scan aliases (wpak is dead after the scan)
  unsigned short* decWb  = wpak;                                // 16,384,000
  unsigned short* predWb = wpak + 16384000;                     //    524,288
  unsigned short* ytbf   = wpak + 16908288;                     //  2,097,152

  init_state<<<dim3(256), dim3(256), 0, stream>>>(h0, c0, uHL0, cbuf, stack, depth, bar);
  embed_kernel<<<dim3(4096), dim3(128), 0, stream>>>(tokens, embW, emb);
  to_f16<<<dim3(2048), dim3(256), 0, stream>>>(emb, embH, 524288);
  pack_wcat16<<<dim3(24576), dim3(256), 0, stream>>>(rWih, sWih, mWih, wcatH);
  pack_whilo<<<dim3(131072), dim3(256), 0, stream>>>(rWhh, sWhh, mWhh, mWih, wpak);

  // Xz = emb @ piW1[:,1024:1536]^T  (fp32, exact sampling path)
  xz_gemm<<<dim3(8, 64), dim3(256), 0, stream>>>(emb, piW1, Xz);
  // X_ih = embH @ wcatH^T  (4096 x 12288, fp16)
  mfma_gemm_f16out<<<dim3(96, 32), dim3(256), 0, stream>>>(embH, wcatH, X_ihH, 512, 12288);

  scan_persistent<<<dim3(NBLK), dim3(512), 0, stream>>>(
      uHL0, uHL1, cbuf, stack, depth, slabG, outsb, bar,
      wpak, X_ihH, Xz, piW1, rb, sbv, mb, pib1, pilng, pilnb, piW2, pib2);

  // pred/dec weights converted after the scan into the dead wpak region
  to_bf16<<<dim3(512), dim3(256), 0, stream>>>(predW, predWb, 131072);
  to_bf16<<<dim3(16000), dim3(256), 0, stream>>>(decW, decWb, 4096000);

  float invS = 1.0f / sqrtf(1.0f + 1e-5f);
  mfma_gemm<1><<<dim3(4, 32), dim3(256), 0, stream>>>(
      outsb, predWb, predb, 1024, 512, nullptr, ytbf, bng, bnb, invS);
  mfma_gemm<0><<<dim3(250, 32), dim3(256), 0, stream>>>(
      ytbf, decWb, decb, 512, 32000, out, nullptr, nullptr, nullptr, 0.0f);
  final_copy<<<dim3(128), dim3(256), 0, stream>>>(uHL0, cbuf, out);
}

// Round 10
// 10215.502 us; speedup vs baseline: 6.8060x; 1.0755x over previous
//
#include <hip/hip_runtime.h>
#include <hip/hip_bf16.h>
#include <stdint.h>
#include <math.h>

using s16x8 = __attribute__((ext_vector_type(8))) short;
using f16x8 = __attribute__((ext_vector_type(8))) _Float16;
using f32x4 = __attribute__((ext_vector_type(4))) float;

#define NBLK 256
#define GRP 32   // NBLK / 8 groups

// ---------------- agent-scope coherent access helpers ----------------
__device__ __forceinline__ float ldGf(const float* p) {
  unsigned v = __hip_atomic_load((const unsigned*)p, __ATOMIC_RELAXED, __HIP_MEMORY_SCOPE_AGENT);
  return __uint_as_float(v);
}
__device__ __forceinline__ void stGf(float* p, float x) {
  __hip_atomic_store((unsigned*)p, __float_as_uint(x), __ATOMIC_RELAXED, __HIP_MEMORY_SCOPE_AGENT);
}
__device__ __forceinline__ void stGu(unsigned* p, unsigned v) {
  __hip_atomic_store(p, v, __ATOMIC_RELAXED, __HIP_MEMORY_SCOPE_AGENT);
}
__device__ __forceinline__ unsigned long long ldU64(const unsigned long long* p) {
  return __hip_atomic_load(p, __ATOMIC_RELAXED, __HIP_MEMORY_SCOPE_AGENT);
}
__device__ __forceinline__ int ldGi(const int* p) {
  return __hip_atomic_load(p, __ATOMIC_RELAXED, __HIP_MEMORY_SCOPE_AGENT);
}
__device__ __forceinline__ void stGi(int* p, int v) {
  __hip_atomic_store(p, v, __ATOMIC_RELAXED, __HIP_MEMORY_SCOPE_AGENT);
}

// ---------------- hi/lo fp16 packing of fp32 ----------------
__device__ __forceinline__ unsigned packHL(float x) {
  _Float16 h = (_Float16)x;
  float r = x - (float)h;
  _Float16 l = (_Float16)r;
  unsigned short hb, lb;
  __builtin_memcpy(&hb, &h, 2); __builtin_memcpy(&lb, &l, 2);
  return (unsigned)hb | ((unsigned)lb << 16);
}
__device__ __forceinline__ float unpackHL(unsigned v) {
  unsigned short hb = (unsigned short)(v & 0xffffu), lb = (unsigned short)(v >> 16);
  _Float16 h, l;
  __builtin_memcpy(&h, &hb, 2); __builtin_memcpy(&l, &lb, 2);
  return (float)h + (float)l;
}

// ---------------- threefry2x32 (JAX-exact, partitionable) ----------------
__device__ __forceinline__ void tf2x32(uint32_t k0, uint32_t k1,
                                       uint32_t x0, uint32_t x1,
                                       uint32_t* o0, uint32_t* o1) {
  uint32_t ks0 = k0, ks1 = k1, ks2 = k0 ^ k1 ^ 0x1BD11BDAu;
  x0 += ks0; x1 += ks1;
  const int R[8] = {13,15,26,6, 17,29,16,24};
#pragma unroll
  for (int g = 0; g < 5; ++g) {
    const int base = (g & 1) ? 4 : 0;
#pragma unroll
    for (int j = 0; j < 4; ++j) {
      int r = R[base + j];
      x0 += x1;
      x1 = (x1 << r) | (x1 >> (32 - r));
      x1 ^= x0;
    }
    switch (g) {
      case 0: x0 += ks1; x1 += ks2 + 1u; break;
      case 1: x0 += ks2; x1 += ks0 + 2u; break;
      case 2: x0 += ks0; x1 += ks1 + 3u; break;
      case 3: x0 += ks1; x1 += ks2 + 4u; break;
      case 4: x0 += ks2; x1 += ks0 + 5u; break;
    }
  }
  *o0 = x0; *o1 = x1;
}

__device__ __forceinline__ float gumbel_from_bits(uint32_t bits) {
  float u = __uint_as_float((bits >> 9) | 0x3f800000u) - 1.0f;
  if (u == 0.0f) u = 1.1754943508222875e-38f;  // finfo(f32).tiny
  return -logf(-logf(u));
}

__device__ __forceinline__ float sigf(float x) { return 1.0f / (1.0f + expf(-x)); }

__device__ __forceinline__ unsigned short f2bf(float f) {
  unsigned u = __float_as_uint(f);
  unsigned r = (u + 0x7fffu + ((u >> 16) & 1u)) >> 16;
  return (unsigned short)r;
}

__device__ __forceinline__ float f16tof(unsigned short v) {
  _Float16 h; __builtin_memcpy(&h, &v, 2); return (float)h;
}

// block reduction over 512 threads (8 waves)
__device__ __forceinline__ float bsum512(float v, volatile float* s8, int tid) {
#pragma unroll
  for (int o = 1; o < 64; o <<= 1) v += __shfl_xor(v, o, 64);
  __syncthreads();
  if ((tid & 63) == 0) s8[tid >> 6] = v;
  __syncthreads();
  float r = 0.0f;
#pragma unroll
  for (int j = 0; j < 8; ++j) r += s8[j];
  return r;
}

// Two-level grid barrier, fence-free (R9-proven): cross-block data moves via
// agent-scope relaxed atomics; __syncthreads drains vmcnt before arrival.
__device__ __forceinline__ void gsync(int* bar, int* ep_local) {
  __syncthreads();
  if (threadIdx.x == 0) {
    int ep = ++(*ep_local);
    int g = blockIdx.x & 7;
    int old = __hip_atomic_fetch_add(&bar[g * 16], 1, __ATOMIC_RELAXED, __HIP_MEMORY_SCOPE_AGENT);
    if (old == ep * GRP - 1) {
      int mo = __hip_atomic_fetch_add(&bar[128], 1, __ATOMIC_RELAXED, __HIP_MEMORY_SCOPE_AGENT);
      if (mo == ep * 8 - 1)
        __hip_atomic_store(&bar[144], ep, __ATOMIC_RELAXED, __HIP_MEMORY_SCOPE_AGENT);
    }
    while (__hip_atomic_load(&bar[144], __ATOMIC_RELAXED, __HIP_MEMORY_SCOPE_AGENT) < ep)
      __builtin_amdgcn_s_sleep(8);
  }
  __syncthreads();
}

// ---------------- init / embed / copy / convert / pack ----------------
__global__ void init_state(const float* __restrict__ h0, const float* __restrict__ c0,
                           unsigned* __restrict__ uHL0, float* __restrict__ cbuf,
                           float* __restrict__ stack, int* __restrict__ depth,
                           int* __restrict__ bar) {
  int i = blockIdx.x * blockDim.x + threadIdx.x;  // 65536
  if (i < 65536) {
    int b = i >> 11, k = i & 2047;
    float v = (k < 1024) ? h0[b * 1024 + k] : 0.0f;   // [h0 | si=0]
    uHL0[i] = packHL(v);
    stack[i] = 0.0f;
  }
  if (i < 32768) cbuf[i] = c0[i];
  if (i < 64) depth[i] = 0;
  if (i < 160) bar[i] = 0;
}

__global__ void embed_kernel(const int* __restrict__ toks, const float* __restrict__ embW,
                             float* __restrict__ emb) {
  int row = blockIdx.x;            // t*32+b
  int tid = threadIdx.x;           // 128 threads
  int tk = toks[row];
  float4 v = ((const float4*)(embW + (size_t)tk * 512))[tid];
  ((float4*)(emb + (size_t)row * 512))[tid] = v;
}

__global__ void final_copy(const unsigned* __restrict__ uHL0, const float* __restrict__ cbuf,
                           float* __restrict__ out) {
  int i = blockIdx.x * blockDim.x + threadIdx.x;  // 32768
  int b = i >> 10, k = i & 1023;
  out[131072000u + i] = unpackHL(uHL0[(size_t)b * 2048 + k]);
  out[131072000u + 32768u + i] = cbuf[i];
}

__global__ void to_bf16(const float* __restrict__ s, unsigned short* __restrict__ d, int n4) {
  int i = blockIdx.x * blockDim.x + threadIdx.x;
  if (i < n4) {
    float4 v = *(const float4*)(s + (size_t)i * 4);
    ushort4 o;
    o.x = f2bf(v.x); o.y = f2bf(v.y); o.z = f2bf(v.z); o.w = f2bf(v.w);
    *(ushort4*)(d + (size_t)i * 4) = o;
  }
}

__global__ void to_f16(const float* __restrict__ s, unsigned short* __restrict__ d, int n4) {
  int i = blockIdx.x * blockDim.x + threadIdx.x;
  if (i < n4) {
    float4 v = *(const float4*)(s + (size_t)i * 4);
    _Float16 h0_ = (_Float16)v.x, h1 = (_Float16)v.y, h2 = (_Float16)v.z, h3 = (_Float16)v.w;
    ushort4 o;
    __builtin_memcpy(&o.x, &h0_, 2); __builtin_memcpy(&o.y, &h1, 2);
    __builtin_memcpy(&o.z, &h2, 2); __builtin_memcpy(&o.w, &h3, 2);
    *(ushort4*)(d + (size_t)i * 4) = o;
  }
}

// Wcat fp16 (12288 x 512): rows 0..4095 rWih, 4096..8191 sWih, 8192..12287 mWih[:, :512]
__global__ void pack_wcat16(const float* __restrict__ rWih, const float* __restrict__ sWih,
                            const float* __restrict__ mWih, unsigned short* __restrict__ wcat) {
  int idx = blockIdx.x * 256 + threadIdx.x;   // 6,291,456
  if (idx >= 12288 * 512) return;
  int c = idx >> 9, k = idx & 511;
  float v;
  if (c < 4096)      v = rWih[(size_t)c * 512 + k];
  else if (c < 8192) v = sWih[(size_t)(c - 4096) * 512 + k];
  else               v = mWih[(size_t)(c - 8192) * 1536 + k];
  _Float16 h = (_Float16)v;
  unsigned short b; __builtin_memcpy(&b, &h, 2);
  wcat[idx] = b;
}

// wpak NEW layout for 256-block scan: idx = (((blk*8 + w)*32 + f)*64 + lane)*8 + e
// wave (blk, w): ct = w&3 (16-col tile), kh = w>>2 (512-K half of the block's K range).
// frag f<16 = hi plane, f>=16 = lo plane; within frag: k_loc = (f&15)*32 + (lane>>4)*8 + e,
// col = coltile_base + (lane&15).
// blk<64: r (cols blk*64+ct*16), W = rWhh[col][kh*512+k_loc]
// blk<128: s. blk<192: m h-half (mWhh). blk>=192: m si-half (mWih[col][512 + kh*512+k_loc]).
__global__ void pack_whilo(const float* __restrict__ rWhh, const float* __restrict__ sWhh,
                           const float* __restrict__ mWhh, const float* __restrict__ mWih,
                           unsigned short* __restrict__ wpak) {
  int idx = blockIdx.x * 256 + threadIdx.x;  // 33,554,432
  int e = idx & 7, lane = (idx >> 3) & 63, f = (idx >> 9) & 31,
      w = (idx >> 14) & 7, blk = idx >> 17;
  int lr = lane & 15, lk = lane >> 4;
  int hilo = f >> 4, fk = f & 15;
  int ct = w & 3, kh = w >> 2;
  int k = (kh << 9) + (fk << 5) + (lk << 3) + e;   // 0..1023
  float v;
  if (blk < 64) {
    int col = blk * 64 + ct * 16 + lr;           v = rWhh[(size_t)col * 1024 + k];
  } else if (blk < 128) {
    int col = (blk - 64) * 64 + ct * 16 + lr;    v = sWhh[(size_t)col * 1024 + k];
  } else if (blk < 192) {
    int col = (blk - 128) * 64 + ct * 16 + lr;   v = mWhh[(size_t)col * 1024 + k];
  } else {
    int col = (blk - 192) * 64 + ct * 16 + lr;   v = mWih[(size_t)col * 1536 + 512 + k];
  }
  _Float16 hv = (_Float16)v;
  _Float16 ov = hilo ? (_Float16)(v - (float)hv) : hv;
  unsigned short b; __builtin_memcpy(&b, &ov, 2);
  wpak[idx] = b;
}

// ---------------- X_z fp32 GEMM: Xz = emb(4096x512) @ piW1[:,1024:1536]^T ----------------
__global__ __launch_bounds__(256) void xz_gemm(const float* __restrict__ A,
                                               const float* __restrict__ W,
                                               float* __restrict__ C) {
  __shared__ float Asb[32][68];
  __shared__ float Bsb[32][68];
  int tid = threadIdx.x;
  int tx = tid & 15, ty = tid >> 4;
  int m0 = blockIdx.y * 64, n0 = blockIdx.x * 64;
  int r = tid >> 3, kb = (tid & 7) * 4;
  float acc[4][4] = {};
  for (int k0 = 0; k0 < 512; k0 += 32) {
    __syncthreads();
    float4 a0 = *(const float4*)(A + (size_t)(m0 + r) * 512 + k0 + kb);
    float4 a1 = *(const float4*)(A + (size_t)(m0 + r + 32) * 512 + k0 + kb);
    float4 b0 = *(const float4*)(W + (size_t)(n0 + r) * 1536 + 1024 + k0 + kb);
    float4 b1 = *(const float4*)(W + (size_t)(n0 + r + 32) * 1536 + 1024 + k0 + kb);
    Asb[kb + 0][r] = a0.x; Asb[kb + 1][r] = a0.y; Asb[kb + 2][r] = a0.z; Asb[kb + 3][r] = a0.w;
    Asb[kb + 0][r + 32] = a1.x; Asb[kb + 1][r + 32] = a1.y; Asb[kb + 2][r + 32] = a1.z; Asb[kb + 3][r + 32] = a1.w;
    Bsb[kb + 0][r] = b0.x; Bsb[kb + 1][r] = b0.y; Bsb[kb + 2][r] = b0.z; Bsb[kb + 3][r] = b0.w;
    Bsb[kb + 0][r + 32] = b1.x; Bsb[kb + 1][r + 32] = b1.y; Bsb[kb + 2][r + 32] = b1.z; Bsb[kb + 3][r + 32] = b1.w;
    __syncthreads();
#pragma unroll
    for (int kk = 0; kk < 32; ++kk) {
      float4 av = *(const float4*)&Asb[kk][ty * 4];
      float4 bv = *(const float4*)&Bsb[kk][tx * 4];
      float aa[4] = {av.x, av.y, av.z, av.w};
      float bw[4] = {bv.x, bv.y, bv.z, bv.w};
#pragma unroll
      for (int i = 0; i < 4; ++i)
#pragma unroll
        for (int j = 0; j < 4; ++j) acc[i][j] += aa[i] * bw[j];
    }
  }
#pragma unroll
  for (int i = 0; i < 4; ++i)
#pragma unroll
    for (int j = 0; j < 4; ++j)
      C[(size_t)(m0 + ty * 4 + i) * 512 + n0 + tx * 4 + j] = acc[i][j];
}

// ---------------- fp16 MFMA GEMM (X_ih): C = A(M,K) @ W(N,K)^T -> fp16 ----------------
__global__ __launch_bounds__(256) void mfma_gemm_f16out(
    const unsigned short* __restrict__ A, const unsigned short* __restrict__ W,
    unsigned short* __restrict__ C, int K, int N) {
  __shared__ unsigned short As[128][40];
  __shared__ unsigned short Bs[128][40];
  int tid = threadIdx.x;
  int m0 = blockIdx.y << 7, n0 = blockIdx.x << 7;
  int wid = tid >> 6, lane = tid & 63;
  int wm = (wid >> 1) << 6, wn = (wid & 1) << 6;
  int lr = lane & 15, lk = (lane >> 4) << 3;
  f32x4 acc[4][4] = {};
  for (int k0 = 0; k0 < K; k0 += 32) {
    __syncthreads();
#pragma unroll
    for (int q = 0; q < 2; ++q) {
      int idx = tid + (q << 8);
      int row = idx >> 2, k8 = (idx & 3) << 3;
      *(s16x8*)&As[row][k8] = *(const s16x8*)(A + (size_t)(m0 + row) * K + k0 + k8);
      *(s16x8*)&Bs[row][k8] = *(const s16x8*)(W + (size_t)(n0 + row) * K + k0 + k8);
    }
    __syncthreads();
#pragma unroll
    for (int i = 0; i < 4; ++i)
#pragma unroll
      for (int j = 0; j < 4; ++j) {
        f16x8 af = *(const f16x8*)&As[wm + (i << 4) + lr][lk];
        f16x8 bw = *(const f16x8*)&Bs[wn + (j << 4) + lr][lk];
        acc[i][j] = __builtin_amdgcn_mfma_f32_16x16x32_f16(af, bw, acc[i][j], 0, 0, 0);
      }
  }
#pragma unroll
  for (int i = 0; i < 4; ++i) {
    int row = m0 + wm + (i << 4) + ((lane >> 4) << 2);
#pragma unroll
    for (int j = 0; j < 4; ++j) {
      int col = n0 + wn + (j << 4) + lr;
#pragma unroll
      for (int r = 0; r < 4; ++r) {
        _Float16 h = (_Float16)acc[i][j][r];
        unsigned short b; __builtin_memcpy(&b, &h, 2);
        C[(size_t)(row + r) * N + col] = b;
      }
    }
  }
}

// ---------------- persistent scan: 256 blocks x 512 threads, 1 block/CU ----------------
// blk<64: r (64 cols, K1024/h). blk<128: s. blk<192: m h-half. blk>=192: m si-half
// (partials to slabG2). Wave w: ct=w&3 (16 cols), kh=w>>2 (512-K window).
// Weights register-resident (128 VGPR/wave); 256 VGPR budget via waves_per_eu(2,2).
__global__ __launch_bounds__(512)
__attribute__((amdgpu_waves_per_eu(2, 2)))
void scan_persistent(
    unsigned* __restrict__ uHL0, unsigned* __restrict__ uHL1,
    float* __restrict__ cbuf, float* __restrict__ stack, int* __restrict__ depth,
    float* __restrict__ slabG, float* __restrict__ slabG2,
    unsigned short* __restrict__ outsb, int* __restrict__ bar,
    const unsigned short* __restrict__ wpak, const unsigned short* __restrict__ X_ihH,
    const float* __restrict__ Xz, const float* __restrict__ piW1,
    const float* __restrict__ rb, const float* __restrict__ sbv, const float* __restrict__ mb,
    const float* __restrict__ pib1, const float* __restrict__ pilng,
    const float* __restrict__ pilnb, const float* __restrict__ piW2,
    const float* __restrict__ pib2) {
  __shared__ __align__(16) _Float16 AsH[32 * 520];
  __shared__ __align__(16) _Float16 AsL[32 * 520];
  __shared__ float Cred[2048];
  __shared__ float zredC[2048];
  __shared__ float s8[8];
  __shared__ int sact[2];

  int blk = blockIdx.x, tid = threadIdx.x;
  int ep_local = 0;
  int w = tid >> 6, lane = tid & 63;
  int lr = lane & 15, lk = lane >> 4;
  int ct = w & 3, kh = w >> 2;
  int seg = (blk < 64) ? 0 : (blk < 128) ? 1 : (blk < 192) ? 2 : 3;
  int nb = blk - ((seg == 0) ? 0 : (seg == 1) ? 64 : (seg == 2) ? 128 : 192);
  int colbase = (seg == 0) ? nb * 64 : (seg == 1) ? 4096 + nb * 64 : 8192 + nb * 64;
  int kbase_u = (seg == 3) ? 1024 : 0;
  int rr = tid >> 4, kw = tid & 15;
  int rq = lk << 2;

  // ---- load W hi/lo fragments into registers (once) ----
  f16x8 whi[16], wlo[16];
  {
    const f16x8* wp = (const f16x8*)(wpak + (((size_t)(blk * 8 + w)) << 14)) + lane;
#pragma unroll
    for (int f = 0; f < 16; ++f) {
      whi[f] = wp[(size_t)f * 64];
      wlo[f] = wp[(size_t)(f + 16) * 64];
    }
  }

  for (int t = 0; t < 128; ++t) {
    const unsigned* uP = (t & 1) ? uHL1 : uHL0;
    unsigned* uN = (t & 1) ? uHL0 : uHL1;

    f32x4 acc0 = {0.f, 0.f, 0.f, 0.f}, acc1 = {0.f, 0.f, 0.f, 0.f};
    float za0 = 0.f, za1 = 0.f, za2 = 0.f, za3 = 0.f;

#pragma unroll
    for (int win = 0; win < 2; ++win) {
      // ---- issue 16x8B sc loads (128 B/thread in flight) ----
      unsigned long long d[16];
      {
        const unsigned long long* up =
            (const unsigned long long*)(uP + (size_t)rr * 2048 + kbase_u + win * 512 + kw * 32);
#pragma unroll
        for (int j = 0; j < 16; ++j) d[j] = ldU64(up + j);
      }
      // ---- z partials straight from registers (blocks 0..127 own 4 z-cols) ----
      if (seg < 2) {
        const float* p0 = piW1 + (size_t)(4 * blk) * 1536 + win * 512 + kw * 32;
#pragma unroll
        for (int j = 0; j < 16; ++j) {
          float e0 = unpackHL((unsigned)d[j]);
          float e1 = unpackHL((unsigned)(d[j] >> 32));
          int kk = 2 * j;
          za0 += e0 * p0[kk]        + e1 * p0[kk + 1];
          za1 += e0 * p0[1536 + kk] + e1 * p0[1537 + kk];
          za2 += e0 * p0[3072 + kk] + e1 * p0[3073 + kk];
          za3 += e0 * p0[4608 + kk] + e1 * p0[4609 + kk];
        }
      }
      __syncthreads();   // previous window's LDS fully consumed
      // ---- unpack hi/lo planes to LDS ----
      {
        unsigned hi[16], lo[16];
#pragma unroll
        for (int j = 0; j < 16; ++j) {
          unsigned a0 = (unsigned)d[j], a1 = (unsigned)(d[j] >> 32);
          hi[j] = (a0 & 0xffffu) | (a1 << 16);
          lo[j] = (a0 >> 16) | (a1 & 0xffff0000u);
        }
        _Float16* hp = &AsH[rr * 520 + kw * 32];
        _Float16* lp = &AsL[rr * 520 + kw * 32];
#pragma unroll
        for (int q = 0; q < 4; ++q) {
          uint4 hv = {hi[4 * q], hi[4 * q + 1], hi[4 * q + 2], hi[4 * q + 3]};
          uint4 lv = {lo[4 * q], lo[4 * q + 1], lo[4 * q + 2], lo[4 * q + 3]};
          *(uint4*)(hp + q * 8) = hv;
          *(uint4*)(lp + q * 8) = lv;
        }
      }
      __syncthreads();
      // ---- MFMA: wave consumes its matching 512-K window ----
      if (win == kh) {
#pragma unroll
        for (int fl = 0; fl < 16; ++fl) {
          int ko = fl * 32 + lk * 8;
          f16x8 Ah0 = *(const f16x8*)&AsH[lr * 520 + ko];
          f16x8 Al0 = *(const f16x8*)&AsL[lr * 520 + ko];
          f16x8 Ah1 = *(const f16x8*)&AsH[(16 + lr) * 520 + ko];
          f16x8 Al1 = *(const f16x8*)&AsL[(16 + lr) * 520 + ko];
          acc0 = __builtin_amdgcn_mfma_f32_16x16x32_f16(Ah0, whi[fl], acc0, 0, 0, 0);
          acc0 = __builtin_amdgcn_mfma_f32_16x16x32_f16(Al0, whi[fl], acc0, 0, 0, 0);
          acc0 = __builtin_amdgcn_mfma_f32_16x16x32_f16(Ah0, wlo[fl], acc0, 0, 0, 0);
          acc1 = __builtin_amdgcn_mfma_f32_16x16x32_f16(Ah1, whi[fl], acc1, 0, 0, 0);
          acc1 = __builtin_amdgcn_mfma_f32_16x16x32_f16(Al1, whi[fl], acc1, 0, 0, 0);
          acc1 = __builtin_amdgcn_mfma_f32_16x16x32_f16(Ah1, wlo[fl], acc1, 0, 0, 0);
        }
      }
    }

    // ---- combine K-halves (kh pair) via Cred, write G planes (sc) ----
    __syncthreads();
    if (kh == 1) {
#pragma unroll
      for (int q = 0; q < 4; ++q) {
        Cred[ct * 512 + (rq + q) * 16 + lr] = acc0[q];
        Cred[ct * 512 + (16 + rq + q) * 16 + lr] = acc1[q];
      }
    }
    __syncthreads();
    if (kh == 0) {
      if (seg < 3) {
#pragma unroll
        for (int q = 0; q < 4; ++q) {
          stGf(&slabG[(size_t)(rq + q) * 12800 + colbase + ct * 16 + lr],
               acc0[q] + Cred[ct * 512 + (rq + q) * 16 + lr]);
          stGf(&slabG[(size_t)(16 + rq + q) * 12800 + colbase + ct * 16 + lr],
               acc1[q] + Cred[ct * 512 + (16 + rq + q) * 16 + lr]);
        }
      } else {
        int c2 = nb * 64 + ct * 16 + lr;
#pragma unroll
        for (int q = 0; q < 4; ++q) {
          stGf(&slabG2[(size_t)(rq + q) * 4096 + c2],
               acc0[q] + Cred[ct * 512 + (rq + q) * 16 + lr]);
          stGf(&slabG2[(size_t)(16 + rq + q) * 4096 + c2],
               acc1[q] + Cred[ct * 512 + (16 + rq + q) * 16 + lr]);
        }
      }
    }
    // ---- z reduce: blocks 0..127 write z cols 4*blk..4*blk+3 ----
    if (seg < 2) {
      zredC[rr * 16 + kw] = za0;
      zredC[512 + rr * 16 + kw] = za1;
      zredC[1024 + rr * 16 + kw] = za2;
      zredC[1536 + rr * 16 + kw] = za3;
    }
    __syncthreads();
    if (seg < 2 && tid < 128) {
      int c = tid >> 5, r = tid & 31;
      float z = 0.f;
#pragma unroll
      for (int j = 0; j < 16; ++j) z += zredC[c * 512 + r * 16 + j];
      stGf(&slabG[(size_t)r * 12800 + 12288 + 4 * blk + c], z);
    }
    gsync(bar, &ep_local);

    // ---------- pointwise (blocks 0..63: b = blk>>1, k-half = blk&1) ----------
    if (blk < 64) {
      int b = blk >> 1, kh2 = blk & 1;
      int k = (kh2 << 9) + tid;
      size_t xrow = (size_t)t * 32 + b;
      const unsigned short* Xg = X_ihH + xrow * 12288;
      const float* Xzr = Xz + xrow * 512;
      float* Gb = slabG + (size_t)b * 12800;
      float* G2b = slabG2 + (size_t)b * 4096;
      float zc = ldGf(&Gb[12288 + tid]) + Xzr[tid] + pib1[tid];
      float mu = bsum512(zc, s8, tid) * (1.0f / 512.0f);
      float dv = zc - mu;
      float var = bsum512(dv * dv, s8, tid) * (1.0f / 512.0f);
      float rstd = rsqrtf(var + 1e-5f);
      float l = fmaxf(dv * rstd * pilng[tid] + pilnb[tid], 0.0f);
      float lg[3];
#pragma unroll
      for (int kk = 0; kk < 3; ++kk)
        lg[kk] = bsum512(l * piW2[kk * 512 + tid], s8, tid);
      if (tid == 0) {
        int dcur = ldGi(&depth[(t & 1) * 32 + b]);
#pragma unroll
        for (int kk = 0; kk < 3; ++kk) lg[kk] += pib2[kk];
        if (dcur >= 2) lg[0] = -INFINITY;
        if (dcur == 0) lg[2] = -INFINITY;
        uint32_t kt0, kt1;
        tf2x32(0u, 42u, 0u, (uint32_t)t, &kt0, &kt1);
#pragma unroll
        for (int kk = 0; kk < 3; ++kk) {
          uint32_t o0, o1;
          tf2x32(kt0, kt1, 0u, (uint32_t)(3 * b + kk), &o0, &o1);
          lg[kk] += gumbel_from_bits(o0 ^ o1);
        }
        int a = 0; float best = lg[0];
        if (lg[1] > best) { best = lg[1]; a = 1; }
        if (lg[2] > best) { a = 2; }
        sact[0] = a; sact[1] = dcur;
      }
      __syncthreads();
      int a = sact[0], dcur = sact[1];
      int dnew = dcur + ((a == 0) ? 1 : 0) - ((a == 2) ? 1 : 0);
#define GV(c) (ldGf(&Gb[(c)]) + f16tof(Xg[(c)]))
#define GVM(c2) (ldGf(&Gb[8192 + (c2)]) + ldGf(&G2b[(c2)]) + f16tof(Xg[8192 + (c2)]))
      float ir = GV(k)        + rb[k],        fr_ = GV(1024 + k)  + rb[1024 + k];
      float gr = GV(2048 + k) + rb[2048 + k], orr = GV(3072 + k)  + rb[3072 + k];
      float is = GV(4096 + k) + sbv[k],       fs  = GV(5120 + k)  + sbv[1024 + k];
      float gs = GV(6144 + k) + sbv[2048 + k], os = GV(7168 + k)  + sbv[3072 + k];
      float im = GVM(k) + mb[k],              fm  = GVM(1024 + k) + mb[1024 + k];
      float gm = GVM(2048 + k) + mb[2048 + k], om = GVM(3072 + k) + mb[3072 + k];
#undef GV
#undef GVM
      float cold = cbuf[b * 1024 + k];
      float crn = sigf(fr_) * cold + sigf(ir) * tanhf(gr); float hrn = sigf(orr) * tanhf(crn);
      float csn = sigf(fs)  * cold + sigf(is) * tanhf(gs); float hsn = sigf(os)  * tanhf(csn);
      float cmn = sigf(fm)  * cold + sigf(im) * tanhf(gm); float hmn = sigf(om)  * tanhf(cmn);
      float hn = (a == 0) ? hsn : ((a == 1) ? hrn : hmn);
      float cn = (a == 0) ? csn : ((a == 1) ? crn : cmn);
      cbuf[b * 1024 + k] = cn;
      outsb[(size_t)t * 32768 + b * 1024 + k] = f2bf(hn);
      float si;
      if (a == 0) { stack[(size_t)(b * 2 + dcur) * 1024 + k] = hsn; si = hsn; }
      else si = (dnew > 0) ? stack[(size_t)(b * 2 + (dnew - 1)) * 1024 + k] : 0.0f;
      stGu(&uN[(size_t)b * 2048 + k], packHL(hn));
      stGu(&uN[(size_t)b * 2048 + 1024 + k], packHL(si));
      if (kh2 == 0 && tid == 0) stGi(&depth[((t + 1) & 1) * 32 + b], dnew);
    }
    gsync(bar, &ep_local);
  }
}

// ---------------- bf16 MFMA GEMM (pred/dec): C = A(M,K)@W(N,K)^T + bias [tanh-BN] ----------------
template <int EPI>   // 0: fp32 + bias; 1: tanh-BN -> bf16
__global__ __launch_bounds__(256) void mfma_gemm(
    const unsigned short* __restrict__ A, const unsigned short* __restrict__ W,
    const float* __restrict__ bias, int K, int N,
    float* __restrict__ Cf, unsigned short* __restrict__ Cb,
    const float* __restrict__ g, const float* __restrict__ bb, float invS) {
  __shared__ unsigned short As[128][40];
  __shared__ unsigned short Bs[128][40];
  int tid = threadIdx.x;
  int m0 = blockIdx.y << 7, n0 = blockIdx.x << 7;
  int wid = tid >> 6, lane = tid & 63;
  int wm = (wid >> 1) << 6, wn = (wid & 1) << 6;
  int lr = lane & 15, lk = (lane >> 4) << 3;
  f32x4 acc[4][4] = {};
  for (int k0 = 0; k0 < K; k0 += 32) {
    __syncthreads();
#pragma unroll
    for (int q = 0; q < 2; ++q) {
      int idx = tid + (q << 8);
      int row = idx >> 2, k8 = (idx & 3) << 3;
      *(s16x8*)&As[row][k8] = *(const s16x8*)(A + (size_t)(m0 + row) * K + k0 + k8);
      *(s16x8*)&Bs[row][k8] = *(const s16x8*)(W + (size_t)(n0 + row) * K + k0 + k8);
    }
    __syncthreads();
    s16x8 af[4], bw[4];
#pragma unroll
    for (int i = 0; i < 4; ++i) {
      af[i] = *(const s16x8*)&As[wm + (i << 4) + lr][lk];
      bw[i] = *(const s16x8*)&Bs[wn + (i << 4) + lr][lk];
    }
#pragma unroll
    for (int i = 0; i < 4; ++i)
#pragma unroll
      for (int j = 0; j < 4; ++j)
        acc[i][j] = __builtin_amdgcn_mfma_f32_16x16x32_bf16(af[i], bw[j], acc[i][j], 0, 0, 0);
  }
#pragma unroll
  for (int i = 0; i < 4; ++i) {
    int row = m0 + wm + (i << 4) + ((lane >> 4) << 2);
#pragma unroll
    for (int j = 0; j < 4; ++j) {
      int col = n0 + wn + (j << 4) + lr;
      float bv = bias[col];
#pragma unroll
      for (int r = 0; r < 4; ++r) {
        float v = acc[i][j][r] + bv;
        if (EPI) {
          v = tanhf(v * invS * g[col] + bb[col]);
          Cb[(size_t)(row + r) * N + col] = f2bf(v);
        } else {
          Cf[(size_t)(row + r) * N + col] = v;
        }
      }
    }
  }
}

// ---------------- launcher ----------------
extern "C" void kernel_launch(void* const* d_in, const int* in_sizes, int n_in,
                              void* d_out, int out_size, void* d_ws, size_t ws_size,
                              hipStream_t stream) {
  const int*   tokens = (const int*)d_in[0];
  const float* h0    = (const float*)d_in[1];
  const float* c0    = (const float*)d_in[2];
  const float* embW  = (const float*)d_in[3];
  const float* rWih  = (const float*)d_in[4];
  const float* rWhh  = (const float*)d_in[5];
  const float* rb    = (const float*)d_in[6];
  const float* sWih  = (const float*)d_in[7];
  const float* sWhh  = (const float*)d_in[8];
  const float* sbv   = (const float*)d_in[9];
  const float* mWih  = (const float*)d_in[10];
  const float* mWhh  = (const float*)d_in[11];
  const float* mb    = (const float*)d_in[12];
  const float* piW1  = (const float*)d_in[13];
  const float* pib1  = (const float*)d_in[14];
  const float* pilng = (const float*)d_in[15];
  const float* pilnb = (const float*)d_in[16];
  const float* piW2  = (const float*)d_in[17];
  const float* pib2  = (const float*)d_in[18];
  const float* predW = (const float*)d_in[19];
  const float* predb = (const float*)d_in[20];
  const float* bng   = (const float*)d_in[21];
  const float* bnb   = (const float*)d_in[22];
  const float* decW  = (const float*)d_in[23];
  const float* decb  = (const float*)d_in[24];
  float* out = (float*)d_out;
  float* ws  = (float*)d_ws;

  // float region
  float* emb   = ws;                             // 2,097,152
  unsigned* uHL0 = (unsigned*)(emb + 2097152);   //    65,536
  unsigned* uHL1 = uHL0 + 65536;                 //    65,536
  float* cbuf  = (float*)(uHL1 + 65536);         //    32,768
  float* stack = cbuf + 32768;                   //    65,536
  float* slabG = stack + 65536;                  //   409,600
  float* slabG2 = slabG + 409600;                //   131,072
  float* Xz    = slabG2 + 131072;                // 2,097,152
  // ushort region
  unsigned short* X_ihH  = (unsigned short*)(Xz + 2097152);     // 50,331,648
  unsigned short* wpak   = X_ihH + 50331648;                    // 33,554,432
  unsigned short* wcatH  = wpak + 33554432;                     //  6,291,456
  unsigned short* embH   = wcatH + 6291456;                     //  2,097,152
  unsigned short* outsb  = embH + 2097152;                      //  4,194,304
  int* depth = (int*)(outsb + 4194304);                         // 64 ints
  int* bar   = depth + 64;                                      // 160 ints
  // post-scan aliases (wpak is dead after the scan)
  unsigned short* decWb  = wpak;                                // 16,384,000
  unsigned short* predWb = wpak + 16384000;                     //    524,288
  unsigned short* ytbf   = wpak + 16908288;                     //  2,097,152

  init_state<<<dim3(256), dim3(256), 0, stream>>>(h0, c0, uHL0, cbuf, stack, depth, bar);
  embed_kernel<<<dim3(4096), dim3(128), 0, stream>>>(tokens, embW, emb);
  to_f16<<<dim3(2048), dim3(256), 0, stream>>>(emb, embH, 524288);
  pack_wcat16<<<dim3(24576), dim3(256), 0, stream>>>(rWih, sWih, mWih, wcatH);
  pack_whilo<<<dim3(131072), dim3(256), 0, stream>>>(rWhh, sWhh, mWhh, mWih, wpak);

  // Xz = emb @ piW1[:,1024:1536]^T  (fp32, exact sampling path)
  xz_gemm<<<dim3(8, 64), dim3(256), 0, stream>>>(emb, piW1, Xz);
  // X_ih = embH @ wcatH^T  (4096 x 12288, fp16)
  mfma_gemm_f16out<<<dim3(96, 32), dim3(256), 0, stream>>>(embH, wcatH, X_ihH, 512, 12288);

  scan_persistent<<<dim3(NBLK), dim3(512), 0, stream>>>(
      uHL0, uHL1, cbuf, stack, depth, slabG, slabG2, outsb, bar,
      wpak, X_ihH, Xz, piW1, rb, sbv, mb, pib1, pilng, pilnb, piW2, pib2);

  // pred/dec weights converted after the scan into the dead wpak region
  to_bf16<<<dim3(512), dim3(256), 0, stream>>>(predW, predWb, 131072);
  to_bf16<<<dim3(16000), dim3(256), 0, stream>>>(decW, decWb, 4096000);

  float invS = 1.0f / sqrtf(1.0f + 1e-5f);
  mfma_gemm<1><<<dim3(4, 32), dim3(256), 0, stream>>>(
      outsb, predWb, predb, 1024, 512, nullptr, ytbf, bng, bnb, invS);
  mfma_gemm<0><<<dim3(250, 32), dim3(256), 0, stream>>>(
      ytbf, decWb, decb, 512, 32000, out, nullptr, nullptr, nullptr, 0.0f);
  final_copy<<<dim3(128), dim3(256), 0, stream>>>(uHL0, cbuf, out);
}

// Round 11
// 10184.810 us; speedup vs baseline: 6.8265x; 1.0030x over previous
//
#include <hip/hip_runtime.h>
#include <hip/hip_bf16.h>
#include <stdint.h>
#include <math.h>

using s16x8 = __attribute__((ext_vector_type(8))) short;
using f16x8 = __attribute__((ext_vector_type(8))) _Float16;
using f32x4 = __attribute__((ext_vector_type(4))) float;

#define NBLK 256
#define GRP 32   // NBLK / 8 groups

// ---------------- agent-scope coherent access helpers ----------------
__device__ __forceinline__ float ldGf(const float* p) {
  unsigned v = __hip_atomic_load((const unsigned*)p, __ATOMIC_RELAXED, __HIP_MEMORY_SCOPE_AGENT);
  return __uint_as_float(v);
}
__device__ __forceinline__ void stGf(float* p, float x) {
  __hip_atomic_store((unsigned*)p, __float_as_uint(x), __ATOMIC_RELAXED, __HIP_MEMORY_SCOPE_AGENT);
}
__device__ __forceinline__ void stGu(unsigned* p, unsigned v) {
  __hip_atomic_store(p, v, __ATOMIC_RELAXED, __HIP_MEMORY_SCOPE_AGENT);
}
__device__ __forceinline__ unsigned long long ldU64(const unsigned long long* p) {
  return __hip_atomic_load(p, __ATOMIC_RELAXED, __HIP_MEMORY_SCOPE_AGENT);
}
__device__ __forceinline__ int ldGi(const int* p) {
  return __hip_atomic_load(p, __ATOMIC_RELAXED, __HIP_MEMORY_SCOPE_AGENT);
}
__device__ __forceinline__ void stGi(int* p, int v) {
  __hip_atomic_store(p, v, __ATOMIC_RELAXED, __HIP_MEMORY_SCOPE_AGENT);
}

// ---------------- hi/lo fp16 packing of fp32 ----------------
__device__ __forceinline__ unsigned packHL(float x) {
  _Float16 h = (_Float16)x;
  float r = x - (float)h;
  _Float16 l = (_Float16)r;
  unsigned short hb, lb;
  __builtin_memcpy(&hb, &h, 2); __builtin_memcpy(&lb, &l, 2);
  return (unsigned)hb | ((unsigned)lb << 16);
}
__device__ __forceinline__ float unpackHL(unsigned v) {
  unsigned short hb = (unsigned short)(v & 0xffffu), lb = (unsigned short)(v >> 16);
  _Float16 h, l;
  __builtin_memcpy(&h, &hb, 2); __builtin_memcpy(&l, &lb, 2);
  return (float)h + (float)l;
}

// ---------------- threefry2x32 (JAX-exact, partitionable) ----------------
__device__ __forceinline__ void tf2x32(uint32_t k0, uint32_t k1,
                                       uint32_t x0, uint32_t x1,
                                       uint32_t* o0, uint32_t* o1) {
  uint32_t ks0 = k0, ks1 = k1, ks2 = k0 ^ k1 ^ 0x1BD11BDAu;
  x0 += ks0; x1 += ks1;
  const int R[8] = {13,15,26,6, 17,29,16,24};
#pragma unroll
  for (int g = 0; g < 5; ++g) {
    const int base = (g & 1) ? 4 : 0;
#pragma unroll
    for (int j = 0; j < 4; ++j) {
      int r = R[base + j];
      x0 += x1;
      x1 = (x1 << r) | (x1 >> (32 - r));
      x1 ^= x0;
    }
    switch (g) {
      case 0: x0 += ks1; x1 += ks2 + 1u; break;
      case 1: x0 += ks2; x1 += ks0 + 2u; break;
      case 2: x0 += ks0; x1 += ks1 + 3u; break;
      case 3: x0 += ks1; x1 += ks2 + 4u; break;
      case 4: x0 += ks2; x1 += ks0 + 5u; break;
    }
  }
  *o0 = x0; *o1 = x1;
}

__device__ __forceinline__ float gumbel_from_bits(uint32_t bits) {
  float u = __uint_as_float((bits >> 9) | 0x3f800000u) - 1.0f;
  if (u == 0.0f) u = 1.1754943508222875e-38f;  // finfo(f32).tiny
  return -logf(-logf(u));
}

__device__ __forceinline__ float sigf(float x) { return 1.0f / (1.0f + expf(-x)); }

__device__ __forceinline__ unsigned short f2bf(float f) {
  unsigned u = __float_as_uint(f);
  unsigned r = (u + 0x7fffu + ((u >> 16) & 1u)) >> 16;
  return (unsigned short)r;
}

__device__ __forceinline__ float f16tof(unsigned short v) {
  _Float16 h; __builtin_memcpy(&h, &v, 2); return (float)h;
}

// block reduction over 512 threads (8 waves)
__device__ __forceinline__ float bsum512(float v, volatile float* s8, int tid) {
#pragma unroll
  for (int o = 1; o < 64; o <<= 1) v += __shfl_xor(v, o, 64);
  __syncthreads();
  if ((tid & 63) == 0) s8[tid >> 6] = v;
  __syncthreads();
  float r = 0.0f;
#pragma unroll
  for (int j = 0; j < 8; ++j) r += s8[j];
  return r;
}

// Two-level grid barrier, fence-free (R9-proven): cross-block data moves via
// agent-scope relaxed atomics; __syncthreads drains vmcnt before arrival.
__device__ __forceinline__ void gsync(int* bar, int* ep_local) {
  __syncthreads();
  if (threadIdx.x == 0) {
    int ep = ++(*ep_local);
    int g = blockIdx.x & 7;
    int old = __hip_atomic_fetch_add(&bar[g * 16], 1, __ATOMIC_RELAXED, __HIP_MEMORY_SCOPE_AGENT);
    if (old == ep * GRP - 1) {
      int mo = __hip_atomic_fetch_add(&bar[128], 1, __ATOMIC_RELAXED, __HIP_MEMORY_SCOPE_AGENT);
      if (mo == ep * 8 - 1)
        __hip_atomic_store(&bar[144], ep, __ATOMIC_RELAXED, __HIP_MEMORY_SCOPE_AGENT);
    }
    while (__hip_atomic_load(&bar[144], __ATOMIC_RELAXED, __HIP_MEMORY_SCOPE_AGENT) < ep)
      __builtin_amdgcn_s_sleep(8);
  }
  __syncthreads();
}

// ---------------- init / embed / copy / convert / pack ----------------
__global__ void init_state(const float* __restrict__ h0, const float* __restrict__ c0,
                           unsigned* __restrict__ uHL0, float* __restrict__ cbuf,
                           float* __restrict__ stack, int* __restrict__ depth,
                           int* __restrict__ bar) {
  int i = blockIdx.x * blockDim.x + threadIdx.x;  // 65536
  if (i < 65536) {
    int b = i >> 11, k = i & 2047;
    float v = (k < 1024) ? h0[b * 1024 + k] : 0.0f;   // [h0 | si=0]
    uHL0[i] = packHL(v);
    stack[i] = 0.0f;
  }
  if (i < 32768) cbuf[i] = c0[i];
  if (i < 64) depth[i] = 0;
  if (i < 160) bar[i] = 0;
}

__global__ void embed_kernel(const int* __restrict__ toks, const float* __restrict__ embW,
                             float* __restrict__ emb) {
  int row = blockIdx.x;            // t*32+b
  int tid = threadIdx.x;           // 128 threads
  int tk = toks[row];
  float4 v = ((const float4*)(embW + (size_t)tk * 512))[tid];
  ((float4*)(emb + (size_t)row * 512))[tid] = v;
}

__global__ void final_copy(const unsigned* __restrict__ uHL0, const float* __restrict__ cbuf,
                           float* __restrict__ out) {
  int i = blockIdx.x * blockDim.x + threadIdx.x;  // 32768
  int b = i >> 10, k = i & 1023;
  out[131072000u + i] = unpackHL(uHL0[(size_t)b * 2048 + k]);
  out[131072000u + 32768u + i] = cbuf[i];
}

__global__ void to_bf16(const float* __restrict__ s, unsigned short* __restrict__ d, int n4) {
  int i = blockIdx.x * blockDim.x + threadIdx.x;
  if (i < n4) {
    float4 v = *(const float4*)(s + (size_t)i * 4);
    ushort4 o;
    o.x = f2bf(v.x); o.y = f2bf(v.y); o.z = f2bf(v.z); o.w = f2bf(v.w);
    *(ushort4*)(d + (size_t)i * 4) = o;
  }
}

__global__ void to_f16(const float* __restrict__ s, unsigned short* __restrict__ d, int n4) {
  int i = blockIdx.x * blockDim.x + threadIdx.x;
  if (i < n4) {
    float4 v = *(const float4*)(s + (size_t)i * 4);
    _Float16 h0_ = (_Float16)v.x, h1 = (_Float16)v.y, h2 = (_Float16)v.z, h3 = (_Float16)v.w;
    ushort4 o;
    __builtin_memcpy(&o.x, &h0_, 2); __builtin_memcpy(&o.y, &h1, 2);
    __builtin_memcpy(&o.z, &h2, 2); __builtin_memcpy(&o.w, &h3, 2);
    *(ushort4*)(d + (size_t)i * 4) = o;
  }
}

// Wcat fp16 (12288 x 512): rows 0..4095 rWih, 4096..8191 sWih, 8192..12287 mWih[:, :512]
__global__ void pack_wcat16(const float* __restrict__ rWih, const float* __restrict__ sWih,
                            const float* __restrict__ mWih, unsigned short* __restrict__ wcat) {
  int idx = blockIdx.x * 256 + threadIdx.x;   // 6,291,456
  if (idx >= 12288 * 512) return;
  int c = idx >> 9, k = idx & 511;
  float v;
  if (c < 4096)      v = rWih[(size_t)c * 512 + k];
  else if (c < 8192) v = sWih[(size_t)(c - 4096) * 512 + k];
  else               v = mWih[(size_t)(c - 8192) * 1536 + k];
  _Float16 h = (_Float16)v;
  unsigned short b; __builtin_memcpy(&b, &h, 2);
  wcat[idx] = b;
}

// wpak layout (R10): idx = (((blk*8 + w)*32 + f)*64 + lane)*8 + e
// wave (blk, w): ct = w&3 (16-col tile), kh = w>>2 (512-K half).
// frag f<16 = hi plane, f>=16 = lo plane; k_loc = (f&15)*32 + (lane>>4)*8 + e,
// col = coltile_base + (lane&15).
__global__ void pack_whilo(const float* __restrict__ rWhh, const float* __restrict__ sWhh,
                           const float* __restrict__ mWhh, const float* __restrict__ mWih,
                           unsigned short* __restrict__ wpak) {
  int idx = blockIdx.x * 256 + threadIdx.x;  // 33,554,432
  int e = idx & 7, lane = (idx >> 3) & 63, f = (idx >> 9) & 31,
      w = (idx >> 14) & 7, blk = idx >> 17;
  int lr = lane & 15, lk = lane >> 4;
  int hilo = f >> 4, fk = f & 15;
  int ct = w & 3, kh = w >> 2;
  int k = (kh << 9) + (fk << 5) + (lk << 3) + e;   // 0..1023
  float v;
  if (blk < 64) {
    int col = blk * 64 + ct * 16 + lr;           v = rWhh[(size_t)col * 1024 + k];
  } else if (blk < 128) {
    int col = (blk - 64) * 64 + ct * 16 + lr;    v = sWhh[(size_t)col * 1024 + k];
  } else if (blk < 192) {
    int col = (blk - 128) * 64 + ct * 16 + lr;   v = mWhh[(size_t)col * 1024 + k];
  } else {
    int col = (blk - 192) * 64 + ct * 16 + lr;   v = mWih[(size_t)col * 1536 + 512 + k];
  }
  _Float16 hv = (_Float16)v;
  _Float16 ov = hilo ? (_Float16)(v - (float)hv) : hv;
  unsigned short b; __builtin_memcpy(&b, &ov, 2);
  wpak[idx] = b;
}

// ---------------- X_z fp32 GEMM: Xz = emb(4096x512) @ piW1[:,1024:1536]^T ----------------
__global__ __launch_bounds__(256) void xz_gemm(const float* __restrict__ A,
                                               const float* __restrict__ W,
                                               float* __restrict__ C) {
  __shared__ float Asb[32][68];
  __shared__ float Bsb[32][68];
  int tid = threadIdx.x;
  int tx = tid & 15, ty = tid >> 4;
  int m0 = blockIdx.y * 64, n0 = blockIdx.x * 64;
  int r = tid >> 3, kb = (tid & 7) * 4;
  float acc[4][4] = {};
  for (int k0 = 0; k0 < 512; k0 += 32) {
    __syncthreads();
    float4 a0 = *(const float4*)(A + (size_t)(m0 + r) * 512 + k0 + kb);
    float4 a1 = *(const float4*)(A + (size_t)(m0 + r + 32) * 512 + k0 + kb);
    float4 b0 = *(const float4*)(W + (size_t)(n0 + r) * 1536 + 1024 + k0 + kb);
    float4 b1 = *(const float4*)(W + (size_t)(n0 + r + 32) * 1536 + 1024 + k0 + kb);
    Asb[kb + 0][r] = a0.x; Asb[kb + 1][r] = a0.y; Asb[kb + 2][r] = a0.z; Asb[kb + 3][r] = a0.w;
    Asb[kb + 0][r + 32] = a1.x; Asb[kb + 1][r + 32] = a1.y; Asb[kb + 2][r + 32] = a1.z; Asb[kb + 3][r + 32] = a1.w;
    Bsb[kb + 0][r] = b0.x; Bsb[kb + 1][r] = b0.y; Bsb[kb + 2][r] = b0.z; Bsb[kb + 3][r] = b0.w;
    Bsb[kb + 0][r + 32] = b1.x; Bsb[kb + 1][r + 32] = b1.y; Bsb[kb + 2][r + 32] = b1.z; Bsb[kb + 3][r + 32] = b1.w;
    __syncthreads();
#pragma unroll
    for (int kk = 0; kk < 32; ++kk) {
      float4 av = *(const float4*)&Asb[kk][ty * 4];
      float4 bv = *(const float4*)&Bsb[kk][tx * 4];
      float aa[4] = {av.x, av.y, av.z, av.w};
      float bw[4] = {bv.x, bv.y, bv.z, bv.w};
#pragma unroll
      for (int i = 0; i < 4; ++i)
#pragma unroll
        for (int j = 0; j < 4; ++j) acc[i][j] += aa[i] * bw[j];
    }
  }
#pragma unroll
  for (int i = 0; i < 4; ++i)
#pragma unroll
    for (int j = 0; j < 4; ++j)
      C[(size_t)(m0 + ty * 4 + i) * 512 + n0 + tx * 4 + j] = acc[i][j];
}

// ---------------- fp16 MFMA GEMM (X_ih): C = A(M,K) @ W(N,K)^T -> fp16 ----------------
__global__ __launch_bounds__(256) void mfma_gemm_f16out(
    const unsigned short* __restrict__ A, const unsigned short* __restrict__ W,
    unsigned short* __restrict__ C, int K, int N) {
  __shared__ unsigned short As[128][40];
  __shared__ unsigned short Bs[128][40];
  int tid = threadIdx.x;
  int m0 = blockIdx.y << 7, n0 = blockIdx.x << 7;
  int wid = tid >> 6, lane = tid & 63;
  int wm = (wid >> 1) << 6, wn = (wid & 1) << 6;
  int lr = lane & 15, lk = (lane >> 4) << 3;
  f32x4 acc[4][4] = {};
  for (int k0 = 0; k0 < K; k0 += 32) {
    __syncthreads();
#pragma unroll
    for (int q = 0; q < 2; ++q) {
      int idx = tid + (q << 8);
      int row = idx >> 2, k8 = (idx & 3) << 3;
      *(s16x8*)&As[row][k8] = *(const s16x8*)(A + (size_t)(m0 + row) * K + k0 + k8);
      *(s16x8*)&Bs[row][k8] = *(const s16x8*)(W + (size_t)(n0 + row) * K + k0 + k8);
    }
    __syncthreads();
#pragma unroll
    for (int i = 0; i < 4; ++i)
#pragma unroll
      for (int j = 0; j < 4; ++j) {
        f16x8 af = *(const f16x8*)&As[wm + (i << 4) + lr][lk];
        f16x8 bw = *(const f16x8*)&Bs[wn + (j << 4) + lr][lk];
        acc[i][j] = __builtin_amdgcn_mfma_f32_16x16x32_f16(af, bw, acc[i][j], 0, 0, 0);
      }
  }
#pragma unroll
  for (int i = 0; i < 4; ++i) {
    int row = m0 + wm + (i << 4) + ((lane >> 4) << 2);
#pragma unroll
    for (int j = 0; j < 4; ++j) {
      int col = n0 + wn + (j << 4) + lr;
#pragma unroll
      for (int r = 0; r < 4; ++r) {
        _Float16 h = (_Float16)acc[i][j][r];
        unsigned short b; __builtin_memcpy(&b, &h, 2);
        C[(size_t)(row + r) * N + col] = b;
      }
    }
  }
}

// ---------------- persistent scan: 256 blocks x 512 threads, 1 block/CU ----------------
// blk<64: r (64 cols, K1024/h). blk<128: s. blk<192: m h-half. blk>=192: m si-half
// (partials to slabG2). Wave w: ct=w&3 (16 cols), kh=w>>2 (512-K window).
// __launch_bounds__(512, 2): min 2 waves/EU -> 256-VGPR cap so the 128-VGPR
// weight slice stays register-resident (R10 failure: 128-cap -> scratch spill).
__global__ __launch_bounds__(512, 2)
void scan_persistent(
    unsigned* __restrict__ uHL0, unsigned* __restrict__ uHL1,
    float* __restrict__ cbuf, float* __restrict__ stack, int* __restrict__ depth,
    float* __restrict__ slabG, float* __restrict__ slabG2,
    unsigned short* __restrict__ outsb, int* __restrict__ bar,
    const unsigned short* __restrict__ wpak, const unsigned short* __restrict__ X_ihH,
    const float* __restrict__ Xz, const float* __restrict__ piW1,
    const float* __restrict__ rb, const float* __restrict__ sbv, const float* __restrict__ mb,
    const float* __restrict__ pib1, const float* __restrict__ pilng,
    const float* __restrict__ pilnb, const float* __restrict__ piW2,
    const float* __restrict__ pib2) {
  __shared__ __align__(16) _Float16 AsH[32 * 520];
  __shared__ __align__(16) _Float16 AsL[32 * 520];
  __shared__ float Cred[2048];
  __shared__ float zredC[2048];
  __shared__ float s8[8];
  __shared__ int sact[2];

  int blk = blockIdx.x, tid = threadIdx.x;
  int ep_local = 0;
  int w = tid >> 6, lane = tid & 63;
  int lr = lane & 15, lk = lane >> 4;
  int ct = w & 3, kh = w >> 2;
  int seg = (blk < 64) ? 0 : (blk < 128) ? 1 : (blk < 192) ? 2 : 3;
  int nb = blk - ((seg == 0) ? 0 : (seg == 1) ? 64 : (seg == 2) ? 128 : 192);
  int colbase = (seg == 0) ? nb * 64 : (seg == 1) ? 4096 + nb * 64 : 8192 + nb * 64;
  int kbase_u = (seg == 3) ? 1024 : 0;
  int rr = tid >> 4, kw = tid & 15;
  int rq = lk << 2;

  // ---- load W hi/lo fragments into registers (once) ----
  f16x8 whi[16], wlo[16];
  {
    const f16x8* wp = (const f16x8*)(wpak + (((size_t)(blk * 8 + w)) << 14)) + lane;
#pragma unroll
    for (int f = 0; f < 16; ++f) {
      whi[f] = wp[(size_t)f * 64];
      wlo[f] = wp[(size_t)(f + 16) * 64];
    }
  }

  for (int t = 0; t < 128; ++t) {
    const unsigned* uP = (t & 1) ? uHL1 : uHL0;
    unsigned* uN = (t & 1) ? uHL0 : uHL1;

    f32x4 acc0 = {0.f, 0.f, 0.f, 0.f}, acc1 = {0.f, 0.f, 0.f, 0.f};
    float za0 = 0.f, za1 = 0.f, za2 = 0.f, za3 = 0.f;

#pragma unroll
    for (int win = 0; win < 2; ++win) {
      // ---- issue 16x8B sc loads (128 B/thread in flight) ----
      unsigned long long d[16];
      {
        const unsigned long long* up =
            (const unsigned long long*)(uP + (size_t)rr * 2048 + kbase_u + win * 512 + kw * 32);
#pragma unroll
        for (int j = 0; j < 16; ++j) d[j] = ldU64(up + j);
      }
      // ---- z partials straight from registers (blocks 0..127 own 4 z-cols) ----
      if (seg < 2) {
        const float* p0 = piW1 + (size_t)(4 * blk) * 1536 + win * 512 + kw * 32;
#pragma unroll
        for (int j = 0; j < 16; ++j) {
          float e0 = unpackHL((unsigned)d[j]);
          float e1 = unpackHL((unsigned)(d[j] >> 32));
          int kk = 2 * j;
          za0 += e0 * p0[kk]        + e1 * p0[kk + 1];
          za1 += e0 * p0[1536 + kk] + e1 * p0[1537 + kk];
          za2 += e0 * p0[3072 + kk] + e1 * p0[3073 + kk];
          za3 += e0 * p0[4608 + kk] + e1 * p0[4609 + kk];
        }
      }
      __syncthreads();   // previous window's LDS fully consumed
      // ---- unpack hi/lo planes to LDS ----
      {
        unsigned hi[16], lo[16];
#pragma unroll
        for (int j = 0; j < 16; ++j) {
          unsigned a0 = (unsigned)d[j], a1 = (unsigned)(d[j] >> 32);
          hi[j] = (a0 & 0xffffu) | (a1 << 16);
          lo[j] = (a0 >> 16) | (a1 & 0xffff0000u);
        }
        _Float16* hp = &AsH[rr * 520 + kw * 32];
        _Float16* lp = &AsL[rr * 520 + kw * 32];
#pragma unroll
        for (int q = 0; q < 4; ++q) {
          uint4 hv = {hi[4 * q], hi[4 * q + 1], hi[4 * q + 2], hi[4 * q + 3]};
          uint4 lv = {lo[4 * q], lo[4 * q + 1], lo[4 * q + 2], lo[4 * q + 3]};
          *(uint4*)(hp + q * 8) = hv;
          *(uint4*)(lp + q * 8) = lv;
        }
      }
      __syncthreads();
      // ---- MFMA: wave consumes its matching 512-K window ----
      if (win == kh) {
#pragma unroll
        for (int fl = 0; fl < 16; ++fl) {
          int ko = fl * 32 + lk * 8;
          f16x8 Ah0 = *(const f16x8*)&AsH[lr * 520 + ko];
          f16x8 Al0 = *(const f16x8*)&AsL[lr * 520 + ko];
          f16x8 Ah1 = *(const f16x8*)&AsH[(16 + lr) * 520 + ko];
          f16x8 Al1 = *(const f16x8*)&AsL[(16 + lr) * 520 + ko];
          acc0 = __builtin_amdgcn_mfma_f32_16x16x32_f16(Ah0, whi[fl], acc0, 0, 0, 0);
          acc0 = __builtin_amdgcn_mfma_f32_16x16x32_f16(Al0, whi[fl], acc0, 0, 0, 0);
          acc0 = __builtin_amdgcn_mfma_f32_16x16x32_f16(Ah0, wlo[fl], acc0, 0, 0, 0);
          acc1 = __builtin_amdgcn_mfma_f32_16x16x32_f16(Ah1, whi[fl], acc1, 0, 0, 0);
          acc1 = __builtin_amdgcn_mfma_f32_16x16x32_f16(Al1, whi[fl], acc1, 0, 0, 0);
          acc1 = __builtin_amdgcn_mfma_f32_16x16x32_f16(Ah1, wlo[fl], acc1, 0, 0, 0);
        }
      }
    }

    // ---- combine K-halves (kh pair) via Cred, write G planes (sc) ----
    __syncthreads();
    if (kh == 1) {
#pragma unroll
      for (int q = 0; q < 4; ++q) {
        Cred[ct * 512 + (rq + q) * 16 + lr] = acc0[q];
        Cred[ct * 512 + (16 + rq + q) * 16 + lr] = acc1[q];
      }
    }
    __syncthreads();
    if (kh == 0) {
      if (seg < 3) {
#pragma unroll
        for (int q = 0; q < 4; ++q) {
          stGf(&slabG[(size_t)(rq + q) * 12800 + colbase + ct * 16 + lr],
               acc0[q] + Cred[ct * 512 + (rq + q) * 16 + lr]);
          stGf(&slabG[(size_t)(16 + rq + q) * 12800 + colbase + ct * 16 + lr],
               acc1[q] + Cred[ct * 512 + (16 + rq + q) * 16 + lr]);
        }
      } else {
        int c2 = nb * 64 + ct * 16 + lr;
#pragma unroll
        for (int q = 0; q < 4; ++q) {
          stGf(&slabG2[(size_t)(rq + q) * 4096 + c2],
               acc0[q] + Cred[ct * 512 + (rq + q) * 16 + lr]);
          stGf(&slabG2[(size_t)(16 + rq + q) * 4096 + c2],
               acc1[q] + Cred[ct * 512 + (16 + rq + q) * 16 + lr]);
        }
      }
    }
    // ---- z reduce: blocks 0..127 write z cols 4*blk..4*blk+3 ----
    if (seg < 2) {
      zredC[rr * 16 + kw] = za0;
      zredC[512 + rr * 16 + kw] = za1;
      zredC[1024 + rr * 16 + kw] = za2;
      zredC[1536 + rr * 16 + kw] = za3;
    }
    __syncthreads();
    if (seg < 2 && tid < 128) {
      int c = tid >> 5, r = tid & 31;
      float z = 0.f;
#pragma unroll
      for (int j = 0; j < 16; ++j) z += zredC[c * 512 + r * 16 + j];
      stGf(&slabG[(size_t)r * 12800 + 12288 + 4 * blk + c], z);
    }
    gsync(bar, &ep_local);

    // ---------- pointwise (blocks 0..63: b = blk>>1, k-half = blk&1) ----------
    if (blk < 64) {
      int b = blk >> 1, kh2 = blk & 1;
      int k = (kh2 << 9) + tid;
      size_t xrow = (size_t)t * 32 + b;
      const unsigned short* Xg = X_ihH + xrow * 12288;
      const float* Xzr = Xz + xrow * 512;
      float* Gb = slabG + (size_t)b * 12800;
      float* G2b = slabG2 + (size_t)b * 4096;
      float zc = ldGf(&Gb[12288 + tid]) + Xzr[tid] + pib1[tid];
      float mu = bsum512(zc, s8, tid) * (1.0f / 512.0f);
      float dv = zc - mu;
      float var = bsum512(dv * dv, s8, tid) * (1.0f / 512.0f);
      float rstd = rsqrtf(var + 1e-5f);
      float l = fmaxf(dv * rstd * pilng[tid] + pilnb[tid], 0.0f);
      float lg[3];
#pragma unroll
      for (int kk = 0; kk < 3; ++kk)
        lg[kk] = bsum512(l * piW2[kk * 512 + tid], s8, tid);
      if (tid == 0) {
        int dcur = ldGi(&depth[(t & 1) * 32 + b]);
#pragma unroll
        for (int kk = 0; kk < 3; ++kk) lg[kk] += pib2[kk];
        if (dcur >= 2) lg[0] = -INFINITY;
        if (dcur == 0) lg[2] = -INFINITY;
        uint32_t kt0, kt1;
        tf2x32(0u, 42u, 0u, (uint32_t)t, &kt0, &kt1);
#pragma unroll
        for (int kk = 0; kk < 3; ++kk) {
          uint32_t o0, o1;
          tf2x32(kt0, kt1, 0u, (uint32_t)(3 * b + kk), &o0, &o1);
          lg[kk] += gumbel_from_bits(o0 ^ o1);
        }
        int a = 0; float best = lg[0];
        if (lg[1] > best) { best = lg[1]; a = 1; }
        if (lg[2] > best) { a = 2; }
        sact[0] = a; sact[1] = dcur;
      }
      __syncthreads();
      int a = sact[0], dcur = sact[1];
      int dnew = dcur + ((a == 0) ? 1 : 0) - ((a == 2) ? 1 : 0);
#define GV(c) (ldGf(&Gb[(c)]) + f16tof(Xg[(c)]))
#define GVM(c2) (ldGf(&Gb[8192 + (c2)]) + ldGf(&G2b[(c2)]) + f16tof(Xg[8192 + (c2)]))
      float ir = GV(k)        + rb[k],        fr_ = GV(1024 + k)  + rb[1024 + k];
      float gr = GV(2048 + k) + rb[2048 + k], orr = GV(3072 + k)  + rb[3072 + k];
      float is = GV(4096 + k) + sbv[k],       fs  = GV(5120 + k)  + sbv[1024 + k];
      float gs = GV(6144 + k) + sbv[2048 + k], os = GV(7168 + k)  + sbv[3072 + k];
      float im = GVM(k) + mb[k],              fm  = GVM(1024 + k) + mb[1024 + k];
      float gm = GVM(2048 + k) + mb[2048 + k], om = GVM(3072 + k) + mb[3072 + k];
#undef GV
#undef GVM
      float cold = cbuf[b * 1024 + k];
      float crn = sigf(fr_) * cold + sigf(ir) * tanhf(gr); float hrn = sigf(orr) * tanhf(crn);
      float csn = sigf(fs)  * cold + sigf(is) * tanhf(gs); float hsn = sigf(os)  * tanhf(csn);
      float cmn = sigf(fm)  * cold + sigf(im) * tanhf(gm); float hmn = sigf(om)  * tanhf(cmn);
      float hn = (a == 0) ? hsn : ((a == 1) ? hrn : hmn);
      float cn = (a == 0) ? csn : ((a == 1) ? crn : cmn);
      cbuf[b * 1024 + k] = cn;
      outsb[(size_t)t * 32768 + b * 1024 + k] = f2bf(hn);
      float si;
      if (a == 0) { stack[(size_t)(b * 2 + dcur) * 1024 + k] = hsn; si = hsn; }
      else si = (dnew > 0) ? stack[(size_t)(b * 2 + (dnew - 1)) * 1024 + k] : 0.0f;
      stGu(&uN[(size_t)b * 2048 + k], packHL(hn));
      stGu(&uN[(size_t)b * 2048 + 1024 + k], packHL(si));
      if (kh2 == 0 && tid == 0) stGi(&depth[((t + 1) & 1) * 32 + b], dnew);
    }
    gsync(bar, &ep_local);
  }
}

// ---------------- bf16 MFMA GEMM (pred/dec): C = A(M,K)@W(N,K)^T + bias [tanh-BN] ----------------
template <int EPI>   // 0: fp32 + bias; 1: tanh-BN -> bf16
__global__ __launch_bounds__(256) void mfma_gemm(
    const unsigned short* __restrict__ A, const unsigned short* __restrict__ W,
    const float* __restrict__ bias, int K, int N,
    float* __restrict__ Cf, unsigned short* __restrict__ Cb,
    const float* __restrict__ g, const float* __restrict__ bb, float invS) {
  __shared__ unsigned short As[128][40];
  __shared__ unsigned short Bs[128][40];
  int tid = threadIdx.x;
  int m0 = blockIdx.y << 7, n0 = blockIdx.x << 7;
  int wid = tid >> 6, lane = tid & 63;
  int wm = (wid >> 1) << 6, wn = (wid & 1) << 6;
  int lr = lane & 15, lk = (lane >> 4) << 3;
  f32x4 acc[4][4] = {};
  for (int k0 = 0; k0 < K; k0 += 32) {
    __syncthreads();
#pragma unroll
    for (int q = 0; q < 2; ++q) {
      int idx = tid + (q << 8);
      int row = idx >> 2, k8 = (idx & 3) << 3;
      *(s16x8*)&As[row][k8] = *(const s16x8*)(A + (size_t)(m0 + row) * K + k0 + k8);
      *(s16x8*)&Bs[row][k8] = *(const s16x8*)(W + (size_t)(n0 + row) * K + k0 + k8);
    }
    __syncthreads();
    s16x8 af[4], bw[4];
#pragma unroll
    for (int i = 0; i < 4; ++i) {
      af[i] = *(const s16x8*)&As[wm + (i << 4) + lr][lk];
      bw[i] = *(const s16x8*)&Bs[wn + (i << 4) + lr][lk];
    }
#pragma unroll
    for (int i = 0; i < 4; ++i)
#pragma unroll
      for (int j = 0; j < 4; ++j)
        acc[i][j] = __builtin_amdgcn_mfma_f32_16x16x32_bf16(af[i], bw[j], acc[i][j], 0, 0, 0);
  }
#pragma unroll
  for (int i = 0; i < 4; ++i) {
    int row = m0 + wm + (i << 4) + ((lane >> 4) << 2);
#pragma unroll
    for (int j = 0; j < 4; ++j) {
      int col = n0 + wn + (j << 4) + lr;
      float bv = bias[col];
#pragma unroll
      for (int r = 0; r < 4; ++r) {
        float v = acc[i][j][r] + bv;
        if (EPI) {
          v = tanhf(v * invS * g[col] + bb[col]);
          Cb[(size_t)(row + r) * N + col] = f2bf(v);
        } else {
          Cf[(size_t)(row + r) * N + col] = v;
        }
      }
    }
  }
}

// ---------------- launcher ----------------
extern "C" void kernel_launch(void* const* d_in, const int* in_sizes, int n_in,
                              void* d_out, int out_size, void* d_ws, size_t ws_size,
                              hipStream_t stream) {
  const int*   tokens = (const int*)d_in[0];
  const float* h0    = (const float*)d_in[1];
  const float* c0    = (const float*)d_in[2];
  const float* embW  = (const float*)d_in[3];
  const float* rWih  = (const float*)d_in[4];
  const float* rWhh  = (const float*)d_in[5];
  const float* rb    = (const float*)d_in[6];
  const float* sWih  = (const float*)d_in[7];
  const float* sWhh  = (const float*)d_in[8];
  const float* sbv   = (const float*)d_in[9];
  const float* mWih  = (const float*)d_in[10];
  const float* mWhh  = (const float*)d_in[11];
  const float* mb    = (const float*)d_in[12];
  const float* piW1  = (const float*)d_in[13];
  const float* pib1  = (const float*)d_in[14];
  const float* pilng = (const float*)d_in[15];
  const float* pilnb = (const float*)d_in[16];
  const float* piW2  = (const float*)d_in[17];
  const float* pib2  = (const float*)d_in[18];
  const float* predW = (const float*)d_in[19];
  const float* predb = (const float*)d_in[20];
  const float* bng   = (const float*)d_in[21];
  const float* bnb   = (const float*)d_in[22];
  const float* decW  = (const float*)d_in[23];
  const float* decb  = (const float*)d_in[24];
  float* out = (float*)d_out;
  float* ws  = (float*)d_ws;

  // float region
  float* emb   = ws;                             // 2,097,152
  unsigned* uHL0 = (unsigned*)(emb + 2097152);   //    65,536
  unsigned* uHL1 = uHL0 + 65536;                 //    65,536
  float* cbuf  = (float*)(uHL1 + 65536);         //    32,768
  float* stack = cbuf + 32768;                   //    65,536
  float* slabG = stack + 65536;                  //   409,600
  float* slabG2 = slabG + 409600;                //   131,072
  float* Xz    = slabG2 + 131072;                // 2,097,152
  // ushort region
  unsigned short* X_ihH  = (unsigned short*)(Xz + 2097152);     // 50,331,648
  unsigned short* wpak   = X_ihH + 50331648;                    // 33,554,432
  unsigned short* wcatH  = wpak + 33554432;                     //  6,291,456
  unsigned short* embH   = wcatH + 6291456;                     //  2,097,152
  unsigned short* outsb  = embH + 2097152;                      //  4,194,304
  int* depth = (int*)(outsb + 4194304);                         // 64 ints
  int* bar   = depth + 64;                                      // 160 ints
  // post-scan aliases (wpak is dead after the scan)
  unsigned short* decWb  = wpak;                                // 16,384,000
  unsigned short* predWb = wpak + 16384000;                     //    524,288
  unsigned short* ytbf   = wpak + 16908288;                     //  2,097,152

  init_state<<<dim3(256), dim3(256), 0, stream>>>(h0, c0, uHL0, cbuf, stack, depth, bar);
  embed_kernel<<<dim3(4096), dim3(128), 0, stream>>>(tokens, embW, emb);
  to_f16<<<dim3(2048), dim3(256), 0, stream>>>(emb, embH, 524288);
  pack_wcat16<<<dim3(24576), dim3(256), 0, stream>>>(rWih, sWih, mWih, wcatH);
  pack_whilo<<<dim3(131072), dim3(256), 0, stream>>>(rWhh, sWhh, mWhh, mWih, wpak);

  // Xz = emb @ piW1[:,1024:1536]^T  (fp32, exact sampling path)
  xz_gemm<<<dim3(8, 64), dim3(256), 0, stream>>>(emb, piW1, Xz);
  // X_ih = embH @ wcatH^T  (4096 x 12288, fp16)
  mfma_gemm_f16out<<<dim3(96, 32), dim3(256), 0, stream>>>(embH, wcatH, X_ihH, 512, 12288);

  scan_persistent<<<dim3(NBLK), dim3(512), 0, stream>>>(
      uHL0, uHL1, cbuf, stack, depth, slabG, slabG2, outsb, bar,
      wpak, X_ihH, Xz, piW1, rb, sbv, mb, pib1, pilng, pilnb, piW2, pib2);

  // pred/dec weights converted after the scan into the dead wpak region
  to_bf16<<<dim3(512), dim3(256), 0, stream>>>(predW, predWb, 131072);
  to_bf16<<<dim3(16000), dim3(256), 0, stream>>>(decW, decWb, 4096000);

  float invS = 1.0f / sqrtf(1.0f + 1e-5f);
  mfma_gemm<1><<<dim3(4, 32), dim3(256), 0, stream>>>(
      outsb, predWb, predb, 1024, 512, nullptr, ytbf, bng, bnb, invS);
  mfma_gemm<0><<<dim3(250, 32), dim3(256), 0, stream>>>(
      ytbf, decWb, decb, 512, 32000, out, nullptr, nullptr, nullptr, 0.0f);
  final_copy<<<dim3(128), dim3(256), 0, stream>>>(uHL0, cbuf, out);
}